// Round 1
// 1965.048 us; speedup vs baseline: 1.9624x; 1.9624x over previous
//
#include <hip/hip_runtime.h>
#include <cstdint>
#include <cstddef>

#define NODES   55
#define BGRAPH  16384
#define NTOT    (BGRAPH*NODES)    // 901120
#define INCH    13
#define HID     32
#define ETOT    (4*NTOT)          // 3604480
#define NCHUNK  (NTOT/1024)       // 880 exact
#define NPB     128               // nodes per block (layer kernels)
#define ECAP    640               // LDS edge-list capacity (mean 512, +5.7 sigma; global fallback)

typedef _Float16 f16;
typedef _Float16 f16x4 __attribute__((ext_vector_type(4))); // 8B
typedef _Float16 f16x8 __attribute__((ext_vector_type(8))); // 16B

__device__ __forceinline__ float selu_f(float v){
  const float s  = 1.0507009873554805f;
  const float sa = 1.7580993408473766f;   // scale*alpha
  return v > 0.f ? s*v : sa*(__expf(v)-1.f);
}

// ---------------- CSR build ----------------
__global__ void k_hist(const int* __restrict__ dst, int* __restrict__ deg){
  int e = blockIdx.x*256 + threadIdx.x;
  if (e < ETOT) atomicAdd(&deg[dst[e]], 1);
}

__global__ void k_scan1(const int* __restrict__ deg, int* __restrict__ part){
  __shared__ int sd[256];
  int b = blockIdx.x, t = threadIdx.x;
  const int4* p = (const int4*)(deg + b*1024);
  int4 v = p[t];
  sd[t] = v.x+v.y+v.z+v.w;
  __syncthreads();
  for (int o=128;o>0;o>>=1){ if (t<o) sd[t]+=sd[t+o]; __syncthreads(); }
  if (t==0) part[b] = sd[0];
}

__global__ void k_scan2(int* __restrict__ part, int nc){
  __shared__ int sd[1024];
  int t = threadIdx.x;
  int orig = (t<nc) ? part[t] : 0;
  sd[t] = orig;
  __syncthreads();
  for (int o=1;o<1024;o<<=1){
    int v = (t>=o) ? sd[t-o] : 0;
    __syncthreads();
    sd[t] += v;
    __syncthreads();
  }
  if (t<nc) part[t] = sd[t] - orig;   // exclusive
}

__global__ void k_scan3(const int* __restrict__ deg, const int* __restrict__ part,
                        int* __restrict__ off){
  __shared__ int sd[256];
  int b = blockIdx.x, t = threadIdx.x;
  const int4* p = (const int4*)(deg + b*1024);
  int4 v = p[t];
  int s = v.x+v.y+v.z+v.w;
  sd[t] = s;
  __syncthreads();
  for (int o=1;o<256;o<<=1){
    int val = (t>=o) ? sd[t-o] : 0;
    __syncthreads();
    sd[t] += val;
    __syncthreads();
  }
  int base = part[b] + sd[t] - s;     // exclusive prefix for this thread
  int i = b*1024 + t*4;
  off[i]   = base;
  off[i+1] = base + v.x;
  off[i+2] = base + v.x + v.y;
  off[i+3] = base + v.x + v.y + v.z;
  if (b==0 && t==0) off[NTOT] = ETOT;
}

// node-owner gather no longer needs packed dst bits: plain src index
__global__ void k_fill(const int* __restrict__ src, const int* __restrict__ dst,
                       int* __restrict__ cur, uint32_t* __restrict__ csrp){
  int e = blockIdx.x*256 + threadIdx.x;
  if (e >= ETOT) return;
  int d = dst[e];
  int pos = atomicAdd(&cur[d], 1);
  csrp[pos] = (uint32_t)src[e];
}

// ---------------- pad x[N,13] fp32 -> xf[N,16] fp32 (64B aligned rows) ----------------
__global__ __launch_bounds__(256) void k_pad(const float* __restrict__ x,
                                             float* __restrict__ xf){
  int i = blockIdx.x*256 + threadIdx.x;   // one float4 per thread, NTOT*4 total (grid exact)
  int node = i>>2, q = i&3;
  const float* r = x + (size_t)node*INCH + q*4;
  float4 v;
  v.x = r[0];
  v.y = (q<3) ? r[1] : 0.f;
  v.z = (q<3) ? r[2] : 0.f;
  v.w = (q<3) ? r[3] : 0.f;
  ((float4*)xf)[i] = v;
}

// ---------------- fused SAGE layer 0 (node-owner register gather) ----------------
__global__ __launch_bounds__(256,8) void k_layer0(
    const float* __restrict__ xf,
    const int* __restrict__ off, const uint32_t* __restrict__ csrp,
    const float* __restrict__ wl0, const float* __restrict__ bl0,
    const float* __restrict__ wr0,
    f16* __restrict__ hout, f16* __restrict__ jkout)
{
  __shared__ float    AG0[NPB*17];      // 8704 B; aliased as f16 staging later
  __shared__ uint32_t EL[ECAP];         // 2560 B edge list
  __shared__ int      sOFF[NPB+2];      // 520 B
  int t = threadIdx.x;
  int base = blockIdx.x*NPB;
  int e0 = off[base];                   // uniform -> scalar load
  int e1 = off[base+NPB];
  for (int i=t; i<NPB+1; i+=256) sOFF[i] = off[base+i];
  int lim = (e1-e0) < ECAP ? (e1-e0) : ECAP;
  for (int i=t; i<lim; i+=256) EL[i] = csrp[e0+i];
  __syncthreads();

  // gather: 4 lanes per node (16B each), register accumulation, no atomics
  int c4 = t & 3;
  #pragma unroll
  for (int p=0;p<2;p++){
    int nl = p*64 + (t>>2);
    int s = sOFF[nl] - e0;
    int d = sOFF[nl+1] - sOFF[nl];
    float a0=0.f,a1=0.f,a2=0.f,a3=0.f;
    for (int i=0;i<d;i+=4){
      int j0 = s+i;
      bool q1=i+1<d, q2=i+2<d, q3=i+3<d;
      int j1=q1?j0+1:j0, j2=q2?j0+2:j0, j3=q3?j0+3:j0;
      uint32_t k0,k1,k2,k3;
      if (j0+3 < ECAP){ k0=EL[j0]; k1=EL[j1]; k2=EL[j2]; k3=EL[j3]; }
      else            { k0=csrp[e0+j0]; k1=csrp[e0+j1]; k2=csrp[e0+j2]; k3=csrp[e0+j3]; }
      float4 g0 = *((const float4*)(xf + (size_t)k0*16u) + c4);
      float4 g1 = *((const float4*)(xf + (size_t)k1*16u) + c4);
      float4 g2 = *((const float4*)(xf + (size_t)k2*16u) + c4);
      float4 g3 = *((const float4*)(xf + (size_t)k3*16u) + c4);
      a0 += (g0.x + (q1?g1.x:0.f)) + ((q2?g2.x:0.f) + (q3?g3.x:0.f));
      a1 += (g0.y + (q1?g1.y:0.f)) + ((q2?g2.y:0.f) + (q3?g3.y:0.f));
      a2 += (g0.z + (q1?g1.z:0.f)) + ((q2?g2.z:0.f) + (q3?g3.z:0.f));
      a3 += (g0.w + (q1?g1.w:0.f)) + ((q2?g2.w:0.f) + (q3?g3.w:0.f));
    }
    int di = nl*17 + 4*c4;
    AG0[di]=a0; AG0[di+1]=a1; AG0[di+2]=a2; AG0[di+3]=a3;
  }
  __syncthreads();

  // phase 2: node = base+(t&127), ochalf = t>>7 (wave-uniform -> scalar weights)
  int nl2 = t & 127;
  int node = base + nl2;
  int oc0 = __builtin_amdgcn_readfirstlane((t>>7)*16);
  int cnt = sOFF[nl2+1]-sOFF[nl2]; if (cnt<1) cnt=1;
  float inv = 1.f/(float)cnt;
  const float4* xr4 = (const float4*)(xf + (size_t)node*16);
  float4 X0=xr4[0], X1=xr4[1], X2=xr4[2];
  float x12 = ((const float*)(xr4+3))[0];
  float xc[13] = {X0.x,X0.y,X0.z,X0.w,X1.x,X1.y,X1.z,X1.w,X2.x,X2.y,X2.z,X2.w,x12};
  float acc[16];
  #pragma unroll
  for (int j=0;j<16;j++) acc[j] = bl0[oc0+j];
  #pragma unroll
  for (int cc=0;cc<INCH;cc++){
    float xcv = xc[cc];
    float mc = AG0[nl2*17+cc]*inv;
    #pragma unroll
    for (int j=0;j<16;j++)
      acc[j] = fmaf(xcv, wr0[cc*HID+oc0+j], fmaf(mc, wl0[cc*HID+oc0+j], acc[j]));
  }
  __syncthreads();                      // AG0 reads done -> safe to alias as staging
  f16* ST0 = (f16*)AG0;
  #pragma unroll
  for (int j=0;j<16;j++) ST0[nl2*34 + oc0 + j] = (f16)selu_f(acc[j]);
  __syncthreads();

  const uint32_t* STd = (const uint32_t*)AG0;
  uint4* ho4 = (uint4*)hout;
  uint4* jo4 = (uint4*)jkout;
  int gbase = blockIdx.x*(NPB*HID/8);   // 512 16B-chunks per block
  #pragma unroll
  for (int k=0;k<2;k++){
    int cch = t + 256*k;
    int n = cch>>2, m = cch&3;
    int dd = n*17 + m*4;
    uint4 u;
    u.x=STd[dd]; u.y=STd[dd+1]; u.z=STd[dd+2]; u.w=STd[dd+3];
    ho4[gbase+cch] = u;
    jo4[gbase+cch] = u;
  }
}

// ---------------- fused SAGE layers 1..4 (node-owner register gather) ----------------
__global__ __launch_bounds__(256,8) void k_layer(
    const f16* __restrict__ hin,
    const int* __restrict__ off, const uint32_t* __restrict__ csrp,
    const float* __restrict__ wl, const float* __restrict__ bl,
    const float* __restrict__ wr,
    f16* __restrict__ hout, f16* __restrict__ jkio)
{
  __shared__ float    AGf[NPB*33];      // 16896 B; aliased as f16 staging later
  __shared__ uint32_t EL[ECAP];         // 2560 B
  __shared__ int      sOFF[NPB+2];      // 520 B  (total 19976 B -> 8 blocks/CU)
  int t = threadIdx.x;
  int base = blockIdx.x*NPB;
  int e0 = off[base];
  int e1 = off[base+NPB];
  for (int i=t; i<NPB+1; i+=256) sOFF[i] = off[base+i];
  int lim = (e1-e0) < ECAP ? (e1-e0) : ECAP;
  for (int i=t; i<lim; i+=256) EL[i] = csrp[e0+i];
  __syncthreads();

  // gather: 4 lanes per node (f16x8 = 16B each), register accumulation, no atomics.
  // 4 edges batched per iteration -> 16 nodes x 4 x 64B = 4KB in flight per wave.
  int c4 = t & 3;
  #pragma unroll
  for (int p=0;p<2;p++){
    int nl = p*64 + (t>>2);
    int s = sOFF[nl] - e0;
    int d = sOFF[nl+1] - sOFF[nl];
    float a[8];
    #pragma unroll
    for (int r=0;r<8;r++) a[r] = 0.f;
    for (int i=0;i<d;i+=4){
      int j0 = s+i;
      bool q1=i+1<d, q2=i+2<d, q3=i+3<d;
      int j1=q1?j0+1:j0, j2=q2?j0+2:j0, j3=q3?j0+3:j0;
      uint32_t k0,k1,k2,k3;
      if (j0+3 < ECAP){ k0=EL[j0]; k1=EL[j1]; k2=EL[j2]; k3=EL[j3]; }
      else            { k0=csrp[e0+j0]; k1=csrp[e0+j1]; k2=csrp[e0+j2]; k3=csrp[e0+j3]; }
      f16x8 g0 = *((const f16x8*)(hin + (size_t)k0*32u) + c4);
      f16x8 g1 = *((const f16x8*)(hin + (size_t)k1*32u) + c4);
      f16x8 g2 = *((const f16x8*)(hin + (size_t)k2*32u) + c4);
      f16x8 g3 = *((const f16x8*)(hin + (size_t)k3*32u) + c4);
      #pragma unroll
      for (int r=0;r<8;r++){
        float s0=(float)g0[r];
        float s1=q1?(float)g1[r]:0.f;
        float s2=q2?(float)g2[r]:0.f;
        float s3=q3?(float)g3[r]:0.f;
        a[r] += (s0+s1)+(s2+s3);
      }
    }
    int di = nl*33 + 8*c4;
    #pragma unroll
    for (int r=0;r<8;r++) AGf[di+r] = a[r];
  }
  __syncthreads();

  // phase 2: node = base+(t&127), ochalf = t>>7 (wave-uniform -> scalar weights)
  int nl2 = t & 127;
  int node = base + nl2;
  int oc0 = __builtin_amdgcn_readfirstlane((t>>7)*16);
  int cnt = sOFF[nl2+1]-sOFF[nl2]; if (cnt<1) cnt=1;
  float inv = 1.f/(float)cnt;
  const f16x8* h8 = (const f16x8*)(hin + (size_t)node*HID);
  float acc[16];
  #pragma unroll
  for (int j=0;j<16;j++) acc[j] = bl[oc0+j];
  #pragma unroll
  for (int jj=0;jj<4;jj++){
    f16x8 vh = h8[jj];
    #pragma unroll
    for (int r=0;r<8;r++){
      int cc = 8*jj+r;
      float hc = (float)vh[r];
      float mc = AGf[nl2*33+cc]*inv;
      #pragma unroll
      for (int j=0;j<16;j++)
        acc[j] = fmaf(hc, wr[cc*HID+oc0+j], fmaf(mc, wl[cc*HID+oc0+j], acc[j]));
    }
  }
  __syncthreads();   // all AGf reads done -> safe to alias as staging
  f16* ST = (f16*)AGf;
  #pragma unroll
  for (int j=0;j<16;j++) ST[nl2*34 + oc0 + j] = (f16)selu_f(acc[j]);
  __syncthreads();

  const uint32_t* STd = (const uint32_t*)AGf;
  uint4* ho4 = (uint4*)hout;
  uint4* jo4 = (uint4*)jkio;
  int gbase = blockIdx.x*(NPB*HID/8);
  #pragma unroll
  for (int k=0;k<2;k++){
    int cch = t + 256*k;
    int n = cch>>2, m = cch&3;
    int dd = n*17 + m*4;
    union { uint4 u; f16 hh[8]; } hv, jv;
    hv.u.x=STd[dd]; hv.u.y=STd[dd+1]; hv.u.z=STd[dd+2]; hv.u.w=STd[dd+3];
    jv.u = jo4[gbase+cch];
    #pragma unroll
    for (int r=0;r<8;r++){
      float a = (float)jv.hh[r], b = (float)hv.hh[r];
      jv.hh[r] = (f16)fmaxf(a, b);
    }
    ho4[gbase+cch] = hv.u;
    jo4[gbase+cch] = jv.u;
  }
}

// ---------------- attention + head, one block per graph ----------------
__global__ __launch_bounds__(256) void k_attn(
    const f16* __restrict__ jk, const float* __restrict__ x,
    const int* __restrict__ shuf,
    const float* __restrict__ wq, const float* __restrict__ bq,
    const float* __restrict__ wk, const float* __restrict__ bk,
    const float* __restrict__ wv, const float* __restrict__ bv,
    const float* __restrict__ wo, const float* __restrict__ bo,
    const float* __restrict__ wfc, const float* __restrict__ bfc,
    float* __restrict__ out)
{
  __shared__ float H[NODES*33];
  __shared__ float K[NODES*33];
  __shared__ float V[NODES*33];
  __shared__ float Wq[HID*HID];
  __shared__ float Wo[HID*HID];
  __shared__ float Wfc[192*6];
  __shared__ float Qs[6*33];
  __shared__ float S[6*56];
  __shared__ float O[6*33];
  __shared__ float SO[192];
  __shared__ float part[96];
  __shared__ float M[NODES];
  __shared__ int order[8];
  __shared__ int sel[6];

  int g = blockIdx.x, t = threadIdx.x;
  for (int i=t; i<HID*HID; i+=256){ Wq[i]=wq[i]; Wo[i]=wo[i]; }
  for (int i=t; i<192*6;   i+=256){ Wfc[i]=wfc[i]; }
  {
    const f16x8* j8 = (const f16x8*)(jk + (size_t)g*NODES*HID);
    for (int i=t; i<NODES*HID/8; i+=256){     // 220 vectors of 8
      f16x8 v = j8[i];
      int node = i >> 2, c0 = (i & 3)*8;
      #pragma unroll
      for (int r=0;r<8;r++) H[node*33 + c0 + r] = selu_f((float)v[r]);
    }
  }
  if (t < NODES) M[t] = x[(size_t)(g*NODES+t)*INCH + (INCH-3)];
  __syncthreads();
  if (t == 0){
    int c = 0;
    for (int n=0;n<NODES;n++) if (M[n] > 0.5f && c < 6) order[c++] = n;
  }
  __syncthreads();
  if (t < 6) sel[t] = order[shuf[g*6 + t]];
  __syncthreads();

  // K and V: lane = node, wave-uniform output-channel group -> scalar weights
  {
    int k = t & 63;
    int ocg = __builtin_amdgcn_readfirstlane(t >> 6);   // 0..3, wave-uniform
    const float* wkp = wk + ocg*8;
    const float* wvp = wv + ocg*8;
    if (k < NODES){
      float ak[8], av[8];
      #pragma unroll
      for (int j=0;j<8;j++){ ak[j]=bk[ocg*8+j]; av[j]=bv[ocg*8+j]; }
      #pragma unroll
      for (int c=0;c<HID;c++){
        float hv = H[k*33+c];
        #pragma unroll
        for (int j=0;j<8;j++){
          ak[j] = fmaf(hv, wkp[c*HID+j], ak[j]);
          av[j] = fmaf(hv, wvp[c*HID+j], av[j]);
        }
      }
      #pragma unroll
      for (int j=0;j<8;j++){ K[k*33+ocg*8+j]=ak[j]; V[k*33+ocg*8+j]=av[j]; }
    }
  }
  // Q: 6 queries x 32 channels
  if (t < 192){
    int q = t>>5, oc = t&31;
    int node = sel[q];
    float a = bq[oc];
    #pragma unroll
    for (int c=0;c<HID;c++) a = fmaf(H[node*33+c], Wq[c*HID+oc], a);
    Qs[q*33+oc] = a;
  }
  __syncthreads();

  // scores = Q.K^T / sqrt(32)
  for (int idx=t; idx<6*NODES; idx+=256){
    int q = idx % 6, k = idx / 6;
    float a = 0.f;
    #pragma unroll
    for (int c=0;c<HID;c++) a = fmaf(Qs[q*33+c], K[k*33+c], a);
    S[q*56+k] = a * 0.17677669529663687f;
  }
  __syncthreads();

  // softmax over 55 keys: 32-lane group per query
  if (t < 192){
    int q = t>>5, l = t&31;
    float v0 = (l      < NODES) ? S[q*56+l]    : -1e30f;
    float v1 = (l+32   < NODES) ? S[q*56+l+32] : -1e30f;
    float mx = fmaxf(v0, v1);
    #pragma unroll
    for (int o=16;o>0;o>>=1) mx = fmaxf(mx, __shfl_xor(mx, o, 32));
    float p0 = (l    < NODES) ? __expf(v0-mx) : 0.f;
    float p1 = (l+32 < NODES) ? __expf(v1-mx) : 0.f;
    float sm = p0 + p1;
    #pragma unroll
    for (int o=16;o>0;o>>=1) sm += __shfl_xor(sm, o, 32);
    float inv = 1.f/sm;
    if (l    < NODES) S[q*56+l]    = p0*inv;
    if (l+32 < NODES) S[q*56+l+32] = p1*inv;
  }
  __syncthreads();

  // attn @ V
  if (t < 192){
    int q = t>>5, oc = t&31;
    float a = 0.f;
    for (int k=0;k<NODES;k++) a = fmaf(S[q*56+k], V[k*33+oc], a);
    O[q*33+oc] = a;
  }
  __syncthreads();

  // @ wo + bo, selu
  if (t < 192){
    int q = t>>5, oc = t&31;
    float a = bo[oc];
    #pragma unroll
    for (int c=0;c<HID;c++) a = fmaf(O[q*33+c], Wo[c*HID+oc], a);
    SO[t] = selu_f(a);   // t == q*32+oc == flat reshape index
  }
  __syncthreads();

  // final FC: 6 outputs = SO[192] . Wfc[:,j]
  if (t < 96){
    int j = t % 6, pp = t / 6;   // 16 partials per output
    float a = 0.f;
    #pragma unroll
    for (int r=0;r<12;r++) a = fmaf(SO[pp*12+r], Wfc[(pp*12+r)*6+j], a);
    part[pp*6+j] = a;
  }
  __syncthreads();
  if (t < 6){
    float a = bfc[t];
    #pragma unroll
    for (int pp=0;pp<16;pp++) a += part[pp*6+t];
    out[g*6+t] = a;
  }
}

extern "C" void kernel_launch(void* const* d_in, const int* in_sizes, int n_in,
                              void* d_out, int out_size, void* d_ws, size_t ws_size,
                              hipStream_t stream)
{
  const float* x   = (const float*)d_in[0];
  const int*   eix = (const int*)d_in[1];
  const int*   shf = (const int*)d_in[2];
  const float* wl0 = (const float*)d_in[3];
  const float* bl0 = (const float*)d_in[4];
  const float* wr0 = (const float*)d_in[5];
  const float* wl  = (const float*)d_in[6];
  const float* bl  = (const float*)d_in[7];
  const float* wr  = (const float*)d_in[8];
  const float* wq  = (const float*)d_in[9];
  const float* bq  = (const float*)d_in[10];
  const float* wk  = (const float*)d_in[11];
  const float* bk  = (const float*)d_in[12];
  const float* wv  = (const float*)d_in[13];
  const float* bv  = (const float*)d_in[14];
  const float* wo  = (const float*)d_in[15];
  const float* bo  = (const float*)d_in[16];
  const float* wfc = (const float*)d_in[17];
  const float* bfc = (const float*)d_in[18];
  float* out = (float*)d_out;

  const int* esrc = eix;
  const int* edst = eix + ETOT;

  // workspace carve — total ~195 MB
  char* p = (char*)d_ws;
  auto carve = [&](size_t bytes){ void* r = (void*)p; p += (bytes + 255) & ~(size_t)255; return r; };
  int*      deg  = (int*)carve(sizeof(int)*NTOT);          // reused as `cur` for k_fill
  int*      off  = (int*)carve(sizeof(int)*(NTOT+1));
  int*      part = (int*)carve(sizeof(int)*1024);
  uint32_t* csrp = (uint32_t*)carve(sizeof(uint32_t)*(size_t)ETOT);
  f16*      h_a  = (f16*)carve(2*(size_t)NTOT*HID);
  f16*      h_b  = (f16*)carve(2*(size_t)NTOT*HID);
  f16*      jk16 = (f16*)carve(2*(size_t)NTOT*HID);

  // xf (padded fp32 x, N x 16 = 57.7MB) aliases h_b: dead before layer 1 writes h_b
  float* xf = (float*)h_b;

  hipMemsetAsync(deg, 0, sizeof(int)*NTOT, stream);
  k_pad  <<<ETOT/256,  256, 0, stream>>>(x, xf);
  k_hist <<<ETOT/256,  256, 0, stream>>>(edst, deg);
  k_scan1<<<NCHUNK,    256, 0, stream>>>(deg, part);
  k_scan2<<<1,        1024, 0, stream>>>(part, NCHUNK);
  k_scan3<<<NCHUNK,    256, 0, stream>>>(deg, part, off);
  // reuse deg as the fill cursor
  hipMemcpyAsync(deg, off, sizeof(int)*NTOT, hipMemcpyDeviceToDevice, stream);
  k_fill <<<ETOT/256,  256, 0, stream>>>(esrc, edst, deg, csrp);

  k_layer0<<<NTOT/NPB, 256, 0, stream>>>(xf, off, csrp, wl0, bl0, wr0, h_a, jk16);
  f16* hc = h_a; f16* hn = h_b;
  for (int l=0; l<4; l++){
    k_layer<<<NTOT/NPB, 256, 0, stream>>>(hc, off, csrp,
                                          wl + l*HID*HID, bl + l*HID, wr + l*HID*HID,
                                          hn, jk16);
    f16* tmp = hc; hc = hn; hn = tmp;
  }
  k_attn<<<BGRAPH, 256, 0, stream>>>(jk16, x, shf,
                                     wq, bq, wk, bk, wv, bv, wo, bo, wfc, bfc, out);
}

// Round 2
// 1871.419 us; speedup vs baseline: 2.0606x; 1.0500x over previous
//
#include <hip/hip_runtime.h>
#include <cstdint>
#include <cstddef>

#define NODES   55
#define BGRAPH  16384
#define NTOT    (BGRAPH*NODES)    // 901120
#define INCH    13
#define HID     32
#define ETOT    (4*NTOT)          // 3604480
#define NPB     128               // nodes per block (layer kernels)
#define ECAP    640               // LDS edge-list capacity in layer kernels

// ---- binned CSR build ----
#define NBUCK   220               // NTOT/4096 buckets
#define BSH     12                // 4096 nodes per bucket
#define BMSK    4095
#define BCAP    64                // staged entries per bucket per block (mean 32, +5.7 sigma)
#define BSTRIDE 17664             // global region per bucket (mean 16384, +10 sigma), mult of 16
#define BINBLK  512
#define BINTH   256
#define BINGRP  (ETOT/4/BINBLK)   // 1760 int4-groups per block

typedef _Float16 f16;
typedef _Float16 f16x4 __attribute__((ext_vector_type(4))); // 8B
typedef _Float16 f16x8 __attribute__((ext_vector_type(8))); // 16B

__device__ __forceinline__ float selu_f(float v){
  const float s  = 1.0507009873554805f;
  const float sa = 1.7580993408473766f;   // scale*alpha
  return v > 0.f ? s*v : sa*(__expf(v)-1.f);
}

// ---------------- pad x[N,13] fp32 -> xf[N,16] fp32; also zero bucket cursors ----------------
__global__ __launch_bounds__(256) void k_pad(const float* __restrict__ x,
                                             float* __restrict__ xf,
                                             int* __restrict__ gcur){
  if (blockIdx.x == 0) gcur[threadIdx.x & 255] = 0;   // 256 >= NBUCK
  int i = blockIdx.x*256 + threadIdx.x;   // one float4 per thread, ETOT total (grid exact)
  int node = i>>2, q = i&3;
  const float* r = x + (size_t)node*INCH + q*4;
  float4 v;
  v.x = r[0];
  v.y = (q<3) ? r[1] : 0.f;
  v.z = (q<3) ? r[2] : 0.f;
  v.w = (q<3) ? r[3] : 0.f;
  ((float4*)xf)[i] = v;
}

// ---------------- phase A: bin edges by dst>>12, LDS-staged, single flush per bucket ----------------
__global__ __launch_bounds__(BINTH) void k_bin(
    const int* __restrict__ src, const int* __restrict__ dst,
    int* __restrict__ gcur, uint32_t* __restrict__ binned)
{
  __shared__ uint32_t staged[NBUCK*BCAP];   // 56320 B
  __shared__ int lcnt[NBUCK];
  int t = threadIdx.x, bid = blockIdx.x;
  for (int i=t;i<NBUCK;i+=BINTH) lcnt[i]=0;
  __syncthreads();
  const int4* s4 = (const int4*)src;
  const int4* d4 = (const int4*)dst;
  int g0 = bid*BINGRP;
  for (int i=t; i<BINGRP; i+=BINTH){
    int4 s = s4[g0+i];
    int4 d = d4[g0+i];
    #pragma unroll
    for (int j=0;j<4;j++){
      int dd = (&d.x)[j];
      int ss = (&s.x)[j];
      int b  = dd >> BSH;
      uint32_t entry = (uint32_t)ss | ((uint32_t)(dd & BMSK) << 20);
      int pos = atomicAdd(&lcnt[b], 1);
      if (pos < BCAP) staged[b*BCAP+pos] = entry;
      else {                                  // ~never (5.7 sigma); correctness fallback
        int gp = atomicAdd(&gcur[b], 1);
        if (gp < BSTRIDE) binned[(size_t)b*BSTRIDE + gp] = entry;
      }
    }
  }
  __syncthreads();
  // flush: wave w handles buckets [w*55, (w+1)*55)
  int w = t >> 6, lane = t & 63;
  for (int b = w*55; b < w*55+55; ++b){
    int c = lcnt[b]; if (c > BCAP) c = BCAP;
    if (c == 0) continue;
    int base;
    if (lane == 0) base = atomicAdd(&gcur[b], c);
    base = __shfl(base, 0);
    if (lane < c){
      int gp = base + lane;
      if (gp < BSTRIDE) binned[(size_t)b*BSTRIDE + gp] = staged[b*BCAP+lane];
    }
  }
}

// ---------------- exclusive scan of 220 bucket counts ----------------
__global__ __launch_bounds__(256) void k_bscan(const int* __restrict__ gcur,
                                               int* __restrict__ bbase){
  __shared__ int sd[256];
  int t = threadIdx.x;
  int v = (t<NBUCK) ? gcur[t] : 0;
  sd[t] = v; __syncthreads();
  for (int o=1;o<256;o<<=1){
    int u = (t>=o) ? sd[t-o] : 0;
    __syncthreads();
    sd[t] += u;
    __syncthreads();
  }
  if (t<NBUCK) bbase[t] = sd[t] - v;
}

// ---------------- phase B: per-bucket counting sort -> off + csrp (L2-local scatter) ----------------
__global__ __launch_bounds__(1024) void k_bucket(
    const uint32_t* __restrict__ binned, const int* __restrict__ gcur,
    const int* __restrict__ bbase, int* __restrict__ off,
    uint32_t* __restrict__ csrp)
{
  __shared__ int hist[4096];   // degree counts -> scatter cursors
  __shared__ int ws[1024];
  int b = blockIdx.x, t = threadIdx.x;
  int cnt = gcur[b]; if (cnt > BSTRIDE) cnt = BSTRIDE;
  int base = bbase[b];
  const uint32_t* ep = binned + (size_t)b*BSTRIDE;
  #pragma unroll
  for (int i=0;i<4;i++) hist[t+1024*i] = 0;
  __syncthreads();
  // pass 1: local-degree histogram
  int nv = cnt>>2;
  const uint4* e4 = (const uint4*)ep;
  for (int i=t;i<nv;i+=1024){
    uint4 e = e4[i];
    atomicAdd(&hist[(e.x>>20)&BMSK],1);
    atomicAdd(&hist[(e.y>>20)&BMSK],1);
    atomicAdd(&hist[(e.z>>20)&BMSK],1);
    atomicAdd(&hist[(e.w>>20)&BMSK],1);
  }
  for (int i=nv*4+t;i<cnt;i+=1024) atomicAdd(&hist[(ep[i]>>20)&BMSK],1);
  __syncthreads();
  // exclusive scan of 4096 degrees
  int t4 = t*4;
  int s0=hist[t4], s1=hist[t4+1], s2=hist[t4+2], s3=hist[t4+3];
  int sum = s0+s1+s2+s3;
  ws[t] = sum; __syncthreads();
  for (int o=1;o<1024;o<<=1){
    int u = (t>=o) ? ws[t-o] : 0;
    __syncthreads();
    ws[t] += u;
    __syncthreads();
  }
  int ex = ws[t] - sum;          // exclusive prefix of this thread's 4-group
  int p0 = ex, p1 = ex+s0, p2 = ex+s0+s1, p3 = ex+s0+s1+s2;
  hist[t4]=p0; hist[t4+1]=p1; hist[t4+2]=p2; hist[t4+3]=p3;   // cursors
  // write off (coalesced int4)
  int nb = b<<BSH;
  int4 ov; ov.x = base+p0; ov.y = base+p1; ov.z = base+p2; ov.w = base+p3;
  ((int4*)(off+nb))[t] = ov;
  if (b == NBUCK-1 && t == 1023) off[NTOT] = ETOT;
  __syncthreads();
  // pass 2: scatter to final CSR (64KB window -> single-XCD L2 absorbs)
  for (int i=t;i<nv;i+=1024){
    uint4 e = e4[i];
    int p;
    p = atomicAdd(&hist[(e.x>>20)&BMSK],1); csrp[base+p] = e.x & 0xFFFFFu;
    p = atomicAdd(&hist[(e.y>>20)&BMSK],1); csrp[base+p] = e.y & 0xFFFFFu;
    p = atomicAdd(&hist[(e.z>>20)&BMSK],1); csrp[base+p] = e.z & 0xFFFFFu;
    p = atomicAdd(&hist[(e.w>>20)&BMSK],1); csrp[base+p] = e.w & 0xFFFFFu;
  }
  for (int i=nv*4+t;i<cnt;i+=1024){
    uint32_t e = ep[i];
    int p = atomicAdd(&hist[(e>>20)&BMSK],1);
    csrp[base+p] = e & 0xFFFFFu;
  }
}

// ---------------- fused SAGE layer 0 (node-owner register gather) ----------------
__global__ __launch_bounds__(256,8) void k_layer0(
    const float* __restrict__ xf,
    const int* __restrict__ off, const uint32_t* __restrict__ csrp,
    const float* __restrict__ wl0, const float* __restrict__ bl0,
    const float* __restrict__ wr0,
    f16* __restrict__ hout, f16* __restrict__ jkout)
{
  __shared__ float    AG0[NPB*17];      // 8704 B; aliased as f16 staging later
  __shared__ uint32_t EL[ECAP];         // 2560 B edge list
  __shared__ int      sOFF[NPB+2];      // 520 B
  int t = threadIdx.x;
  int base = blockIdx.x*NPB;
  int e0 = off[base];                   // uniform -> scalar load
  int e1 = off[base+NPB];
  for (int i=t; i<NPB+1; i+=256) sOFF[i] = off[base+i];
  int lim = (e1-e0) < ECAP ? (e1-e0) : ECAP;
  for (int i=t; i<lim; i+=256) EL[i] = csrp[e0+i];
  __syncthreads();

  // gather: 4 lanes per node (16B each), register accumulation, no atomics
  int c4 = t & 3;
  #pragma unroll
  for (int p=0;p<2;p++){
    int nl = p*64 + (t>>2);
    int s = sOFF[nl] - e0;
    int d = sOFF[nl+1] - sOFF[nl];
    float a0=0.f,a1=0.f,a2=0.f,a3=0.f;
    for (int i=0;i<d;i+=4){
      int j0 = s+i;
      bool q1=i+1<d, q2=i+2<d, q3=i+3<d;
      int j1=q1?j0+1:j0, j2=q2?j0+2:j0, j3=q3?j0+3:j0;
      uint32_t k0,k1,k2,k3;
      if (j0+3 < ECAP){ k0=EL[j0]; k1=EL[j1]; k2=EL[j2]; k3=EL[j3]; }
      else            { k0=csrp[e0+j0]; k1=csrp[e0+j1]; k2=csrp[e0+j2]; k3=csrp[e0+j3]; }
      float4 g0 = *((const float4*)(xf + (size_t)k0*16u) + c4);
      float4 g1 = *((const float4*)(xf + (size_t)k1*16u) + c4);
      float4 g2 = *((const float4*)(xf + (size_t)k2*16u) + c4);
      float4 g3 = *((const float4*)(xf + (size_t)k3*16u) + c4);
      a0 += (g0.x + (q1?g1.x:0.f)) + ((q2?g2.x:0.f) + (q3?g3.x:0.f));
      a1 += (g0.y + (q1?g1.y:0.f)) + ((q2?g2.y:0.f) + (q3?g3.y:0.f));
      a2 += (g0.z + (q1?g1.z:0.f)) + ((q2?g2.z:0.f) + (q3?g3.z:0.f));
      a3 += (g0.w + (q1?g1.w:0.f)) + ((q2?g2.w:0.f) + (q3?g3.w:0.f));
    }
    int di = nl*17 + 4*c4;
    AG0[di]=a0; AG0[di+1]=a1; AG0[di+2]=a2; AG0[di+3]=a3;
  }
  __syncthreads();

  // phase 2: node = base+(t&127), ochalf = t>>7 (wave-uniform -> scalar weights)
  int nl2 = t & 127;
  int node = base + nl2;
  int oc0 = __builtin_amdgcn_readfirstlane((t>>7)*16);
  int cnt = sOFF[nl2+1]-sOFF[nl2]; if (cnt<1) cnt=1;
  float inv = 1.f/(float)cnt;
  const float4* xr4 = (const float4*)(xf + (size_t)node*16);
  float4 X0=xr4[0], X1=xr4[1], X2=xr4[2];
  float x12 = ((const float*)(xr4+3))[0];
  float xc[13] = {X0.x,X0.y,X0.z,X0.w,X1.x,X1.y,X1.z,X1.w,X2.x,X2.y,X2.z,X2.w,x12};
  float acc[16];
  #pragma unroll
  for (int j=0;j<16;j++) acc[j] = bl0[oc0+j];
  #pragma unroll
  for (int cc=0;cc<INCH;cc++){
    float xcv = xc[cc];
    float mc = AG0[nl2*17+cc]*inv;
    #pragma unroll
    for (int j=0;j<16;j++)
      acc[j] = fmaf(xcv, wr0[cc*HID+oc0+j], fmaf(mc, wl0[cc*HID+oc0+j], acc[j]));
  }
  __syncthreads();                      // AG0 reads done -> safe to alias as staging
  f16* ST0 = (f16*)AG0;
  #pragma unroll
  for (int j=0;j<16;j++) ST0[nl2*34 + oc0 + j] = (f16)selu_f(acc[j]);
  __syncthreads();

  const uint32_t* STd = (const uint32_t*)AG0;
  uint4* ho4 = (uint4*)hout;
  uint4* jo4 = (uint4*)jkout;
  int gbase = blockIdx.x*(NPB*HID/8);   // 512 16B-chunks per block
  #pragma unroll
  for (int k=0;k<2;k++){
    int cch = t + 256*k;
    int n = cch>>2, m = cch&3;
    int dd = n*17 + m*4;
    uint4 u;
    u.x=STd[dd]; u.y=STd[dd+1]; u.z=STd[dd+2]; u.w=STd[dd+3];
    ho4[gbase+cch] = u;
    jo4[gbase+cch] = u;
  }
}

// ---------------- fused SAGE layers 1..4 (node-owner register gather) ----------------
__global__ __launch_bounds__(256,8) void k_layer(
    const f16* __restrict__ hin,
    const int* __restrict__ off, const uint32_t* __restrict__ csrp,
    const float* __restrict__ wl, const float* __restrict__ bl,
    const float* __restrict__ wr,
    f16* __restrict__ hout, f16* __restrict__ jkio)
{
  __shared__ float    AGf[NPB*33];      // 16896 B; aliased as f16 staging later
  __shared__ uint32_t EL[ECAP];         // 2560 B
  __shared__ int      sOFF[NPB+2];      // 520 B
  int t = threadIdx.x;
  int base = blockIdx.x*NPB;
  int e0 = off[base];
  int e1 = off[base+NPB];
  for (int i=t; i<NPB+1; i+=256) sOFF[i] = off[base+i];
  int lim = (e1-e0) < ECAP ? (e1-e0) : ECAP;
  for (int i=t; i<lim; i+=256) EL[i] = csrp[e0+i];
  __syncthreads();

  // gather: 4 lanes per node (f16x8 = 16B each), register accumulation, no atomics.
  int c4 = t & 3;
  #pragma unroll
  for (int p=0;p<2;p++){
    int nl = p*64 + (t>>2);
    int s = sOFF[nl] - e0;
    int d = sOFF[nl+1] - sOFF[nl];
    float a[8];
    #pragma unroll
    for (int r=0;r<8;r++) a[r] = 0.f;
    for (int i=0;i<d;i+=4){
      int j0 = s+i;
      bool q1=i+1<d, q2=i+2<d, q3=i+3<d;
      int j1=q1?j0+1:j0, j2=q2?j0+2:j0, j3=q3?j0+3:j0;
      uint32_t k0,k1,k2,k3;
      if (j0+3 < ECAP){ k0=EL[j0]; k1=EL[j1]; k2=EL[j2]; k3=EL[j3]; }
      else            { k0=csrp[e0+j0]; k1=csrp[e0+j1]; k2=csrp[e0+j2]; k3=csrp[e0+j3]; }
      f16x8 g0 = *((const f16x8*)(hin + (size_t)k0*32u) + c4);
      f16x8 g1 = *((const f16x8*)(hin + (size_t)k1*32u) + c4);
      f16x8 g2 = *((const f16x8*)(hin + (size_t)k2*32u) + c4);
      f16x8 g3 = *((const f16x8*)(hin + (size_t)k3*32u) + c4);
      #pragma unroll
      for (int r=0;r<8;r++){
        float s0=(float)g0[r];
        float s1=q1?(float)g1[r]:0.f;
        float s2=q2?(float)g2[r]:0.f;
        float s3=q3?(float)g3[r]:0.f;
        a[r] += (s0+s1)+(s2+s3);
      }
    }
    int di = nl*33 + 8*c4;
    #pragma unroll
    for (int r=0;r<8;r++) AGf[di+r] = a[r];
  }
  __syncthreads();

  // phase 2
  int nl2 = t & 127;
  int node = base + nl2;
  int oc0 = __builtin_amdgcn_readfirstlane((t>>7)*16);
  int cnt = sOFF[nl2+1]-sOFF[nl2]; if (cnt<1) cnt=1;
  float inv = 1.f/(float)cnt;
  const f16x8* h8 = (const f16x8*)(hin + (size_t)node*HID);
  float acc[16];
  #pragma unroll
  for (int j=0;j<16;j++) acc[j] = bl[oc0+j];
  #pragma unroll
  for (int jj=0;jj<4;jj++){
    f16x8 vh = h8[jj];
    #pragma unroll
    for (int r=0;r<8;r++){
      int cc = 8*jj+r;
      float hc = (float)vh[r];
      float mc = AGf[nl2*33+cc]*inv;
      #pragma unroll
      for (int j=0;j<16;j++)
        acc[j] = fmaf(hc, wr[cc*HID+oc0+j], fmaf(mc, wl[cc*HID+oc0+j], acc[j]));
    }
  }
  __syncthreads();   // all AGf reads done -> safe to alias as staging
  f16* ST = (f16*)AGf;
  #pragma unroll
  for (int j=0;j<16;j++) ST[nl2*34 + oc0 + j] = (f16)selu_f(acc[j]);
  __syncthreads();

  const uint32_t* STd = (const uint32_t*)AGf;
  uint4* ho4 = (uint4*)hout;
  uint4* jo4 = (uint4*)jkio;
  int gbase = blockIdx.x*(NPB*HID/8);
  #pragma unroll
  for (int k=0;k<2;k++){
    int cch = t + 256*k;
    int n = cch>>2, m = cch&3;
    int dd = n*17 + m*4;
    union { uint4 u; f16 hh[8]; } hv, jv;
    hv.u.x=STd[dd]; hv.u.y=STd[dd+1]; hv.u.z=STd[dd+2]; hv.u.w=STd[dd+3];
    jv.u = jo4[gbase+cch];
    #pragma unroll
    for (int r=0;r<8;r++){
      float a = (float)jv.hh[r], b = (float)hv.hh[r];
      jv.hh[r] = (f16)fmaxf(a, b);
    }
    ho4[gbase+cch] = hv.u;
    jo4[gbase+cch] = jv.u;
  }
}

// ---------------- attention + head, one block per graph ----------------
__global__ __launch_bounds__(256) void k_attn(
    const f16* __restrict__ jk, const float* __restrict__ x,
    const int* __restrict__ shuf,
    const float* __restrict__ wq, const float* __restrict__ bq,
    const float* __restrict__ wk, const float* __restrict__ bk,
    const float* __restrict__ wv, const float* __restrict__ bv,
    const float* __restrict__ wo, const float* __restrict__ bo,
    const float* __restrict__ wfc, const float* __restrict__ bfc,
    float* __restrict__ out)
{
  __shared__ float H[NODES*33];
  __shared__ float K[NODES*33];
  __shared__ float V[NODES*33];
  __shared__ float Wq[HID*HID];
  __shared__ float Wo[HID*HID];
  __shared__ float Wfc[192*6];
  __shared__ float Qs[6*33];
  __shared__ float S[6*56];
  __shared__ float O[6*33];
  __shared__ float SO[192];
  __shared__ float part[96];
  __shared__ float M[NODES];
  __shared__ int order[8];
  __shared__ int sel[6];

  int g = blockIdx.x, t = threadIdx.x;
  for (int i=t; i<HID*HID; i+=256){ Wq[i]=wq[i]; Wo[i]=wo[i]; }
  for (int i=t; i<192*6;   i+=256){ Wfc[i]=wfc[i]; }
  {
    const f16x8* j8 = (const f16x8*)(jk + (size_t)g*NODES*HID);
    for (int i=t; i<NODES*HID/8; i+=256){     // 220 vectors of 8
      f16x8 v = j8[i];
      int node = i >> 2, c0 = (i & 3)*8;
      #pragma unroll
      for (int r=0;r<8;r++) H[node*33 + c0 + r] = selu_f((float)v[r]);
    }
  }
  if (t < NODES) M[t] = x[(size_t)(g*NODES+t)*INCH + (INCH-3)];
  __syncthreads();
  if (t == 0){
    int c = 0;
    for (int n=0;n<NODES;n++) if (M[n] > 0.5f && c < 6) order[c++] = n;
  }
  __syncthreads();
  if (t < 6) sel[t] = order[shuf[g*6 + t]];
  __syncthreads();

  // K and V: lane = node, wave-uniform output-channel group -> scalar weights
  {
    int k = t & 63;
    int ocg = __builtin_amdgcn_readfirstlane(t >> 6);   // 0..3, wave-uniform
    const float* wkp = wk + ocg*8;
    const float* wvp = wv + ocg*8;
    if (k < NODES){
      float ak[8], av[8];
      #pragma unroll
      for (int j=0;j<8;j++){ ak[j]=bk[ocg*8+j]; av[j]=bv[ocg*8+j]; }
      #pragma unroll
      for (int c=0;c<HID;c++){
        float hv = H[k*33+c];
        #pragma unroll
        for (int j=0;j<8;j++){
          ak[j] = fmaf(hv, wkp[c*HID+j], ak[j]);
          av[j] = fmaf(hv, wvp[c*HID+j], av[j]);
        }
      }
      #pragma unroll
      for (int j=0;j<8;j++){ K[k*33+ocg*8+j]=ak[j]; V[k*33+ocg*8+j]=av[j]; }
    }
  }
  // Q: 6 queries x 32 channels
  if (t < 192){
    int q = t>>5, oc = t&31;
    int node = sel[q];
    float a = bq[oc];
    #pragma unroll
    for (int c=0;c<HID;c++) a = fmaf(H[node*33+c], Wq[c*HID+oc], a);
    Qs[q*33+oc] = a;
  }
  __syncthreads();

  // scores = Q.K^T / sqrt(32)
  for (int idx=t; idx<6*NODES; idx+=256){
    int q = idx % 6, k = idx / 6;
    float a = 0.f;
    #pragma unroll
    for (int c=0;c<HID;c++) a = fmaf(Qs[q*33+c], K[k*33+c], a);
    S[q*56+k] = a * 0.17677669529663687f;
  }
  __syncthreads();

  // softmax over 55 keys: 32-lane group per query
  if (t < 192){
    int q = t>>5, l = t&31;
    float v0 = (l      < NODES) ? S[q*56+l]    : -1e30f;
    float v1 = (l+32   < NODES) ? S[q*56+l+32] : -1e30f;
    float mx = fmaxf(v0, v1);
    #pragma unroll
    for (int o=16;o>0;o>>=1) mx = fmaxf(mx, __shfl_xor(mx, o, 32));
    float p0 = (l    < NODES) ? __expf(v0-mx) : 0.f;
    float p1 = (l+32 < NODES) ? __expf(v1-mx) : 0.f;
    float sm = p0 + p1;
    #pragma unroll
    for (int o=16;o>0;o>>=1) sm += __shfl_xor(sm, o, 32);
    float inv = 1.f/sm;
    if (l    < NODES) S[q*56+l]    = p0*inv;
    if (l+32 < NODES) S[q*56+l+32] = p1*inv;
  }
  __syncthreads();

  // attn @ V
  if (t < 192){
    int q = t>>5, oc = t&31;
    float a = 0.f;
    for (int k=0;k<NODES;k++) a = fmaf(S[q*56+k], V[k*33+oc], a);
    O[q*33+oc] = a;
  }
  __syncthreads();

  // @ wo + bo, selu
  if (t < 192){
    int q = t>>5, oc = t&31;
    float a = bo[oc];
    #pragma unroll
    for (int c=0;c<HID;c++) a = fmaf(O[q*33+c], Wo[c*HID+oc], a);
    SO[t] = selu_f(a);   // t == q*32+oc == flat reshape index
  }
  __syncthreads();

  // final FC: 6 outputs = SO[192] . Wfc[:,j]
  if (t < 96){
    int j = t % 6, pp = t / 6;   // 16 partials per output
    float a = 0.f;
    #pragma unroll
    for (int r=0;r<12;r++) a = fmaf(SO[pp*12+r], Wfc[(pp*12+r)*6+j], a);
    part[pp*6+j] = a;
  }
  __syncthreads();
  if (t < 6){
    float a = bfc[t];
    #pragma unroll
    for (int pp=0;pp<16;pp++) a += part[pp*6+t];
    out[g*6+t] = a;
  }
}

extern "C" void kernel_launch(void* const* d_in, const int* in_sizes, int n_in,
                              void* d_out, int out_size, void* d_ws, size_t ws_size,
                              hipStream_t stream)
{
  const float* x   = (const float*)d_in[0];
  const int*   eix = (const int*)d_in[1];
  const int*   shf = (const int*)d_in[2];
  const float* wl0 = (const float*)d_in[3];
  const float* bl0 = (const float*)d_in[4];
  const float* wr0 = (const float*)d_in[5];
  const float* wl  = (const float*)d_in[6];
  const float* bl  = (const float*)d_in[7];
  const float* wr  = (const float*)d_in[8];
  const float* wq  = (const float*)d_in[9];
  const float* bq  = (const float*)d_in[10];
  const float* wk  = (const float*)d_in[11];
  const float* bk  = (const float*)d_in[12];
  const float* wv  = (const float*)d_in[13];
  const float* bv  = (const float*)d_in[14];
  const float* wo  = (const float*)d_in[15];
  const float* bo  = (const float*)d_in[16];
  const float* wfc = (const float*)d_in[17];
  const float* bfc = (const float*)d_in[18];
  float* out = (float*)d_out;

  const int* esrc = eix;
  const int* edst = eix + ETOT;

  // workspace carve
  char* p = (char*)d_ws;
  auto carve = [&](size_t bytes){ void* r = (void*)p; p += (bytes + 255) & ~(size_t)255; return r; };
  int*      off   = (int*)carve(sizeof(int)*(NTOT+1));
  int*      gcur  = (int*)carve(sizeof(int)*256);
  int*      bbase = (int*)carve(sizeof(int)*256);
  uint32_t* csrp  = (uint32_t*)carve(sizeof(uint32_t)*(size_t)ETOT);
  f16*      h_a   = (f16*)carve(2*(size_t)NTOT*HID);
  f16*      h_b   = (f16*)carve(2*(size_t)NTOT*HID);
  f16*      jk16  = (f16*)carve(2*(size_t)NTOT*HID);

  // aliases over dead regions:
  float*    xf     = (float*)h_b;       // padded x, dead after k_layer0
  uint32_t* binned = (uint32_t*)h_a;    // 220*17664*4 = 15.5MB <= 57.7MB, dead after k_bucket

  k_pad   <<<ETOT/256,  256, 0, stream>>>(x, xf, gcur);
  k_bin   <<<BINBLK, BINTH, 0, stream>>>(esrc, edst, gcur, binned);
  k_bscan <<<1,         256, 0, stream>>>(gcur, bbase);
  k_bucket<<<NBUCK,    1024, 0, stream>>>(binned, gcur, bbase, off, csrp);

  k_layer0<<<NTOT/NPB, 256, 0, stream>>>(xf, off, csrp, wl0, bl0, wr0, h_a, jk16);
  f16* hc = h_a; f16* hn = h_b;
  for (int l=0; l<4; l++){
    k_layer<<<NTOT/NPB, 256, 0, stream>>>(hc, off, csrp,
                                          wl + l*HID*HID, bl + l*HID, wr + l*HID*HID,
                                          hn, jk16);
    f16* tmp = hc; hc = hn; hn = tmp;
  }
  k_attn<<<BGRAPH, 256, 0, stream>>>(jk16, x, shf,
                                     wq, bq, wk, bk, wv, bv, wo, bo, wfc, bfc, out);
}

// Round 3
// 1635.950 us; speedup vs baseline: 2.3572x; 1.1439x over previous
//
#include <hip/hip_runtime.h>
#include <cstdint>
#include <cstddef>

#define NODES   55
#define BGRAPH  16384
#define NTOT    (BGRAPH*NODES)    // 901120
#define INCH    13
#define HID     32
#define ETOT    (4*NTOT)          // 3604480
#define NPB     128               // nodes per block (layer kernels)
#define ECAP    640               // LDS edge-list capacity in layer kernels

// ---- deterministic binned CSR build ----
#define NBUCK   220               // NTOT/4096 buckets
#define BSH     12                // 4096 nodes per bucket
#define BMSK    4095
#define NBLK    2048              // k_bin blocks
#define BCAP2   32                // slots per (bucket,block) segment; mean 8, +8.5 sigma
#define BINTH   256
#define BINGRP  (ETOT/4/NBLK)     // 440 int4-groups per block (exact)
#define OVFCAP  8192

typedef _Float16 f16;
typedef _Float16 f16x4 __attribute__((ext_vector_type(4))); // 8B
typedef _Float16 f16x8 __attribute__((ext_vector_type(8))); // 16B

__device__ __forceinline__ float selu_f(float v){
  const float s  = 1.0507009873554805f;
  const float sa = 1.7580993408473766f;   // scale*alpha
  return v > 0.f ? s*v : sa*(__expf(v)-1.f);
}

// ---------------- pad x[N,13] fp32 -> xf[N,16] fp32; zero overflow cursor ----------------
__global__ __launch_bounds__(256) void k_pad(const float* __restrict__ x,
                                             float* __restrict__ xf,
                                             int* __restrict__ ocnt){
  if (blockIdx.x == 0 && threadIdx.x == 0) *ocnt = 0;
  int i = blockIdx.x*256 + threadIdx.x;   // one float4 per thread, ETOT total (grid exact)
  int node = i>>2, q = i&3;
  const float* r = x + (size_t)node*INCH + q*4;
  float4 v;
  v.x = r[0];
  v.y = (q<3) ? r[1] : 0.f;
  v.z = (q<3) ? r[2] : 0.f;
  v.w = (q<3) ? r[3] : 0.f;
  ((float4*)xf)[i] = v;
}

// ---------------- phase A: bin edges into per-(bucket,block) segments, no global atomics ----------------
__global__ __launch_bounds__(BINTH) void k_bin(
    const int* __restrict__ src, const int* __restrict__ dst,
    uint32_t* __restrict__ binned, int* __restrict__ gcnt,
    uint2* __restrict__ ovf, int* __restrict__ ocnt)
{
  __shared__ int lcnt[NBUCK];
  int t = threadIdx.x, bid = blockIdx.x;
  for (int i=t;i<NBUCK;i+=BINTH) lcnt[i]=0;
  __syncthreads();
  const int4* s4 = (const int4*)src;
  const int4* d4 = (const int4*)dst;
  int g0 = bid*BINGRP;
  for (int i=t; i<BINGRP; i+=BINTH){
    int4 s = s4[g0+i];
    int4 d = d4[g0+i];
    #pragma unroll
    for (int j=0;j<4;j++){
      int dd = (&d.x)[j];
      int ss = (&s.x)[j];
      int b  = dd >> BSH;
      uint32_t entry = (uint32_t)ss | ((uint32_t)(dd & BMSK) << 20);
      int pos = atomicAdd(&lcnt[b], 1);
      if (pos < BCAP2) binned[((size_t)b*NBLK + bid)*BCAP2 + pos] = entry;
      else {                                  // ~1e-10/cell; correctness fallback
        int gp = atomicAdd(ocnt, 1);
        if (gp < OVFCAP) ovf[gp] = make_uint2(entry, (uint32_t)b);
      }
    }
  }
  __syncthreads();
  for (int i=t;i<NBUCK;i+=BINTH){
    int c = lcnt[i]; if (c > BCAP2) c = BCAP2;
    gcnt[bid*NBUCK + i] = c;                  // coalesced per-block row
  }
}

// ---------------- bucket totals (incl. overflow) ----------------
__global__ __launch_bounds__(256) void k_btot(const int* __restrict__ gcnt,
                                              const uint2* __restrict__ ovf,
                                              const int* __restrict__ ocnt,
                                              int* __restrict__ btot){
  __shared__ int sd[256];
  int b = blockIdx.x, t = threadIdx.x;
  int s = 0;
  for (int i=t;i<NBLK;i+=256) s += gcnt[i*NBUCK + b];
  int oc = *ocnt; if (oc > OVFCAP) oc = OVFCAP;
  for (int j=t;j<oc;j+=256) if (ovf[j].y == (uint32_t)b) s++;
  sd[t]=s; __syncthreads();
  for (int o=128;o>0;o>>=1){ if (t<o) sd[t]+=sd[t+o]; __syncthreads(); }
  if (t==0) btot[b]=sd[0];
}

// ---------------- exclusive scan of 220 bucket totals ----------------
__global__ __launch_bounds__(256) void k_bscan(const int* __restrict__ btot,
                                               int* __restrict__ bbase){
  __shared__ int sd[256];
  int t = threadIdx.x;
  int v = (t<NBUCK) ? btot[t] : 0;
  sd[t] = v; __syncthreads();
  for (int o=1;o<256;o<<=1){
    int u = (t>=o) ? sd[t-o] : 0;
    __syncthreads();
    sd[t] += u;
    __syncthreads();
  }
  if (t<NBUCK) bbase[t] = sd[t] - v;
}

// ---------------- phase B: per-bucket counting sort -> off + csrp (L2-local) ----------------
__global__ __launch_bounds__(1024) void k_bucket(
    const uint32_t* __restrict__ binned, const int* __restrict__ gcnt,
    const int* __restrict__ bbase,
    const uint2* __restrict__ ovf, const int* __restrict__ ocnt,
    int* __restrict__ off, uint32_t* __restrict__ csrp)
{
  __shared__ int hist[4096];   // degree counts -> scatter cursors
  __shared__ int cnts[NBLK];
  __shared__ int ws[1024];
  int b = blockIdx.x, t = threadIdx.x;
  int base = bbase[b];
  for (int i=t;i<NBLK;i+=1024) cnts[i] = gcnt[i*NBUCK + b];
  #pragma unroll
  for (int i=0;i<4;i++) hist[t+1024*i] = 0;
  int oc = *ocnt; if (oc > OVFCAP) oc = OVFCAP;
  __syncthreads();

  const uint4* bb4 = (const uint4*)(binned + (size_t)b*(NBLK*BCAP2));
  // pass 1: local-degree histogram
  for (int i=t; i<NBLK*BCAP2/4; i+=1024){
    uint4 e = bb4[i];
    int c = cnts[i>>3];
    int s0 = (i&7)*4;
    if (s0   < c) atomicAdd(&hist[(e.x>>20)&BMSK],1);
    if (s0+1 < c) atomicAdd(&hist[(e.y>>20)&BMSK],1);
    if (s0+2 < c) atomicAdd(&hist[(e.z>>20)&BMSK],1);
    if (s0+3 < c) atomicAdd(&hist[(e.w>>20)&BMSK],1);
  }
  for (int j=t;j<oc;j+=1024){
    uint2 pr = ovf[j];
    if (pr.y == (uint32_t)b) atomicAdd(&hist[(pr.x>>20)&BMSK],1);
  }
  __syncthreads();
  // exclusive scan of 4096 degrees
  int t4 = t*4;
  int s0=hist[t4], s1=hist[t4+1], s2=hist[t4+2], s3=hist[t4+3];
  int sum = s0+s1+s2+s3;
  ws[t] = sum; __syncthreads();
  for (int o=1;o<1024;o<<=1){
    int u = (t>=o) ? ws[t-o] : 0;
    __syncthreads();
    ws[t] += u;
    __syncthreads();
  }
  int ex = ws[t] - sum;
  int p0 = ex, p1 = ex+s0, p2 = ex+s0+s1, p3 = ex+s0+s1+s2;
  hist[t4]=p0; hist[t4+1]=p1; hist[t4+2]=p2; hist[t4+3]=p3;   // cursors
  int4 ov; ov.x = base+p0; ov.y = base+p1; ov.z = base+p2; ov.w = base+p3;
  ((int4*)(off + (b<<BSH)))[t] = ov;
  if (b == NBUCK-1 && t == 1023) off[NTOT] = ETOT;
  __syncthreads();
  // pass 2: scatter to final CSR (256KB window -> single-XCD L2 absorbs)
  for (int i=t; i<NBLK*BCAP2/4; i+=1024){
    uint4 e = bb4[i];
    int c = cnts[i>>3];
    int s0b = (i&7)*4;
    int p;
    if (s0b   < c){ p = atomicAdd(&hist[(e.x>>20)&BMSK],1); csrp[base+p] = e.x & 0xFFFFFu; }
    if (s0b+1 < c){ p = atomicAdd(&hist[(e.y>>20)&BMSK],1); csrp[base+p] = e.y & 0xFFFFFu; }
    if (s0b+2 < c){ p = atomicAdd(&hist[(e.z>>20)&BMSK],1); csrp[base+p] = e.z & 0xFFFFFu; }
    if (s0b+3 < c){ p = atomicAdd(&hist[(e.w>>20)&BMSK],1); csrp[base+p] = e.w & 0xFFFFFu; }
  }
  for (int j=t;j<oc;j+=1024){
    uint2 pr = ovf[j];
    if (pr.y == (uint32_t)b){
      int p = atomicAdd(&hist[(pr.x>>20)&BMSK],1);
      csrp[base+p] = pr.x & 0xFFFFFu;
    }
  }
}

// ---------------- fused SAGE layer 0 (node-owner register gather) ----------------
__global__ __launch_bounds__(256,8) void k_layer0(
    const float* __restrict__ xf,
    const int* __restrict__ off, const uint32_t* __restrict__ csrp,
    const float* __restrict__ wl0, const float* __restrict__ bl0,
    const float* __restrict__ wr0,
    f16* __restrict__ hout, f16* __restrict__ jkout)
{
  __shared__ float    AG0[NPB*17];      // 8704 B; aliased as f16 staging later
  __shared__ uint32_t EL[ECAP];         // 2560 B edge list
  __shared__ int      sOFF[NPB+2];      // 520 B
  int t = threadIdx.x;
  int base = blockIdx.x*NPB;
  int e0 = off[base];                   // uniform -> scalar load
  int e1 = off[base+NPB];
  for (int i=t; i<NPB+1; i+=256) sOFF[i] = off[base+i];
  int lim = (e1-e0) < ECAP ? (e1-e0) : ECAP;
  for (int i=t; i<lim; i+=256) EL[i] = csrp[e0+i];
  __syncthreads();

  // gather: 4 lanes per node (16B each), register accumulation, no atomics
  int c4 = t & 3;
  #pragma unroll
  for (int p=0;p<2;p++){
    int nl = p*64 + (t>>2);
    int s = sOFF[nl] - e0;
    int d = sOFF[nl+1] - sOFF[nl];
    float a0=0.f,a1=0.f,a2=0.f,a3=0.f;
    for (int i=0;i<d;i+=4){
      int j0 = s+i;
      bool q1=i+1<d, q2=i+2<d, q3=i+3<d;
      int j1=q1?j0+1:j0, j2=q2?j0+2:j0, j3=q3?j0+3:j0;
      uint32_t k0,k1,k2,k3;
      if (j0+3 < ECAP){ k0=EL[j0]; k1=EL[j1]; k2=EL[j2]; k3=EL[j3]; }
      else            { k0=csrp[e0+j0]; k1=csrp[e0+j1]; k2=csrp[e0+j2]; k3=csrp[e0+j3]; }
      float4 g0 = *((const float4*)(xf + (size_t)k0*16u) + c4);
      float4 g1 = *((const float4*)(xf + (size_t)k1*16u) + c4);
      float4 g2 = *((const float4*)(xf + (size_t)k2*16u) + c4);
      float4 g3 = *((const float4*)(xf + (size_t)k3*16u) + c4);
      a0 += (g0.x + (q1?g1.x:0.f)) + ((q2?g2.x:0.f) + (q3?g3.x:0.f));
      a1 += (g0.y + (q1?g1.y:0.f)) + ((q2?g2.y:0.f) + (q3?g3.y:0.f));
      a2 += (g0.z + (q1?g1.z:0.f)) + ((q2?g2.z:0.f) + (q3?g3.z:0.f));
      a3 += (g0.w + (q1?g1.w:0.f)) + ((q2?g2.w:0.f) + (q3?g3.w:0.f));
    }
    int di = nl*17 + 4*c4;
    AG0[di]=a0; AG0[di+1]=a1; AG0[di+2]=a2; AG0[di+3]=a3;
  }
  __syncthreads();

  // phase 2: node = base+(t&127), ochalf = t>>7 (wave-uniform -> scalar weights)
  int nl2 = t & 127;
  int node = base + nl2;
  int oc0 = __builtin_amdgcn_readfirstlane((t>>7)*16);
  int cnt = sOFF[nl2+1]-sOFF[nl2]; if (cnt<1) cnt=1;
  float inv = 1.f/(float)cnt;
  const float4* xr4 = (const float4*)(xf + (size_t)node*16);
  float4 X0=xr4[0], X1=xr4[1], X2=xr4[2];
  float x12 = ((const float*)(xr4+3))[0];
  float xc[13] = {X0.x,X0.y,X0.z,X0.w,X1.x,X1.y,X1.z,X1.w,X2.x,X2.y,X2.z,X2.w,x12};
  float acc[16];
  #pragma unroll
  for (int j=0;j<16;j++) acc[j] = bl0[oc0+j];
  #pragma unroll
  for (int cc=0;cc<INCH;cc++){
    float xcv = xc[cc];
    float mc = AG0[nl2*17+cc]*inv;
    #pragma unroll
    for (int j=0;j<16;j++)
      acc[j] = fmaf(xcv, wr0[cc*HID+oc0+j], fmaf(mc, wl0[cc*HID+oc0+j], acc[j]));
  }
  __syncthreads();                      // AG0 reads done -> safe to alias as staging
  f16* ST0 = (f16*)AG0;
  #pragma unroll
  for (int j=0;j<16;j++) ST0[nl2*34 + oc0 + j] = (f16)selu_f(acc[j]);
  __syncthreads();

  const uint32_t* STd = (const uint32_t*)AG0;
  uint4* ho4 = (uint4*)hout;
  uint4* jo4 = (uint4*)jkout;
  int gbase = blockIdx.x*(NPB*HID/8);   // 512 16B-chunks per block
  #pragma unroll
  for (int k=0;k<2;k++){
    int cch = t + 256*k;
    int n = cch>>2, m = cch&3;
    int dd = n*17 + m*4;
    uint4 u;
    u.x=STd[dd]; u.y=STd[dd+1]; u.z=STd[dd+2]; u.w=STd[dd+3];
    ho4[gbase+cch] = u;
    jo4[gbase+cch] = u;
  }
}

// ---------------- fused SAGE layers 1..4 (node-owner register gather) ----------------
__global__ __launch_bounds__(256,8) void k_layer(
    const f16* __restrict__ hin,
    const int* __restrict__ off, const uint32_t* __restrict__ csrp,
    const float* __restrict__ wl, const float* __restrict__ bl,
    const float* __restrict__ wr,
    f16* __restrict__ hout, f16* __restrict__ jkio)
{
  __shared__ float    AGf[NPB*33];      // 16896 B; aliased as f16 staging later
  __shared__ uint32_t EL[ECAP];         // 2560 B
  __shared__ int      sOFF[NPB+2];      // 520 B
  int t = threadIdx.x;
  int base = blockIdx.x*NPB;
  int e0 = off[base];
  int e1 = off[base+NPB];
  for (int i=t; i<NPB+1; i+=256) sOFF[i] = off[base+i];
  int lim = (e1-e0) < ECAP ? (e1-e0) : ECAP;
  for (int i=t; i<lim; i+=256) EL[i] = csrp[e0+i];
  __syncthreads();

  // gather: 4 lanes per node (f16x8 = 16B each), register accumulation, no atomics.
  int c4 = t & 3;
  #pragma unroll
  for (int p=0;p<2;p++){
    int nl = p*64 + (t>>2);
    int s = sOFF[nl] - e0;
    int d = sOFF[nl+1] - sOFF[nl];
    float a[8];
    #pragma unroll
    for (int r=0;r<8;r++) a[r] = 0.f;
    for (int i=0;i<d;i+=4){
      int j0 = s+i;
      bool q1=i+1<d, q2=i+2<d, q3=i+3<d;
      int j1=q1?j0+1:j0, j2=q2?j0+2:j0, j3=q3?j0+3:j0;
      uint32_t k0,k1,k2,k3;
      if (j0+3 < ECAP){ k0=EL[j0]; k1=EL[j1]; k2=EL[j2]; k3=EL[j3]; }
      else            { k0=csrp[e0+j0]; k1=csrp[e0+j1]; k2=csrp[e0+j2]; k3=csrp[e0+j3]; }
      f16x8 g0 = *((const f16x8*)(hin + (size_t)k0*32u) + c4);
      f16x8 g1 = *((const f16x8*)(hin + (size_t)k1*32u) + c4);
      f16x8 g2 = *((const f16x8*)(hin + (size_t)k2*32u) + c4);
      f16x8 g3 = *((const f16x8*)(hin + (size_t)k3*32u) + c4);
      #pragma unroll
      for (int r=0;r<8;r++){
        float s0=(float)g0[r];
        float s1=q1?(float)g1[r]:0.f;
        float s2=q2?(float)g2[r]:0.f;
        float s3=q3?(float)g3[r]:0.f;
        a[r] += (s0+s1)+(s2+s3);
      }
    }
    int di = nl*33 + 8*c4;
    #pragma unroll
    for (int r=0;r<8;r++) AGf[di+r] = a[r];
  }
  __syncthreads();

  // phase 2
  int nl2 = t & 127;
  int node = base + nl2;
  int oc0 = __builtin_amdgcn_readfirstlane((t>>7)*16);
  int cnt = sOFF[nl2+1]-sOFF[nl2]; if (cnt<1) cnt=1;
  float inv = 1.f/(float)cnt;
  const f16x8* h8 = (const f16x8*)(hin + (size_t)node*HID);
  float acc[16];
  #pragma unroll
  for (int j=0;j<16;j++) acc[j] = bl[oc0+j];
  #pragma unroll
  for (int jj=0;jj<4;jj++){
    f16x8 vh = h8[jj];
    #pragma unroll
    for (int r=0;r<8;r++){
      int cc = 8*jj+r;
      float hc = (float)vh[r];
      float mc = AGf[nl2*33+cc]*inv;
      #pragma unroll
      for (int j=0;j<16;j++)
        acc[j] = fmaf(hc, wr[cc*HID+oc0+j], fmaf(mc, wl[cc*HID+oc0+j], acc[j]));
    }
  }
  __syncthreads();   // all AGf reads done -> safe to alias as staging
  f16* ST = (f16*)AGf;
  #pragma unroll
  for (int j=0;j<16;j++) ST[nl2*34 + oc0 + j] = (f16)selu_f(acc[j]);
  __syncthreads();

  const uint32_t* STd = (const uint32_t*)AGf;
  uint4* ho4 = (uint4*)hout;
  uint4* jo4 = (uint4*)jkio;
  int gbase = blockIdx.x*(NPB*HID/8);
  #pragma unroll
  for (int k=0;k<2;k++){
    int cch = t + 256*k;
    int n = cch>>2, m = cch&3;
    int dd = n*17 + m*4;
    union { uint4 u; f16 hh[8]; } hv, jv;
    hv.u.x=STd[dd]; hv.u.y=STd[dd+1]; hv.u.z=STd[dd+2]; hv.u.w=STd[dd+3];
    jv.u = jo4[gbase+cch];
    #pragma unroll
    for (int r=0;r<8;r++){
      float a = (float)jv.hh[r], b = (float)hv.hh[r];
      jv.hh[r] = (f16)fmaxf(a, b);
    }
    ho4[gbase+cch] = hv.u;
    jo4[gbase+cch] = jv.u;
  }
}

// ---------------- attention + head, one block per graph ----------------
__global__ __launch_bounds__(256) void k_attn(
    const f16* __restrict__ jk, const float* __restrict__ x,
    const int* __restrict__ shuf,
    const float* __restrict__ wq, const float* __restrict__ bq,
    const float* __restrict__ wk, const float* __restrict__ bk,
    const float* __restrict__ wv, const float* __restrict__ bv,
    const float* __restrict__ wo, const float* __restrict__ bo,
    const float* __restrict__ wfc, const float* __restrict__ bfc,
    float* __restrict__ out)
{
  __shared__ float H[NODES*33];
  __shared__ float K[NODES*33];
  __shared__ float V[NODES*33];
  __shared__ float Wq[HID*HID];
  __shared__ float Wo[HID*HID];
  __shared__ float Wfc[192*6];
  __shared__ float Qs[6*33];
  __shared__ float S[6*56];
  __shared__ float O[6*33];
  __shared__ float SO[192];
  __shared__ float part[96];
  __shared__ float M[NODES];
  __shared__ int order[8];
  __shared__ int sel[6];

  int g = blockIdx.x, t = threadIdx.x;
  for (int i=t; i<HID*HID; i+=256){ Wq[i]=wq[i]; Wo[i]=wo[i]; }
  for (int i=t; i<192*6;   i+=256){ Wfc[i]=wfc[i]; }
  {
    const f16x8* j8 = (const f16x8*)(jk + (size_t)g*NODES*HID);
    for (int i=t; i<NODES*HID/8; i+=256){     // 220 vectors of 8
      f16x8 v = j8[i];
      int node = i >> 2, c0 = (i & 3)*8;
      #pragma unroll
      for (int r=0;r<8;r++) H[node*33 + c0 + r] = selu_f((float)v[r]);
    }
  }
  if (t < NODES) M[t] = x[(size_t)(g*NODES+t)*INCH + (INCH-3)];
  __syncthreads();
  if (t == 0){
    int c = 0;
    for (int n=0;n<NODES;n++) if (M[n] > 0.5f && c < 6) order[c++] = n;
  }
  __syncthreads();
  if (t < 6) sel[t] = order[shuf[g*6 + t]];
  __syncthreads();

  // K and V: lane = node, wave-uniform output-channel group -> scalar weights
  {
    int k = t & 63;
    int ocg = __builtin_amdgcn_readfirstlane(t >> 6);   // 0..3, wave-uniform
    const float* wkp = wk + ocg*8;
    const float* wvp = wv + ocg*8;
    if (k < NODES){
      float ak[8], av[8];
      #pragma unroll
      for (int j=0;j<8;j++){ ak[j]=bk[ocg*8+j]; av[j]=bv[ocg*8+j]; }
      #pragma unroll
      for (int c=0;c<HID;c++){
        float hv = H[k*33+c];
        #pragma unroll
        for (int j=0;j<8;j++){
          ak[j] = fmaf(hv, wkp[c*HID+j], ak[j]);
          av[j] = fmaf(hv, wvp[c*HID+j], av[j]);
        }
      }
      #pragma unroll
      for (int j=0;j<8;j++){ K[k*33+ocg*8+j]=ak[j]; V[k*33+ocg*8+j]=av[j]; }
    }
  }
  // Q: 6 queries x 32 channels
  if (t < 192){
    int q = t>>5, oc = t&31;
    int node = sel[q];
    float a = bq[oc];
    #pragma unroll
    for (int c=0;c<HID;c++) a = fmaf(H[node*33+c], Wq[c*HID+oc], a);
    Qs[q*33+oc] = a;
  }
  __syncthreads();

  // scores = Q.K^T / sqrt(32)
  for (int idx=t; idx<6*NODES; idx+=256){
    int q = idx % 6, k = idx / 6;
    float a = 0.f;
    #pragma unroll
    for (int c=0;c<HID;c++) a = fmaf(Qs[q*33+c], K[k*33+c], a);
    S[q*56+k] = a * 0.17677669529663687f;
  }
  __syncthreads();

  // softmax over 55 keys: 32-lane group per query
  if (t < 192){
    int q = t>>5, l = t&31;
    float v0 = (l      < NODES) ? S[q*56+l]    : -1e30f;
    float v1 = (l+32   < NODES) ? S[q*56+l+32] : -1e30f;
    float mx = fmaxf(v0, v1);
    #pragma unroll
    for (int o=16;o>0;o>>=1) mx = fmaxf(mx, __shfl_xor(mx, o, 32));
    float p0 = (l    < NODES) ? __expf(v0-mx) : 0.f;
    float p1 = (l+32 < NODES) ? __expf(v1-mx) : 0.f;
    float sm = p0 + p1;
    #pragma unroll
    for (int o=16;o>0;o>>=1) sm += __shfl_xor(sm, o, 32);
    float inv = 1.f/sm;
    if (l    < NODES) S[q*56+l]    = p0*inv;
    if (l+32 < NODES) S[q*56+l+32] = p1*inv;
  }
  __syncthreads();

  // attn @ V
  if (t < 192){
    int q = t>>5, oc = t&31;
    float a = 0.f;
    for (int k=0;k<NODES;k++) a = fmaf(S[q*56+k], V[k*33+oc], a);
    O[q*33+oc] = a;
  }
  __syncthreads();

  // @ wo + bo, selu
  if (t < 192){
    int q = t>>5, oc = t&31;
    float a = bo[oc];
    #pragma unroll
    for (int c=0;c<HID;c++) a = fmaf(O[q*33+c], Wo[c*HID+oc], a);
    SO[t] = selu_f(a);   // t == q*32+oc == flat reshape index
  }
  __syncthreads();

  // final FC: 6 outputs = SO[192] . Wfc[:,j]
  if (t < 96){
    int j = t % 6, pp = t / 6;   // 16 partials per output
    float a = 0.f;
    #pragma unroll
    for (int r=0;r<12;r++) a = fmaf(SO[pp*12+r], Wfc[(pp*12+r)*6+j], a);
    part[pp*6+j] = a;
  }
  __syncthreads();
  if (t < 6){
    float a = bfc[t];
    #pragma unroll
    for (int pp=0;pp<16;pp++) a += part[pp*6+t];
    out[g*6+t] = a;
  }
}

extern "C" void kernel_launch(void* const* d_in, const int* in_sizes, int n_in,
                              void* d_out, int out_size, void* d_ws, size_t ws_size,
                              hipStream_t stream)
{
  const float* x   = (const float*)d_in[0];
  const int*   eix = (const int*)d_in[1];
  const int*   shf = (const int*)d_in[2];
  const float* wl0 = (const float*)d_in[3];
  const float* bl0 = (const float*)d_in[4];
  const float* wr0 = (const float*)d_in[5];
  const float* wl  = (const float*)d_in[6];
  const float* bl  = (const float*)d_in[7];
  const float* wr  = (const float*)d_in[8];
  const float* wq  = (const float*)d_in[9];
  const float* bq  = (const float*)d_in[10];
  const float* wk  = (const float*)d_in[11];
  const float* bk  = (const float*)d_in[12];
  const float* wv  = (const float*)d_in[13];
  const float* bv  = (const float*)d_in[14];
  const float* wo  = (const float*)d_in[15];
  const float* bo  = (const float*)d_in[16];
  const float* wfc = (const float*)d_in[17];
  const float* bfc = (const float*)d_in[18];
  float* out = (float*)d_out;

  const int* esrc = eix;
  const int* edst = eix + ETOT;

  // workspace carve
  char* p = (char*)d_ws;
  auto carve = [&](size_t bytes){ void* r = (void*)p; p += (bytes + 255) & ~(size_t)255; return r; };
  int*      off   = (int*)carve(sizeof(int)*(NTOT+1));
  int*      gcnt  = (int*)carve(sizeof(int)*(size_t)NBLK*NBUCK);   // 1.8 MB
  int*      btot  = (int*)carve(sizeof(int)*256);
  int*      bbase = (int*)carve(sizeof(int)*256);
  uint2*    ovf   = (uint2*)carve(sizeof(uint2)*OVFCAP);
  int*      ocnt  = (int*)carve(sizeof(int)*64);
  uint32_t* csrp  = (uint32_t*)carve(sizeof(uint32_t)*(size_t)ETOT);
  f16*      h_a   = (f16*)carve(2*(size_t)NTOT*HID);
  f16*      h_b   = (f16*)carve(2*(size_t)NTOT*HID);
  f16*      jk16  = (f16*)carve(2*(size_t)NTOT*HID);

  // aliases over dead regions:
  float*    xf     = (float*)h_b;       // padded x, dead after k_layer0
  uint32_t* binned = (uint32_t*)h_a;    // 220*2048*32*4 = 57.7MB == h_a, dead after k_bucket

  k_pad   <<<ETOT/256,  256, 0, stream>>>(x, xf, ocnt);
  k_bin   <<<NBLK,    BINTH, 0, stream>>>(esrc, edst, binned, gcnt, ovf, ocnt);
  k_btot  <<<NBUCK,     256, 0, stream>>>(gcnt, ovf, ocnt, btot);
  k_bscan <<<1,         256, 0, stream>>>(btot, bbase);
  k_bucket<<<NBUCK,    1024, 0, stream>>>(binned, gcnt, bbase, ovf, ocnt, off, csrp);

  k_layer0<<<NTOT/NPB, 256, 0, stream>>>(xf, off, csrp, wl0, bl0, wr0, h_a, jk16);
  f16* hc = h_a; f16* hn = h_b;
  for (int l=0; l<4; l++){
    k_layer<<<NTOT/NPB, 256, 0, stream>>>(hc, off, csrp,
                                          wl + l*HID*HID, bl + l*HID, wr + l*HID*HID,
                                          hn, jk16);
    f16* tmp = hc; hc = hn; hn = tmp;
  }
  k_attn<<<BGRAPH, 256, 0, stream>>>(jk16, x, shf,
                                     wq, bq, wk, bk, wv, bv, wo, bo, wfc, bfc, out);
}

// Round 5
// 940.136 us; speedup vs baseline: 4.1018x; 1.7401x over previous
//
#include <hip/hip_runtime.h>
#include <cstdint>
#include <cstddef>

#define NODES   55
#define BGRAPH  16384
#define NTOT    (BGRAPH*NODES)    // 901120
#define INCH    13
#define HID     32
#define ETOT    (4*NTOT)          // 3604480
#define NPB     128               // nodes per block (layer kernels)
#define ECAP    768               // LDS edge-list capacity (mean 512, +11 sigma; global fallback)
#define ZN      NTOT              // dummy zero-row index for masked edge slots

// ---- deterministic binned CSR build ----
#define NBUCK   220               // NTOT/4096 buckets
#define BSH     12                // 4096 nodes per bucket
#define BMSK    4095
#define NBLK    2048              // k_bin blocks
#define BCAP2   32                // slots per (bucket,block) segment; mean 8, +8.5 sigma
#define BINTH   256
#define BINGRP  (ETOT/4/NBLK)     // 440 int4-groups per block (exact)
#define OVFCAP  8192

// ---- MFMA staging ----
#define ASTR    72                // A row stride (f16): 144B rows (16B-aligned)
#define BSTR    72
#define ASTR0   40                // layer0 A/B stride (f16): 80B rows

typedef _Float16 f16;
typedef _Float16 f16x4 __attribute__((ext_vector_type(4))); // 8B
typedef _Float16 f16x8 __attribute__((ext_vector_type(8))); // 16B
typedef float    f32x4 __attribute__((ext_vector_type(4)));

__device__ __forceinline__ float selu_f(float v){
  const float s  = 1.0507009873554805f;
  const float sa = 1.7580993408473766f;   // scale*alpha
  return v > 0.f ? s*v : sa*(__expf(v)-1.f);
}

// ---------------- pad x[N,13] fp32 -> xf[N,16] fp32; zero dummy rows + ovf cursor ----------------
__global__ __launch_bounds__(256) void k_pad(const float* __restrict__ x,
                                             float* __restrict__ xf,
                                             uint32_t* __restrict__ ha32,
                                             int* __restrict__ ocnt){
  if (blockIdx.x == 0){
    int t = threadIdx.x;
    if (t == 0) *ocnt = 0;
    if (t < 16)            xf[(size_t)ZN*16 + t] = 0.f;       // zero row of xf (== h_b row ZN)
    if (t >= 16 && t < 32) ha32[(size_t)ZN*16 + (t-16)] = 0u; // zero row of h_a
  }
  int i = blockIdx.x*256 + threadIdx.x;   // one float4 per thread, ETOT total (grid exact)
  int node = i>>2, q = i&3;
  const float* r = x + (size_t)node*INCH + q*4;
  float4 v;
  v.x = r[0];
  v.y = (q<3) ? r[1] : 0.f;
  v.z = (q<3) ? r[2] : 0.f;
  v.w = (q<3) ? r[3] : 0.f;
  ((float4*)xf)[i] = v;
}

// ---------------- weight prep: concat+transpose to f16 once ----------------
// wcp layout: [0,1024)            = B0^T[32 oc][32 k]  (k<13: wl0, 16..28: wr0, else 0)
//             [1024 + l*2048 ...) = Bl^T[32 oc][64 k]  (k<32: wl[l], else wr[l])
__global__ __launch_bounds__(256) void k_wprep(
    const float* __restrict__ wl0, const float* __restrict__ wr0,
    const float* __restrict__ wl,  const float* __restrict__ wr,
    f16* __restrict__ wcp)
{
  int t = threadIdx.x;
  for (int i=t; i<1024; i+=256){
    int oc = i>>5, k = i&31;
    float v = 0.f;
    if (k < 13)                 v = wl0[k*HID + oc];
    else if (k >= 16 && k < 29) v = wr0[(k-16)*HID + oc];
    wcp[oc*32 + k] = (f16)v;
  }
  for (int i=t; i<4*2048; i+=256){
    int l = i>>11, r = i&2047, oc = r>>6, k = r&63;
    float v = (k<32) ? wl[l*1024 + k*HID + oc] : wr[l*1024 + (k-32)*HID + oc];
    wcp[1024 + l*2048 + oc*64 + k] = (f16)v;
  }
}

// ---------------- phase A: bin edges into per-(bucket,block) segments, no global atomics ----------------
__global__ __launch_bounds__(BINTH) void k_bin(
    const int* __restrict__ src, const int* __restrict__ dst,
    uint32_t* __restrict__ binned, int* __restrict__ gcnt,
    uint2* __restrict__ ovf, int* __restrict__ ocnt)
{
  __shared__ int lcnt[NBUCK];
  int t = threadIdx.x, bid = blockIdx.x;
  for (int i=t;i<NBUCK;i+=BINTH) lcnt[i]=0;
  __syncthreads();
  const int4* s4 = (const int4*)src;
  const int4* d4 = (const int4*)dst;
  int g0 = bid*BINGRP;
  for (int i=t; i<BINGRP; i+=BINTH){
    int4 s = s4[g0+i];
    int4 d = d4[g0+i];
    #pragma unroll
    for (int j=0;j<4;j++){
      int dd = (&d.x)[j];
      int ss = (&s.x)[j];
      int b  = dd >> BSH;
      uint32_t entry = (uint32_t)ss | ((uint32_t)(dd & BMSK) << 20);
      int pos = atomicAdd(&lcnt[b], 1);
      if (pos < BCAP2) binned[((size_t)b*NBLK + bid)*BCAP2 + pos] = entry;
      else {                                  // ~1e-10/cell; correctness fallback
        int gp = atomicAdd(ocnt, 1);
        if (gp < OVFCAP) ovf[gp] = make_uint2(entry, (uint32_t)b);
      }
    }
  }
  __syncthreads();
  for (int i=t;i<NBUCK;i+=BINTH){
    int c = lcnt[i]; if (c > BCAP2) c = BCAP2;
    gcnt[bid*NBUCK + i] = c;                  // coalesced per-block row
  }
}

// ---------------- bucket totals (incl. overflow) ----------------
__global__ __launch_bounds__(256) void k_btot(const int* __restrict__ gcnt,
                                              const uint2* __restrict__ ovf,
                                              const int* __restrict__ ocnt,
                                              int* __restrict__ btot){
  __shared__ int sd[256];
  int b = blockIdx.x, t = threadIdx.x;
  int s = 0;
  for (int i=t;i<NBLK;i+=256) s += gcnt[i*NBUCK + b];
  int oc = *ocnt; if (oc > OVFCAP) oc = OVFCAP;
  for (int j=t;j<oc;j+=256) if (ovf[j].y == (uint32_t)b) s++;
  sd[t]=s; __syncthreads();
  for (int o=128;o>0;o>>=1){ if (t<o) sd[t]+=sd[t+o]; __syncthreads(); }
  if (t==0) btot[b]=sd[0];
}

// ---------------- exclusive scan of 220 bucket totals ----------------
__global__ __launch_bounds__(256) void k_bscan(const int* __restrict__ btot,
                                               int* __restrict__ bbase){
  __shared__ int sd[256];
  int t = threadIdx.x;
  int v = (t<NBUCK) ? btot[t] : 0;
  sd[t] = v; __syncthreads();
  for (int o=1;o<256;o<<=1){
    int u = (t>=o) ? sd[t-o] : 0;
    __syncthreads();
    sd[t] += u;
    __syncthreads();
  }
  if (t<NBUCK) bbase[t] = sd[t] - v;
}

// ---------------- phase B: per-bucket counting sort -> off + csrp (L2-local) ----------------
__global__ __launch_bounds__(1024) void k_bucket(
    const uint32_t* __restrict__ binned, const int* __restrict__ gcnt,
    const int* __restrict__ bbase,
    const uint2* __restrict__ ovf, const int* __restrict__ ocnt,
    int* __restrict__ off, uint32_t* __restrict__ csrp)
{
  __shared__ int hist[4096];   // degree counts -> scatter cursors
  __shared__ int cnts[NBLK];
  __shared__ int ws[1024];
  int b = blockIdx.x, t = threadIdx.x;
  int base = bbase[b];
  for (int i=t;i<NBLK;i+=1024) cnts[i] = gcnt[i*NBUCK + b];
  #pragma unroll
  for (int i=0;i<4;i++) hist[t+1024*i] = 0;
  int oc = *ocnt; if (oc > OVFCAP) oc = OVFCAP;
  __syncthreads();

  const uint4* bb4 = (const uint4*)(binned + (size_t)b*(NBLK*BCAP2));
  // pass 1: local-degree histogram
  for (int i=t; i<NBLK*BCAP2/4; i+=1024){
    uint4 e = bb4[i];
    int c = cnts[i>>3];
    int s0 = (i&7)*4;
    if (s0   < c) atomicAdd(&hist[(e.x>>20)&BMSK],1);
    if (s0+1 < c) atomicAdd(&hist[(e.y>>20)&BMSK],1);
    if (s0+2 < c) atomicAdd(&hist[(e.z>>20)&BMSK],1);
    if (s0+3 < c) atomicAdd(&hist[(e.w>>20)&BMSK],1);
  }
  for (int j=t;j<oc;j+=1024){
    uint2 pr = ovf[j];
    if (pr.y == (uint32_t)b) atomicAdd(&hist[(pr.x>>20)&BMSK],1);
  }
  __syncthreads();
  // exclusive scan of 4096 degrees
  int t4 = t*4;
  int s0=hist[t4], s1=hist[t4+1], s2=hist[t4+2], s3=hist[t4+3];
  int sum = s0+s1+s2+s3;
  ws[t] = sum; __syncthreads();
  for (int o=1;o<1024;o<<=1){
    int u = (t>=o) ? ws[t-o] : 0;
    __syncthreads();
    ws[t] += u;
    __syncthreads();
  }
  int ex = ws[t] - sum;
  int p0 = ex, p1 = ex+s0, p2 = ex+s0+s1, p3 = ex+s0+s1+s2;
  hist[t4]=p0; hist[t4+1]=p1; hist[t4+2]=p2; hist[t4+3]=p3;   // cursors
  int4 ov; ov.x = base+p0; ov.y = base+p1; ov.z = base+p2; ov.w = base+p3;
  ((int4*)(off + (b<<BSH)))[t] = ov;
  if (b == NBUCK-1 && t == 1023) off[NTOT] = ETOT;
  __syncthreads();
  // pass 2: scatter to final CSR (256KB window -> single-XCD L2 absorbs)
  for (int i=t; i<NBLK*BCAP2/4; i+=1024){
    uint4 e = bb4[i];
    int c = cnts[i>>3];
    int s0b = (i&7)*4;
    int p;
    if (s0b   < c){ p = atomicAdd(&hist[(e.x>>20)&BMSK],1); csrp[base+p] = e.x & 0xFFFFFu; }
    if (s0b+1 < c){ p = atomicAdd(&hist[(e.y>>20)&BMSK],1); csrp[base+p] = e.y & 0xFFFFFu; }
    if (s0b+2 < c){ p = atomicAdd(&hist[(e.z>>20)&BMSK],1); csrp[base+p] = e.z & 0xFFFFFu; }
    if (s0b+3 < c){ p = atomicAdd(&hist[(e.w>>20)&BMSK],1); csrp[base+p] = e.w & 0xFFFFFu; }
  }
  for (int j=t;j<oc;j+=1024){
    uint2 pr = ovf[j];
    if (pr.y == (uint32_t)b){
      int p = atomicAdd(&hist[(pr.x>>20)&BMSK],1);
      csrp[base+p] = pr.x & 0xFFFFFu;
    }
  }
}

// ---------------- fused SAGE layer 0 (gather + MFMA, K=32) ----------------
__global__ __launch_bounds__(256,8) void k_layer0(
    const float* __restrict__ xf,
    const int* __restrict__ off, const uint32_t* __restrict__ csrp,
    const f16* __restrict__ wcat0, const float* __restrict__ bl0,
    f16* __restrict__ hout, f16* __restrict__ jkout)
{
  __shared__ uint32_t ALDS[NPB*(ASTR0/2)];   // 10240B: A[128][40] f16 = [mean16|x16]; reused as ST
  __shared__ uint32_t BLDS[32*(ASTR0/2)];    // 2560B:  B0^T[32][40] f16
  __shared__ uint32_t EL[ECAP];              // 3072B
  __shared__ int      sOFF[NPB+2];
  __shared__ float    biasL[32];
  int t = threadIdx.x;
  int base = blockIdx.x*NPB;
  int e0 = off[base];
  int e1 = off[base+NPB];
  for (int i=t; i<NPB+1; i+=256) sOFF[i] = off[base+i];
  {
    int lim = (e1-e0) < ECAP ? (e1-e0) : ECAP;
    for (int i=t; i<lim; i+=256) EL[i] = csrp[e0+i];
  }
  if (t < 128){
    int oc = t>>2, kq = (t&3)*8;
    f16x8 wv = *(const f16x8*)(wcat0 + oc*32 + kq);
    *(f16x8*)((f16*)BLDS + oc*ASTR0 + kq) = wv;
  }
  if (t < 32) biasL[t] = bl0[t];
  __syncthreads();   // staging (sOFF/EL/BLDS/bias) visible before gather reads  [R4 crash fix]

  // gather: 4 lanes per node (float4 = 4 ch each); masked slots -> zero row ZN
  int c4 = t & 3;
  #pragma unroll
  for (int p=0;p<2;p++){
    int nl = p*64 + (t>>2);
    int node = base + nl;
    float4 xown = *((const float4*)(xf + (size_t)node*16) + c4);
    int s = sOFF[nl] - e0;
    int d = sOFF[nl+1] - sOFF[nl];
    float a0=0.f,a1=0.f,a2=0.f,a3=0.f;
    for (int i=0;i<d;i+=4){
      int j0 = s+i;
      uint32_t k0,k1,k2,k3;
      if (j0+3 < ECAP){ k0=EL[j0]; k1=EL[j0+1]; k2=EL[j0+2]; k3=EL[j0+3]; }
      else            { k0=csrp[e0+j0]; k1=csrp[e0+j0+1]; k2=csrp[e0+j0+2]; k3=csrp[e0+j0+3]; }
      k1 = (i+1<d)?k1:(uint32_t)ZN;
      k2 = (i+2<d)?k2:(uint32_t)ZN;
      k3 = (i+3<d)?k3:(uint32_t)ZN;
      float4 g0 = *((const float4*)(xf + (size_t)k0*16u) + c4);
      float4 g1 = *((const float4*)(xf + (size_t)k1*16u) + c4);
      float4 g2 = *((const float4*)(xf + (size_t)k2*16u) + c4);
      float4 g3 = *((const float4*)(xf + (size_t)k3*16u) + c4);
      a0 += (g0.x+g1.x)+(g2.x+g3.x);
      a1 += (g0.y+g1.y)+(g2.y+g3.y);
      a2 += (g0.z+g1.z)+(g2.z+g3.z);
      a3 += (g0.w+g1.w)+(g2.w+g3.w);
    }
    float inv = 1.f/(float)(d<1?1:d);
    union { f16 h[4]; uint32_t u[2]; } mp, xp;
    mp.h[0]=(f16)(a0*inv); mp.h[1]=(f16)(a1*inv); mp.h[2]=(f16)(a2*inv); mp.h[3]=(f16)(a3*inv);
    xp.h[0]=(f16)xown.x;   xp.h[1]=(f16)xown.y;   xp.h[2]=(f16)xown.z;   xp.h[3]=(f16)xown.w;
    uint32_t* arow = &ALDS[nl*(ASTR0/2)];
    *((uint2*)&arow[2*c4])     = make_uint2(mp.u[0], mp.u[1]);   // mean cols 4c4..
    *((uint2*)&arow[8 + 2*c4]) = make_uint2(xp.u[0], xp.u[1]);   // x cols 16+4c4..
  }
  __syncthreads();

  // MFMA: wave w owns rows 32w..32w+31, cols 0..31; single K=32 step
  int w = t>>6, l = t&63;
  int lrow = l&15, lg = l>>4;
  const f16* Af = (const f16*)ALDS;
  const f16* Bf = (const f16*)BLDS;
  f32x4 D00={0.f,0.f,0.f,0.f}, D01=D00, D10=D00, D11=D00;
  {
    f16x8 af0 = *(const f16x8*)(Af + (32*w+lrow)*ASTR0    + 8*lg);
    f16x8 af1 = *(const f16x8*)(Af + (32*w+16+lrow)*ASTR0 + 8*lg);
    f16x8 bf0 = *(const f16x8*)(Bf + lrow*ASTR0           + 8*lg);
    f16x8 bf1 = *(const f16x8*)(Bf + (16+lrow)*ASTR0      + 8*lg);
    D00 = __builtin_amdgcn_mfma_f32_16x16x32_f16(af0, bf0, D00, 0,0,0);
    D01 = __builtin_amdgcn_mfma_f32_16x16x32_f16(af0, bf1, D01, 0,0,0);
    D10 = __builtin_amdgcn_mfma_f32_16x16x32_f16(af1, bf0, D10, 0,0,0);
    D11 = __builtin_amdgcn_mfma_f32_16x16x32_f16(af1, bf1, D11, 0,0,0);
  }
  __syncthreads();       // all frag reads done -> ALDS reusable as ST

  f16* ST = (f16*)ALDS;  // [128][34] f16 staging
  #pragma unroll
  for (int j=0;j<4;j++){
    int r0 = 32*w + 4*lg + j, r1 = r0 + 16;
    ST[r0*34 + lrow]      = (f16)selu_f(D00[j] + biasL[lrow]);
    ST[r0*34 + 16 + lrow] = (f16)selu_f(D01[j] + biasL[16+lrow]);
    ST[r1*34 + lrow]      = (f16)selu_f(D10[j] + biasL[lrow]);
    ST[r1*34 + 16 + lrow] = (f16)selu_f(D11[j] + biasL[16+lrow]);
  }
  __syncthreads();

  const uint32_t* STd = (const uint32_t*)ALDS;
  uint4* ho4 = (uint4*)hout;
  uint4* jo4 = (uint4*)jkout;
  int gbase = blockIdx.x*(NPB*HID/8);   // 512 16B-chunks per block
  #pragma unroll
  for (int k=0;k<2;k++){
    int cch = t + 256*k;
    int n = cch>>2, m = cch&3;
    int dd = n*17 + m*4;
    uint4 u;
    u.x=STd[dd]; u.y=STd[dd+1]; u.z=STd[dd+2]; u.w=STd[dd+3];
    ho4[gbase+cch] = u;
    jo4[gbase+cch] = u;
  }
}

// ---------------- fused SAGE layers 1..4 (gather + MFMA, K=64) ----------------
__global__ __launch_bounds__(256,6) void k_layer(
    const f16* __restrict__ hin,
    const int* __restrict__ off, const uint32_t* __restrict__ csrp,
    const f16* __restrict__ wcat, const float* __restrict__ bl,
    f16* __restrict__ hout, f16* __restrict__ jkio)
{
  __shared__ uint32_t ALDS[NPB*(ASTR/2)];    // 18432B: A[128][72] f16 = [mean32|h32]; reused as ST
  __shared__ uint32_t BLDS[32*(BSTR/2)];     // 4608B:  B^T[32][72] f16
  __shared__ uint32_t EL[ECAP];              // 3072B
  __shared__ int      sOFF[NPB+2];
  __shared__ float    biasL[32];
  int t = threadIdx.x;
  int base = blockIdx.x*NPB;
  int e0 = off[base];
  int e1 = off[base+NPB];
  for (int i=t; i<NPB+1; i+=256) sOFF[i] = off[base+i];
  {
    int lim = (e1-e0) < ECAP ? (e1-e0) : ECAP;
    for (int i=t; i<lim; i+=256) EL[i] = csrp[e0+i];
  }
  if (t < 128){
    int oc = t>>2, kq = (t&3)*8;               // 4 chunks of 8 f16 per row
    f16x8 wv0 = *(const f16x8*)(wcat + oc*64 + kq);
    f16x8 wv1 = *(const f16x8*)(wcat + oc*64 + 32 + kq);
    *(f16x8*)((f16*)BLDS + oc*BSTR + kq)      = wv0;
    *(f16x8*)((f16*)BLDS + oc*BSTR + 32 + kq) = wv1;
  }
  if (t < 32) biasL[t] = bl[t];
  __syncthreads();   // staging (sOFF/EL/BLDS/bias) visible before gather reads  [R4 crash fix]

  // gather: 4 lanes per node (f16x8 = 8 ch each); masked slots -> zero row ZN
  int c4 = t & 3;
  #pragma unroll
  for (int p=0;p<2;p++){
    int nl = p*64 + (t>>2);
    int node = base + nl;
    f16x8 hown = *(const f16x8*)(hin + (size_t)node*HID + 8u*c4);
    int s = sOFF[nl] - e0;
    int d = sOFF[nl+1] - sOFF[nl];
    float a[8];
    #pragma unroll
    for (int r=0;r<8;r++) a[r]=0.f;
    for (int i=0;i<d;i+=4){
      int j0 = s+i;
      uint32_t k0,k1,k2,k3;
      if (j0+3 < ECAP){ k0=EL[j0]; k1=EL[j0+1]; k2=EL[j0+2]; k3=EL[j0+3]; }
      else            { k0=csrp[e0+j0]; k1=csrp[e0+j0+1]; k2=csrp[e0+j0+2]; k3=csrp[e0+j0+3]; }
      k1 = (i+1<d)?k1:(uint32_t)ZN;
      k2 = (i+2<d)?k2:(uint32_t)ZN;
      k3 = (i+3<d)?k3:(uint32_t)ZN;
      f16x8 g0 = *((const f16x8*)(hin + (size_t)k0*32u) + c4);
      f16x8 g1 = *((const f16x8*)(hin + (size_t)k1*32u) + c4);
      f16x8 g2 = *((const f16x8*)(hin + (size_t)k2*32u) + c4);
      f16x8 g3 = *((const f16x8*)(hin + (size_t)k3*32u) + c4);
      #pragma unroll
      for (int r=0;r<8;r++)
        a[r] += ((float)g0[r]+(float)g1[r]) + ((float)g2[r]+(float)g3[r]);
    }
    float inv = 1.f/(float)(d<1?1:d);
    union { f16 h[8]; uint4 v; } mp;
    #pragma unroll
    for (int r=0;r<8;r++) mp.h[r] = (f16)(a[r]*inv);
    uint32_t* arow = &ALDS[nl*(ASTR/2)];
    *((uint4*)&arow[4*c4]) = mp.v;                          // mean cols 8c4..
    *((f16x8*)((f16*)arow + 32 + 8*c4)) = hown;             // h cols 32+8c4..
  }
  __syncthreads();

  // MFMA: wave w owns rows 32w..32w+31, cols 0..31; two K=32 steps
  int w = t>>6, l = t&63;
  int lrow = l&15, lg = l>>4;
  const f16* Af = (const f16*)ALDS;
  const f16* Bf = (const f16*)BLDS;
  f32x4 D00={0.f,0.f,0.f,0.f}, D01=D00, D10=D00, D11=D00;
  #pragma unroll
  for (int s2=0;s2<2;s2++){
    f16x8 af0 = *(const f16x8*)(Af + (32*w+lrow)*ASTR    + 32*s2 + 8*lg);
    f16x8 af1 = *(const f16x8*)(Af + (32*w+16+lrow)*ASTR + 32*s2 + 8*lg);
    f16x8 bf0 = *(const f16x8*)(Bf + lrow*BSTR           + 32*s2 + 8*lg);
    f16x8 bf1 = *(const f16x8*)(Bf + (16+lrow)*BSTR      + 32*s2 + 8*lg);
    D00 = __builtin_amdgcn_mfma_f32_16x16x32_f16(af0, bf0, D00, 0,0,0);
    D01 = __builtin_amdgcn_mfma_f32_16x16x32_f16(af0, bf1, D01, 0,0,0);
    D10 = __builtin_amdgcn_mfma_f32_16x16x32_f16(af1, bf0, D10, 0,0,0);
    D11 = __builtin_amdgcn_mfma_f32_16x16x32_f16(af1, bf1, D11, 0,0,0);
  }
  __syncthreads();       // all frag reads done -> ALDS reusable as ST

  f16* ST = (f16*)ALDS;  // [128][34] f16 staging
  #pragma unroll
  for (int j=0;j<4;j++){
    int r0 = 32*w + 4*lg + j, r1 = r0 + 16;
    ST[r0*34 + lrow]      = (f16)selu_f(D00[j] + biasL[lrow]);
    ST[r0*34 + 16 + lrow] = (f16)selu_f(D01[j] + biasL[16+lrow]);
    ST[r1*34 + lrow]      = (f16)selu_f(D10[j] + biasL[lrow]);
    ST[r1*34 + 16 + lrow] = (f16)selu_f(D11[j] + biasL[16+lrow]);
  }
  __syncthreads();

  const uint32_t* STd = (const uint32_t*)ALDS;
  uint4* ho4 = (uint4*)hout;
  uint4* jo4 = (uint4*)jkio;
  int gbase = blockIdx.x*(NPB*HID/8);
  #pragma unroll
  for (int k=0;k<2;k++){
    int cch = t + 256*k;
    int n = cch>>2, m = cch&3;
    int dd = n*17 + m*4;
    union { uint4 u; f16 hh[8]; } hv, jv;
    hv.u.x=STd[dd]; hv.u.y=STd[dd+1]; hv.u.z=STd[dd+2]; hv.u.w=STd[dd+3];
    jv.u = jo4[gbase+cch];
    #pragma unroll
    for (int r=0;r<8;r++){
      float a = (float)jv.hh[r], b = (float)hv.hh[r];
      jv.hh[r] = (f16)fmaxf(a, b);
    }
    ho4[gbase+cch] = hv.u;
    jo4[gbase+cch] = jv.u;
  }
}

// ---------------- attention + head, one block per graph ----------------
__global__ __launch_bounds__(256) void k_attn(
    const f16* __restrict__ jk, const float* __restrict__ x,
    const int* __restrict__ shuf,
    const float* __restrict__ wq, const float* __restrict__ bq,
    const float* __restrict__ wk, const float* __restrict__ bk,
    const float* __restrict__ wv, const float* __restrict__ bv,
    const float* __restrict__ wo, const float* __restrict__ bo,
    const float* __restrict__ wfc, const float* __restrict__ bfc,
    float* __restrict__ out)
{
  __shared__ float H[NODES*33];
  __shared__ float K[NODES*33];
  __shared__ float V[NODES*33];
  __shared__ float Wq[HID*HID];
  __shared__ float Wo[HID*HID];
  __shared__ float Wfc[192*6];
  __shared__ float Qs[6*33];
  __shared__ float S[6*56];
  __shared__ float O[6*33];
  __shared__ float SO[192];
  __shared__ float part[96];
  __shared__ float M[NODES];
  __shared__ int order[8];
  __shared__ int sel[6];

  int g = blockIdx.x, t = threadIdx.x;
  for (int i=t; i<HID*HID; i+=256){ Wq[i]=wq[i]; Wo[i]=wo[i]; }
  for (int i=t; i<192*6;   i+=256){ Wfc[i]=wfc[i]; }
  {
    const f16x8* j8 = (const f16x8*)(jk + (size_t)g*NODES*HID);
    for (int i=t; i<NODES*HID/8; i+=256){     // 220 vectors of 8
      f16x8 v = j8[i];
      int node = i >> 2, c0 = (i & 3)*8;
      #pragma unroll
      for (int r=0;r<8;r++) H[node*33 + c0 + r] = selu_f((float)v[r]);
    }
  }
  if (t < NODES) M[t] = x[(size_t)(g*NODES+t)*INCH + (INCH-3)];
  __syncthreads();
  if (t == 0){
    int c = 0;
    for (int n=0;n<NODES;n++) if (M[n] > 0.5f && c < 6) order[c++] = n;
  }
  __syncthreads();
  if (t < 6) sel[t] = order[shuf[g*6 + t]];
  __syncthreads();

  // K and V: lane = node, wave-uniform output-channel group -> scalar weights
  {
    int k = t & 63;
    int ocg = __builtin_amdgcn_readfirstlane(t >> 6);   // 0..3, wave-uniform
    const float* wkp = wk + ocg*8;
    const float* wvp = wv + ocg*8;
    if (k < NODES){
      float ak[8], av[8];
      #pragma unroll
      for (int j=0;j<8;j++){ ak[j]=bk[ocg*8+j]; av[j]=bv[ocg*8+j]; }
      #pragma unroll
      for (int c=0;c<HID;c++){
        float hv = H[k*33+c];
        #pragma unroll
        for (int j=0;j<8;j++){
          ak[j] = fmaf(hv, wkp[c*HID+j], ak[j]);
          av[j] = fmaf(hv, wvp[c*HID+j], av[j]);
        }
      }
      #pragma unroll
      for (int j=0;j<8;j++){ K[k*33+ocg*8+j]=ak[j]; V[k*33+ocg*8+j]=av[j]; }
    }
  }
  // Q: 6 queries x 32 channels
  if (t < 192){
    int q = t>>5, oc = t&31;
    int node = sel[q];
    float a = bq[oc];
    #pragma unroll
    for (int c=0;c<HID;c++) a = fmaf(H[node*33+c], Wq[c*HID+oc], a);
    Qs[q*33+oc] = a;
  }
  __syncthreads();

  // scores = Q.K^T / sqrt(32)
  for (int idx=t; idx<6*NODES; idx+=256){
    int q = idx % 6, k = idx / 6;
    float a = 0.f;
    #pragma unroll
    for (int c=0;c<HID;c++) a = fmaf(Qs[q*33+c], K[k*33+c], a);
    S[q*56+k] = a * 0.17677669529663687f;
  }
  __syncthreads();

  // softmax over 55 keys: 32-lane group per query
  if (t < 192){
    int q = t>>5, l = t&31;
    float v0 = (l      < NODES) ? S[q*56+l]    : -1e30f;
    float v1 = (l+32   < NODES) ? S[q*56+l+32] : -1e30f;
    float mx = fmaxf(v0, v1);
    #pragma unroll
    for (int o=16;o>0;o>>=1) mx = fmaxf(mx, __shfl_xor(mx, o, 32));
    float p0 = (l    < NODES) ? __expf(v0-mx) : 0.f;
    float p1 = (l+32 < NODES) ? __expf(v1-mx) : 0.f;
    float sm = p0 + p1;
    #pragma unroll
    for (int o=16;o>0;o>>=1) sm += __shfl_xor(sm, o, 32);
    float inv = 1.f/sm;
    if (l    < NODES) S[q*56+l]    = p0*inv;
    if (l+32 < NODES) S[q*56+l+32] = p1*inv;
  }
  __syncthreads();

  // attn @ V
  if (t < 192){
    int q = t>>5, oc = t&31;
    float a = 0.f;
    for (int k=0;k<NODES;k++) a = fmaf(S[q*56+k], V[k*33+oc], a);
    O[q*33+oc] = a;
  }
  __syncthreads();

  // @ wo + bo, selu
  if (t < 192){
    int q = t>>5, oc = t&31;
    float a = bo[oc];
    #pragma unroll
    for (int c=0;c<HID;c++) a = fmaf(O[q*33+c], Wo[c*HID+oc], a);
    SO[t] = selu_f(a);   // t == q*32+oc == flat reshape index
  }
  __syncthreads();

  // final FC: 6 outputs = SO[192] . Wfc[:,j]
  if (t < 96){
    int j = t % 6, pp = t / 6;   // 16 partials per output
    float a = 0.f;
    #pragma unroll
    for (int r=0;r<12;r++) a = fmaf(SO[pp*12+r], Wfc[(pp*12+r)*6+j], a);
    part[pp*6+j] = a;
  }
  __syncthreads();
  if (t < 6){
    float a = bfc[t];
    #pragma unroll
    for (int pp=0;pp<16;pp++) a += part[pp*6+t];
    out[g*6+t] = a;
  }
}

extern "C" void kernel_launch(void* const* d_in, const int* in_sizes, int n_in,
                              void* d_out, int out_size, void* d_ws, size_t ws_size,
                              hipStream_t stream)
{
  const float* x   = (const float*)d_in[0];
  const int*   eix = (const int*)d_in[1];
  const int*   shf = (const int*)d_in[2];
  const float* wl0 = (const float*)d_in[3];
  const float* bl0 = (const float*)d_in[4];
  const float* wr0 = (const float*)d_in[5];
  const float* wl  = (const float*)d_in[6];
  const float* bl  = (const float*)d_in[7];
  const float* wr  = (const float*)d_in[8];
  const float* wq  = (const float*)d_in[9];
  const float* bq  = (const float*)d_in[10];
  const float* wk  = (const float*)d_in[11];
  const float* bk  = (const float*)d_in[12];
  const float* wv  = (const float*)d_in[13];
  const float* bv  = (const float*)d_in[14];
  const float* wo  = (const float*)d_in[15];
  const float* bo  = (const float*)d_in[16];
  const float* wfc = (const float*)d_in[17];
  const float* bfc = (const float*)d_in[18];
  float* out = (float*)d_out;

  const int* esrc = eix;
  const int* edst = eix + ETOT;

  // workspace carve
  char* p = (char*)d_ws;
  auto carve = [&](size_t bytes){ void* r = (void*)p; p += (bytes + 255) & ~(size_t)255; return r; };
  int*      off   = (int*)carve(sizeof(int)*(NTOT+1));
  int*      gcnt  = (int*)carve(sizeof(int)*(size_t)NBLK*NBUCK);   // 1.8 MB
  int*      btot  = (int*)carve(sizeof(int)*256);
  int*      bbase = (int*)carve(sizeof(int)*256);
  uint2*    ovf   = (uint2*)carve(sizeof(uint2)*OVFCAP);
  int*      ocnt  = (int*)carve(sizeof(int)*64);
  f16*      wcp   = (f16*)carve(sizeof(f16)*(1024 + 4*2048));
  uint32_t* csrp  = (uint32_t*)carve(sizeof(uint32_t)*((size_t)ETOT + 64));
  f16*      h_a   = (f16*)carve(2*((size_t)NTOT+1)*HID);   // +1 zero row (index ZN)
  f16*      h_b   = (f16*)carve(2*((size_t)NTOT+1)*HID);   // +1 zero row
  f16*      jk16  = (f16*)carve(2*(size_t)NTOT*HID);

  // aliases over dead regions:
  float*    xf     = (float*)h_b;       // padded x [NTOT+1][16] f32, dead after k_layer0
  uint32_t* binned = (uint32_t*)h_a;    // 220*2048*32*4 = 57,671,680 B = NTOT*64 (row ZN untouched)

  k_pad   <<<ETOT/256,  256, 0, stream>>>(x, xf, (uint32_t*)h_a, ocnt);
  k_wprep <<<1,         256, 0, stream>>>(wl0, wr0, wl, wr, wcp);
  k_bin   <<<NBLK,    BINTH, 0, stream>>>(esrc, edst, binned, gcnt, ovf, ocnt);
  k_btot  <<<NBUCK,     256, 0, stream>>>(gcnt, ovf, ocnt, btot);
  k_bscan <<<1,         256, 0, stream>>>(btot, bbase);
  k_bucket<<<NBUCK,    1024, 0, stream>>>(binned, gcnt, bbase, ovf, ocnt, off, csrp);

  k_layer0<<<NTOT/NPB, 256, 0, stream>>>(xf, off, csrp, wcp, bl0, h_a, jk16);
  f16* hc = h_a; f16* hn = h_b;
  for (int l=0; l<4; l++){
    k_layer<<<NTOT/NPB, 256, 0, stream>>>(hc, off, csrp,
                                          wcp + 1024 + l*2048, bl + l*HID,
                                          hn, jk16);
    f16* tmp = hc; hc = hn; hn = tmp;
  }
  k_attn<<<BGRAPH, 256, 0, stream>>>(jk16, x, shf,
                                     wq, bq, wk, bk, wv, bv, wo, bo, wfc, bfc, out);
}

// Round 6
// 841.200 us; speedup vs baseline: 4.5843x; 1.1176x over previous
//
#include <hip/hip_runtime.h>
#include <cstdint>
#include <cstddef>

#define NODES   55
#define BGRAPH  16384
#define NTOT    (BGRAPH*NODES)    // 901120
#define INCH    13
#define HID     32
#define ETOT    (4*NTOT)          // 3604480
#define NPB     128               // nodes per block (layer kernels)
#define ECAP    768               // LDS edge-list capacity (mean 512, +11 sigma; global fallback)
#define ZN      NTOT              // dummy zero-row index for masked edge slots

// ---- deterministic binned CSR build ----
#define NBUCK   220               // NTOT/4096 buckets
#define BSH     12                // 4096 nodes per bucket
#define BMSK    4095
#define NBLK    2048              // k_bin blocks
#define BCAP2   32                // slots per (bucket,block) segment; mean 8, +8.5 sigma
#define BINTH   256
#define BINGRP  (ETOT/4/NBLK)     // 440 int4-groups per block (exact)
#define OVFCAP  8192

// ---- MFMA staging ----
#define ASTR    72                // A row stride (f16): 144B rows (16B-aligned)
#define BSTR    72
#define ASTR0   40                // layer0 A/B stride (f16): 80B rows
#define WKV_OFF 9216              // wkvT offset (f16 elems) inside wcp

typedef _Float16 f16;
typedef _Float16 f16x4 __attribute__((ext_vector_type(4))); // 8B
typedef _Float16 f16x8 __attribute__((ext_vector_type(8))); // 16B
typedef float    f32x4 __attribute__((ext_vector_type(4)));

__device__ __forceinline__ float selu_f(float v){
  const float s  = 1.0507009873554805f;
  const float sa = 1.7580993408473766f;   // scale*alpha
  return v > 0.f ? s*v : sa*(__expf(v)-1.f);
}

// ---------------- pad x[N,13] fp32 -> xf[N,16] fp32; zero dummy rows + ovf cursor ----------------
__global__ __launch_bounds__(256) void k_pad(const float* __restrict__ x,
                                             float* __restrict__ xf,
                                             uint32_t* __restrict__ ha32,
                                             int* __restrict__ ocnt){
  if (blockIdx.x == 0){
    int t = threadIdx.x;
    if (t == 0) *ocnt = 0;
    if (t < 16)            xf[(size_t)ZN*16 + t] = 0.f;       // zero row of xf (== h_b row ZN)
    if (t >= 16 && t < 32) ha32[(size_t)ZN*16 + (t-16)] = 0u; // zero row of h_a
  }
  int i = blockIdx.x*256 + threadIdx.x;   // one float4 per thread, ETOT total (grid exact)
  int node = i>>2, q = i&3;
  const float* r = x + (size_t)node*INCH + q*4;
  float4 v;
  v.x = r[0];
  v.y = (q<3) ? r[1] : 0.f;
  v.z = (q<3) ? r[2] : 0.f;
  v.w = (q<3) ? r[3] : 0.f;
  ((float4*)xf)[i] = v;
}

// ---------------- weight prep: concat+transpose to f16 once ----------------
// wcp layout: [0,1024)            = B0^T[32 oc][32 k]  (k<13: wl0, 16..28: wr0, else 0)
//             [1024 + l*2048 ...) = Bl^T[32 oc][64 k]  (k<32: wl[l], else wr[l])
//             [9216, 11264)       = [Wk|Wv]^T[64 oc][32 k]  (oc<32: wk, else wv)
__global__ __launch_bounds__(256) void k_wprep(
    const float* __restrict__ wl0, const float* __restrict__ wr0,
    const float* __restrict__ wl,  const float* __restrict__ wr,
    const float* __restrict__ wk,  const float* __restrict__ wv,
    f16* __restrict__ wcp)
{
  int t = threadIdx.x;
  for (int i=t; i<1024; i+=256){
    int oc = i>>5, k = i&31;
    float v = 0.f;
    if (k < 13)                 v = wl0[k*HID + oc];
    else if (k >= 16 && k < 29) v = wr0[(k-16)*HID + oc];
    wcp[oc*32 + k] = (f16)v;
  }
  for (int i=t; i<4*2048; i+=256){
    int l = i>>11, r = i&2047, oc = r>>6, k = r&63;
    float v = (k<32) ? wl[l*1024 + k*HID + oc] : wr[l*1024 + (k-32)*HID + oc];
    wcp[1024 + l*2048 + oc*64 + k] = (f16)v;
  }
  for (int i=t; i<2048; i+=256){
    int oc = i>>5, k = i&31;
    float v = (oc < 32) ? wk[k*HID + oc] : wv[k*HID + (oc-32)];
    wcp[WKV_OFF + oc*32 + k] = (f16)v;
  }
}

// ---------------- phase A: bin edges into per-(bucket,block) segments, no global atomics ----------------
__global__ __launch_bounds__(BINTH) void k_bin(
    const int* __restrict__ src, const int* __restrict__ dst,
    uint32_t* __restrict__ binned, int* __restrict__ gcnt,
    uint2* __restrict__ ovf, int* __restrict__ ocnt)
{
  __shared__ int lcnt[NBUCK];
  int t = threadIdx.x, bid = blockIdx.x;
  for (int i=t;i<NBUCK;i+=BINTH) lcnt[i]=0;
  __syncthreads();
  const int4* s4 = (const int4*)src;
  const int4* d4 = (const int4*)dst;
  int g0 = bid*BINGRP;
  for (int i=t; i<BINGRP; i+=BINTH){
    int4 s = s4[g0+i];
    int4 d = d4[g0+i];
    #pragma unroll
    for (int j=0;j<4;j++){
      int dd = (&d.x)[j];
      int ss = (&s.x)[j];
      int b  = dd >> BSH;
      uint32_t entry = (uint32_t)ss | ((uint32_t)(dd & BMSK) << 20);
      int pos = atomicAdd(&lcnt[b], 1);
      if (pos < BCAP2) binned[((size_t)b*NBLK + bid)*BCAP2 + pos] = entry;
      else {                                  // ~1e-10/cell; correctness fallback
        int gp = atomicAdd(ocnt, 1);
        if (gp < OVFCAP) ovf[gp] = make_uint2(entry, (uint32_t)b);
      }
    }
  }
  __syncthreads();
  for (int i=t;i<NBUCK;i+=BINTH){
    int c = lcnt[i]; if (c > BCAP2) c = BCAP2;
    gcnt[bid*NBUCK + i] = c;                  // coalesced per-block row
  }
}

// ---------------- bucket totals (incl. overflow) ----------------
__global__ __launch_bounds__(256) void k_btot(const int* __restrict__ gcnt,
                                              const uint2* __restrict__ ovf,
                                              const int* __restrict__ ocnt,
                                              int* __restrict__ btot){
  __shared__ int sd[256];
  int b = blockIdx.x, t = threadIdx.x;
  int s = 0;
  for (int i=t;i<NBLK;i+=256) s += gcnt[i*NBUCK + b];
  int oc = *ocnt; if (oc > OVFCAP) oc = OVFCAP;
  for (int j=t;j<oc;j+=256) if (ovf[j].y == (uint32_t)b) s++;
  sd[t]=s; __syncthreads();
  for (int o=128;o>0;o>>=1){ if (t<o) sd[t]+=sd[t+o]; __syncthreads(); }
  if (t==0) btot[b]=sd[0];
}

// ---------------- exclusive scan of 220 bucket totals ----------------
__global__ __launch_bounds__(256) void k_bscan(const int* __restrict__ btot,
                                               int* __restrict__ bbase){
  __shared__ int sd[256];
  int t = threadIdx.x;
  int v = (t<NBUCK) ? btot[t] : 0;
  sd[t] = v; __syncthreads();
  for (int o=1;o<256;o<<=1){
    int u = (t>=o) ? sd[t-o] : 0;
    __syncthreads();
    sd[t] += u;
    __syncthreads();
  }
  if (t<NBUCK) bbase[t] = sd[t] - v;
}

// ---------------- phase B: per-bucket counting sort -> off + csrp (L2-local) ----------------
__global__ __launch_bounds__(1024) void k_bucket(
    const uint32_t* __restrict__ binned, const int* __restrict__ gcnt,
    const int* __restrict__ bbase,
    const uint2* __restrict__ ovf, const int* __restrict__ ocnt,
    int* __restrict__ off, uint32_t* __restrict__ csrp)
{
  __shared__ int hist[4096];   // degree counts -> scatter cursors
  __shared__ int cnts[NBLK];
  __shared__ int ws[1024];
  int b = blockIdx.x, t = threadIdx.x;
  int base = bbase[b];
  for (int i=t;i<NBLK;i+=1024) cnts[i] = gcnt[i*NBUCK + b];
  #pragma unroll
  for (int i=0;i<4;i++) hist[t+1024*i] = 0;
  int oc = *ocnt; if (oc > OVFCAP) oc = OVFCAP;
  __syncthreads();

  const uint4* bb4 = (const uint4*)(binned + (size_t)b*(NBLK*BCAP2));
  // pass 1: local-degree histogram
  for (int i=t; i<NBLK*BCAP2/4; i+=1024){
    uint4 e = bb4[i];
    int c = cnts[i>>3];
    int s0 = (i&7)*4;
    if (s0   < c) atomicAdd(&hist[(e.x>>20)&BMSK],1);
    if (s0+1 < c) atomicAdd(&hist[(e.y>>20)&BMSK],1);
    if (s0+2 < c) atomicAdd(&hist[(e.z>>20)&BMSK],1);
    if (s0+3 < c) atomicAdd(&hist[(e.w>>20)&BMSK],1);
  }
  for (int j=t;j<oc;j+=1024){
    uint2 pr = ovf[j];
    if (pr.y == (uint32_t)b) atomicAdd(&hist[(pr.x>>20)&BMSK],1);
  }
  __syncthreads();
  // exclusive scan of 4096 degrees
  int t4 = t*4;
  int s0=hist[t4], s1=hist[t4+1], s2=hist[t4+2], s3=hist[t4+3];
  int sum = s0+s1+s2+s3;
  ws[t] = sum; __syncthreads();
  for (int o=1;o<1024;o<<=1){
    int u = (t>=o) ? ws[t-o] : 0;
    __syncthreads();
    ws[t] += u;
    __syncthreads();
  }
  int ex = ws[t] - sum;
  int p0 = ex, p1 = ex+s0, p2 = ex+s0+s1, p3 = ex+s0+s1+s2;
  hist[t4]=p0; hist[t4+1]=p1; hist[t4+2]=p2; hist[t4+3]=p3;   // cursors
  int4 ov; ov.x = base+p0; ov.y = base+p1; ov.z = base+p2; ov.w = base+p3;
  ((int4*)(off + (b<<BSH)))[t] = ov;
  if (b == NBUCK-1 && t == 1023) off[NTOT] = ETOT;
  __syncthreads();
  // pass 2: scatter to final CSR (256KB window -> single-XCD L2 absorbs)
  for (int i=t; i<NBLK*BCAP2/4; i+=1024){
    uint4 e = bb4[i];
    int c = cnts[i>>3];
    int s0b = (i&7)*4;
    int p;
    if (s0b   < c){ p = atomicAdd(&hist[(e.x>>20)&BMSK],1); csrp[base+p] = e.x & 0xFFFFFu; }
    if (s0b+1 < c){ p = atomicAdd(&hist[(e.y>>20)&BMSK],1); csrp[base+p] = e.y & 0xFFFFFu; }
    if (s0b+2 < c){ p = atomicAdd(&hist[(e.z>>20)&BMSK],1); csrp[base+p] = e.z & 0xFFFFFu; }
    if (s0b+3 < c){ p = atomicAdd(&hist[(e.w>>20)&BMSK],1); csrp[base+p] = e.w & 0xFFFFFu; }
  }
  for (int j=t;j<oc;j+=1024){
    uint2 pr = ovf[j];
    if (pr.y == (uint32_t)b){
      int p = atomicAdd(&hist[(pr.x>>20)&BMSK],1);
      csrp[base+p] = pr.x & 0xFFFFFu;
    }
  }
}

// ---------------- fused SAGE layer 0 (gather + MFMA, K=32) ----------------
__global__ __launch_bounds__(256,8) void k_layer0(
    const float* __restrict__ xf,
    const int* __restrict__ off, const uint32_t* __restrict__ csrp,
    const f16* __restrict__ wcat0, const float* __restrict__ bl0,
    f16* __restrict__ hout, f16* __restrict__ jkout)
{
  __shared__ uint32_t ALDS[NPB*(ASTR0/2)];   // 10240B: A[128][40] f16 = [mean16|x16]; reused as ST
  __shared__ uint32_t BLDS[32*(ASTR0/2)];    // 2560B:  B0^T[32][40] f16
  __shared__ uint32_t EL[ECAP];              // 3072B
  __shared__ int      sOFF[NPB+2];
  __shared__ float    biasL[32];
  int t = threadIdx.x;
  int base = blockIdx.x*NPB;
  int e0 = off[base];
  int e1 = off[base+NPB];
  for (int i=t; i<NPB+1; i+=256) sOFF[i] = off[base+i];
  {
    int lim = (e1-e0) < ECAP ? (e1-e0) : ECAP;
    for (int i=t; i<lim; i+=256) EL[i] = csrp[e0+i];
  }
  if (t < 128){
    int oc = t>>2, kq = (t&3)*8;
    f16x8 wv = *(const f16x8*)(wcat0 + oc*32 + kq);
    *(f16x8*)((f16*)BLDS + oc*ASTR0 + kq) = wv;
  }
  if (t < 32) biasL[t] = bl0[t];
  __syncthreads();   // staging (sOFF/EL/BLDS/bias) visible before gather reads

  // gather: 4 lanes per node (float4 = 4 ch each); masked slots -> zero row ZN
  int c4 = t & 3;
  #pragma unroll
  for (int p=0;p<2;p++){
    int nl = p*64 + (t>>2);
    int node = base + nl;
    float4 xown = *((const float4*)(xf + (size_t)node*16) + c4);
    int s = sOFF[nl] - e0;
    int d = sOFF[nl+1] - sOFF[nl];
    float a0=0.f,a1=0.f,a2=0.f,a3=0.f;
    for (int i=0;i<d;i+=4){
      int j0 = s+i;
      uint32_t k0,k1,k2,k3;
      if (j0+3 < ECAP){ k0=EL[j0]; k1=EL[j0+1]; k2=EL[j0+2]; k3=EL[j0+3]; }
      else            { k0=csrp[e0+j0]; k1=csrp[e0+j0+1]; k2=csrp[e0+j0+2]; k3=csrp[e0+j0+3]; }
      k1 = (i+1<d)?k1:(uint32_t)ZN;
      k2 = (i+2<d)?k2:(uint32_t)ZN;
      k3 = (i+3<d)?k3:(uint32_t)ZN;
      float4 g0 = *((const float4*)(xf + (size_t)k0*16u) + c4);
      float4 g1 = *((const float4*)(xf + (size_t)k1*16u) + c4);
      float4 g2 = *((const float4*)(xf + (size_t)k2*16u) + c4);
      float4 g3 = *((const float4*)(xf + (size_t)k3*16u) + c4);
      a0 += (g0.x+g1.x)+(g2.x+g3.x);
      a1 += (g0.y+g1.y)+(g2.y+g3.y);
      a2 += (g0.z+g1.z)+(g2.z+g3.z);
      a3 += (g0.w+g1.w)+(g2.w+g3.w);
    }
    float inv = 1.f/(float)(d<1?1:d);
    union { f16 h[4]; uint32_t u[2]; } mp, xp;
    mp.h[0]=(f16)(a0*inv); mp.h[1]=(f16)(a1*inv); mp.h[2]=(f16)(a2*inv); mp.h[3]=(f16)(a3*inv);
    xp.h[0]=(f16)xown.x;   xp.h[1]=(f16)xown.y;   xp.h[2]=(f16)xown.z;   xp.h[3]=(f16)xown.w;
    uint32_t* arow = &ALDS[nl*(ASTR0/2)];
    *((uint2*)&arow[2*c4])     = make_uint2(mp.u[0], mp.u[1]);   // mean cols 4c4..
    *((uint2*)&arow[8 + 2*c4]) = make_uint2(xp.u[0], xp.u[1]);   // x cols 16+4c4..
  }
  __syncthreads();

  // MFMA: wave w owns rows 32w..32w+31, cols 0..31; single K=32 step
  int w = t>>6, l = t&63;
  int lrow = l&15, lg = l>>4;
  const f16* Af = (const f16*)ALDS;
  const f16* Bf = (const f16*)BLDS;
  f32x4 D00={0.f,0.f,0.f,0.f}, D01=D00, D10=D00, D11=D00;
  {
    f16x8 af0 = *(const f16x8*)(Af + (32*w+lrow)*ASTR0    + 8*lg);
    f16x8 af1 = *(const f16x8*)(Af + (32*w+16+lrow)*ASTR0 + 8*lg);
    f16x8 bf0 = *(const f16x8*)(Bf + lrow*ASTR0           + 8*lg);
    f16x8 bf1 = *(const f16x8*)(Bf + (16+lrow)*ASTR0      + 8*lg);
    D00 = __builtin_amdgcn_mfma_f32_16x16x32_f16(af0, bf0, D00, 0,0,0);
    D01 = __builtin_amdgcn_mfma_f32_16x16x32_f16(af0, bf1, D01, 0,0,0);
    D10 = __builtin_amdgcn_mfma_f32_16x16x32_f16(af1, bf0, D10, 0,0,0);
    D11 = __builtin_amdgcn_mfma_f32_16x16x32_f16(af1, bf1, D11, 0,0,0);
  }
  __syncthreads();       // all frag reads done -> ALDS reusable as ST

  f16* ST = (f16*)ALDS;  // [128][34] f16 staging
  #pragma unroll
  for (int j=0;j<4;j++){
    int r0 = 32*w + 4*lg + j, r1 = r0 + 16;
    ST[r0*34 + lrow]      = (f16)selu_f(D00[j] + biasL[lrow]);
    ST[r0*34 + 16 + lrow] = (f16)selu_f(D01[j] + biasL[16+lrow]);
    ST[r1*34 + lrow]      = (f16)selu_f(D10[j] + biasL[lrow]);
    ST[r1*34 + 16 + lrow] = (f16)selu_f(D11[j] + biasL[16+lrow]);
  }
  __syncthreads();

  const uint32_t* STd = (const uint32_t*)ALDS;
  uint4* ho4 = (uint4*)hout;
  uint4* jo4 = (uint4*)jkout;
  int gbase = blockIdx.x*(NPB*HID/8);   // 512 16B-chunks per block
  #pragma unroll
  for (int k=0;k<2;k++){
    int cch = t + 256*k;
    int n = cch>>2, m = cch&3;
    int dd = n*17 + m*4;
    uint4 u;
    u.x=STd[dd]; u.y=STd[dd+1]; u.z=STd[dd+2]; u.w=STd[dd+3];
    ho4[gbase+cch] = u;
    jo4[gbase+cch] = u;
  }
}

// ---------------- fused SAGE layers 1..4 (gather + MFMA, K=64) ----------------
__global__ __launch_bounds__(256,6) void k_layer(
    const f16* __restrict__ hin,
    const int* __restrict__ off, const uint32_t* __restrict__ csrp,
    const f16* __restrict__ wcat, const float* __restrict__ bl,
    f16* __restrict__ hout, f16* __restrict__ jkio)
{
  __shared__ uint32_t ALDS[NPB*(ASTR/2)];    // 18432B: A[128][72] f16 = [mean32|h32]; reused as ST
  __shared__ uint32_t BLDS[32*(BSTR/2)];     // 4608B:  B^T[32][72] f16
  __shared__ uint32_t EL[ECAP];              // 3072B
  __shared__ int      sOFF[NPB+2];
  __shared__ float    biasL[32];
  int t = threadIdx.x;
  int base = blockIdx.x*NPB;
  int e0 = off[base];
  int e1 = off[base+NPB];
  for (int i=t; i<NPB+1; i+=256) sOFF[i] = off[base+i];
  {
    int lim = (e1-e0) < ECAP ? (e1-e0) : ECAP;
    for (int i=t; i<lim; i+=256) EL[i] = csrp[e0+i];
  }
  if (t < 128){
    int oc = t>>2, kq = (t&3)*8;               // 4 chunks of 8 f16 per row
    f16x8 wv0 = *(const f16x8*)(wcat + oc*64 + kq);
    f16x8 wv1 = *(const f16x8*)(wcat + oc*64 + 32 + kq);
    *(f16x8*)((f16*)BLDS + oc*BSTR + kq)      = wv0;
    *(f16x8*)((f16*)BLDS + oc*BSTR + 32 + kq) = wv1;
  }
  if (t < 32) biasL[t] = bl[t];
  __syncthreads();   // staging (sOFF/EL/BLDS/bias) visible before gather reads

  // gather: 4 lanes per node (f16x8 = 8 ch each); masked slots -> zero row ZN
  int c4 = t & 3;
  #pragma unroll
  for (int p=0;p<2;p++){
    int nl = p*64 + (t>>2);
    int node = base + nl;
    f16x8 hown = *(const f16x8*)(hin + (size_t)node*HID + 8u*c4);
    int s = sOFF[nl] - e0;
    int d = sOFF[nl+1] - sOFF[nl];
    float a[8];
    #pragma unroll
    for (int r=0;r<8;r++) a[r]=0.f;
    for (int i=0;i<d;i+=4){
      int j0 = s+i;
      uint32_t k0,k1,k2,k3;
      if (j0+3 < ECAP){ k0=EL[j0]; k1=EL[j0+1]; k2=EL[j0+2]; k3=EL[j0+3]; }
      else            { k0=csrp[e0+j0]; k1=csrp[e0+j0+1]; k2=csrp[e0+j0+2]; k3=csrp[e0+j0+3]; }
      k1 = (i+1<d)?k1:(uint32_t)ZN;
      k2 = (i+2<d)?k2:(uint32_t)ZN;
      k3 = (i+3<d)?k3:(uint32_t)ZN;
      f16x8 g0 = *((const f16x8*)(hin + (size_t)k0*32u) + c4);
      f16x8 g1 = *((const f16x8*)(hin + (size_t)k1*32u) + c4);
      f16x8 g2 = *((const f16x8*)(hin + (size_t)k2*32u) + c4);
      f16x8 g3 = *((const f16x8*)(hin + (size_t)k3*32u) + c4);
      #pragma unroll
      for (int r=0;r<8;r++)
        a[r] += ((float)g0[r]+(float)g1[r]) + ((float)g2[r]+(float)g3[r]);
    }
    float inv = 1.f/(float)(d<1?1:d);
    union { f16 h[8]; uint4 v; } mp;
    #pragma unroll
    for (int r=0;r<8;r++) mp.h[r] = (f16)(a[r]*inv);
    uint32_t* arow = &ALDS[nl*(ASTR/2)];
    *((uint4*)&arow[4*c4]) = mp.v;                          // mean cols 8c4..
    *((f16x8*)((f16*)arow + 32 + 8*c4)) = hown;             // h cols 32+8c4..
  }
  __syncthreads();

  // MFMA: wave w owns rows 32w..32w+31, cols 0..31; two K=32 steps
  int w = t>>6, l = t&63;
  int lrow = l&15, lg = l>>4;
  const f16* Af = (const f16*)ALDS;
  const f16* Bf = (const f16*)BLDS;
  f32x4 D00={0.f,0.f,0.f,0.f}, D01=D00, D10=D00, D11=D00;
  #pragma unroll
  for (int s2=0;s2<2;s2++){
    f16x8 af0 = *(const f16x8*)(Af + (32*w+lrow)*ASTR    + 32*s2 + 8*lg);
    f16x8 af1 = *(const f16x8*)(Af + (32*w+16+lrow)*ASTR + 32*s2 + 8*lg);
    f16x8 bf0 = *(const f16x8*)(Bf + lrow*BSTR           + 32*s2 + 8*lg);
    f16x8 bf1 = *(const f16x8*)(Bf + (16+lrow)*BSTR      + 32*s2 + 8*lg);
    D00 = __builtin_amdgcn_mfma_f32_16x16x32_f16(af0, bf0, D00, 0,0,0);
    D01 = __builtin_amdgcn_mfma_f32_16x16x32_f16(af0, bf1, D01, 0,0,0);
    D10 = __builtin_amdgcn_mfma_f32_16x16x32_f16(af1, bf0, D10, 0,0,0);
    D11 = __builtin_amdgcn_mfma_f32_16x16x32_f16(af1, bf1, D11, 0,0,0);
  }
  __syncthreads();       // all frag reads done -> ALDS reusable as ST

  f16* ST = (f16*)ALDS;  // [128][34] f16 staging
  #pragma unroll
  for (int j=0;j<4;j++){
    int r0 = 32*w + 4*lg + j, r1 = r0 + 16;
    ST[r0*34 + lrow]      = (f16)selu_f(D00[j] + biasL[lrow]);
    ST[r0*34 + 16 + lrow] = (f16)selu_f(D01[j] + biasL[16+lrow]);
    ST[r1*34 + lrow]      = (f16)selu_f(D10[j] + biasL[lrow]);
    ST[r1*34 + 16 + lrow] = (f16)selu_f(D11[j] + biasL[16+lrow]);
  }
  __syncthreads();

  const uint32_t* STd = (const uint32_t*)ALDS;
  uint4* ho4 = (uint4*)hout;
  uint4* jo4 = (uint4*)jkio;
  int gbase = blockIdx.x*(NPB*HID/8);
  #pragma unroll
  for (int k=0;k<2;k++){
    int cch = t + 256*k;
    int n = cch>>2, m = cch&3;
    int dd = n*17 + m*4;
    union { uint4 u; f16 hh[8]; } hv, jv;
    hv.u.x=STd[dd]; hv.u.y=STd[dd+1]; hv.u.z=STd[dd+2]; hv.u.w=STd[dd+3];
    jv.u = jo4[gbase+cch];
    #pragma unroll
    for (int r=0;r<8;r++){
      float a = (float)jv.hh[r], b = (float)hv.hh[r];
      jv.hh[r] = (f16)fmaxf(a, b);
    }
    ho4[gbase+cch] = hv.u;
    jo4[gbase+cch] = jv.u;
  }
}

// ---------------- attention + head, one block per graph (MFMA K/V, slim LDS) ----------------
__global__ __launch_bounds__(256) void k_attn(
    const f16* __restrict__ jk, const float* __restrict__ x,
    const int* __restrict__ shuf, const f16* __restrict__ wkvT,
    const float* __restrict__ wq, const float* __restrict__ bq,
    const float* __restrict__ bk, const float* __restrict__ bv,
    const float* __restrict__ wo, const float* __restrict__ bo,
    const float* __restrict__ wfc, const float* __restrict__ bfc,
    float* __restrict__ out)
{
  __shared__ alignas(16) f16 Ah[64*40];   // 5120B: H=selu(jk) f16; rows 55..63 garbage (discarded)
  __shared__ float K[NODES*33];           // 7260B
  __shared__ float V[NODES*33];           // 7260B
  __shared__ float Qs[6*33];
  __shared__ float S[6*56];
  __shared__ float O[6*33];
  __shared__ float SO[192];
  __shared__ float part[96];
  __shared__ int   sel[8];

  int g = blockIdx.x, t = threadIdx.x;

  // stage H = selu(jk) as f16 into A-tile (rows=nodes, 40-f16 stride)
  {
    const f16x8* j8 = (const f16x8*)(jk + (size_t)g*NODES*HID);
    for (int i=t; i<NODES*HID/8; i+=256){   // 220 vectors of 8
      f16x8 v = j8[i];
      int node = i >> 2, c0 = (i & 3)*8;
      f16x8 hv;
      #pragma unroll
      for (int r=0;r<8;r++) hv[r] = (f16)selu_f((float)v[r]);
      *(f16x8*)(Ah + node*40 + c0) = hv;
    }
  }
  // wave 0: neighbor-mask ballot -> sel (no serial loop, no barrier needed pre-write)
  if (t < 64){
    float mv = (t < NODES) ? x[(size_t)(g*NODES+t)*INCH + (INCH-3)] : 0.f;
    unsigned long long mb = __ballot(mv > 0.5f);
    if (t < 6){
      int kk = shuf[g*6 + t];
      for (int i2=0;i2<kk;i2++) mb &= (mb - 1ull);
      sel[t] = (int)__builtin_ctzll(mb);
    }
  }
  __syncthreads();

  // K/V projection via MFMA: [64x32] H @ [32x64] (Wk|Wv), wave w = row-tile w
  {
    int w = t>>6, l = t&63;
    int lrow = l&15, lg = l>>4;
    f16x8 af = *(const f16x8*)(Ah + (16*w + lrow)*40 + 8*lg);
    #pragma unroll
    for (int ct=0; ct<4; ct++){
      f16x8 bf = *(const f16x8*)(wkvT + (16*ct + lrow)*32 + 8*lg);  // global, L2-resident
      f32x4 D = {0.f,0.f,0.f,0.f};
      D = __builtin_amdgcn_mfma_f32_16x16x32_f16(af, bf, D, 0,0,0);
      int ocl = 16*(ct&1) + lrow;
      float bias = (ct < 2) ? bk[ocl] : bv[ocl];
      float* dst = (ct < 2) ? K : V;
      #pragma unroll
      for (int j=0;j<4;j++){
        int node = 16*w + 4*lg + j;
        if (node < NODES) dst[node*33 + ocl] = D[j] + bias;
      }
    }
  }
  // Q projection (6x32, VALU; wq from global - cache-resident)
  if (t < 192){
    int q = t>>5, oc = t&31;
    int node = sel[q];
    const f16x8* hr8 = (const f16x8*)(Ah + node*40);
    float a = bq[oc];
    #pragma unroll
    for (int cc=0;cc<4;cc++){
      f16x8 hv = hr8[cc];
      #pragma unroll
      for (int r=0;r<8;r++) a = fmaf((float)hv[r], wq[(8*cc+r)*HID + oc], a);
    }
    Qs[q*33+oc] = a;
  }
  __syncthreads();

  // scores = Q.K^T / sqrt(32)
  for (int idx=t; idx<6*NODES; idx+=256){
    int q = idx % 6, k = idx / 6;
    float a = 0.f;
    #pragma unroll
    for (int c=0;c<HID;c++) a = fmaf(Qs[q*33+c], K[k*33+c], a);
    S[q*56+k] = a * 0.17677669529663687f;
  }
  __syncthreads();

  // softmax over 55 keys: 32-lane group per query
  if (t < 192){
    int q = t>>5, l = t&31;
    float v0 = (l      < NODES) ? S[q*56+l]    : -1e30f;
    float v1 = (l+32   < NODES) ? S[q*56+l+32] : -1e30f;
    float mx = fmaxf(v0, v1);
    #pragma unroll
    for (int o=16;o>0;o>>=1) mx = fmaxf(mx, __shfl_xor(mx, o, 32));
    float p0 = (l    < NODES) ? __expf(v0-mx) : 0.f;
    float p1 = (l+32 < NODES) ? __expf(v1-mx) : 0.f;
    float sm = p0 + p1;
    #pragma unroll
    for (int o=16;o>0;o>>=1) sm += __shfl_xor(sm, o, 32);
    float inv = 1.f/sm;
    if (l    < NODES) S[q*56+l]    = p0*inv;
    if (l+32 < NODES) S[q*56+l+32] = p1*inv;
  }
  __syncthreads();

  // attn @ V
  if (t < 192){
    int q = t>>5, oc = t&31;
    float a = 0.f;
    for (int k=0;k<NODES;k++) a = fmaf(S[q*56+k], V[k*33+oc], a);
    O[q*33+oc] = a;
  }
  __syncthreads();

  // @ wo + bo, selu  (wo from global - cache-resident, 6x reuse per block)
  if (t < 192){
    int q = t>>5, oc = t&31;
    float a = bo[oc];
    #pragma unroll
    for (int c=0;c<HID;c++) a = fmaf(O[q*33+c], wo[c*HID+oc], a);
    SO[t] = selu_f(a);   // t == q*32+oc == flat reshape index
  }
  __syncthreads();

  // final FC: 6 outputs = SO[192] . Wfc[:,j]  (wfc from global - 1x use, no staging win)
  if (t < 96){
    int j = t % 6, pp = t / 6;   // 16 partials per output
    float a = 0.f;
    #pragma unroll
    for (int r=0;r<12;r++) a = fmaf(SO[pp*12+r], wfc[(pp*12+r)*6+j], a);
    part[pp*6+j] = a;
  }
  __syncthreads();
  if (t < 6){
    float a = bfc[t];
    #pragma unroll
    for (int pp=0;pp<16;pp++) a += part[pp*6+t];
    out[g*6+t] = a;
  }
}

extern "C" void kernel_launch(void* const* d_in, const int* in_sizes, int n_in,
                              void* d_out, int out_size, void* d_ws, size_t ws_size,
                              hipStream_t stream)
{
  const float* x   = (const float*)d_in[0];
  const int*   eix = (const int*)d_in[1];
  const int*   shf = (const int*)d_in[2];
  const float* wl0 = (const float*)d_in[3];
  const float* bl0 = (const float*)d_in[4];
  const float* wr0 = (const float*)d_in[5];
  const float* wl  = (const float*)d_in[6];
  const float* bl  = (const float*)d_in[7];
  const float* wr  = (const float*)d_in[8];
  const float* wq  = (const float*)d_in[9];
  const float* bq  = (const float*)d_in[10];
  const float* wk  = (const float*)d_in[11];
  const float* bk  = (const float*)d_in[12];
  const float* wv  = (const float*)d_in[13];
  const float* bv  = (const float*)d_in[14];
  const float* wo  = (const float*)d_in[15];
  const float* bo  = (const float*)d_in[16];
  const float* wfc = (const float*)d_in[17];
  const float* bfc = (const float*)d_in[18];
  float* out = (float*)d_out;

  const int* esrc = eix;
  const int* edst = eix + ETOT;

  // workspace carve
  char* p = (char*)d_ws;
  auto carve = [&](size_t bytes){ void* r = (void*)p; p += (bytes + 255) & ~(size_t)255; return r; };
  int*      off   = (int*)carve(sizeof(int)*(NTOT+1));
  int*      gcnt  = (int*)carve(sizeof(int)*(size_t)NBLK*NBUCK);   // 1.8 MB
  int*      btot  = (int*)carve(sizeof(int)*256);
  int*      bbase = (int*)carve(sizeof(int)*256);
  uint2*    ovf   = (uint2*)carve(sizeof(uint2)*OVFCAP);
  int*      ocnt  = (int*)carve(sizeof(int)*64);
  f16*      wcp   = (f16*)carve(sizeof(f16)*(WKV_OFF + 2048));
  uint32_t* csrp  = (uint32_t*)carve(sizeof(uint32_t)*((size_t)ETOT + 64));
  f16*      h_a   = (f16*)carve(2*((size_t)NTOT+1)*HID);   // +1 zero row (index ZN)
  f16*      h_b   = (f16*)carve(2*((size_t)NTOT+1)*HID);   // +1 zero row
  f16*      jk16  = (f16*)carve(2*(size_t)NTOT*HID);

  // aliases over dead regions:
  float*    xf     = (float*)h_b;       // padded x [NTOT+1][16] f32, dead after k_layer0
  uint32_t* binned = (uint32_t*)h_a;    // 220*2048*32*4 = 57,671,680 B = NTOT*64 (row ZN untouched)

  k_pad   <<<ETOT/256,  256, 0, stream>>>(x, xf, (uint32_t*)h_a, ocnt);
  k_wprep <<<1,         256, 0, stream>>>(wl0, wr0, wl, wr, wk, wv, wcp);
  k_bin   <<<NBLK,    BINTH, 0, stream>>>(esrc, edst, binned, gcnt, ovf, ocnt);
  k_btot  <<<NBUCK,     256, 0, stream>>>(gcnt, ovf, ocnt, btot);
  k_bscan <<<1,         256, 0, stream>>>(btot, bbase);
  k_bucket<<<NBUCK,    1024, 0, stream>>>(binned, gcnt, bbase, ovf, ocnt, off, csrp);

  k_layer0<<<NTOT/NPB, 256, 0, stream>>>(xf, off, csrp, wcp, bl0, h_a, jk16);
  f16* hc = h_a; f16* hn = h_b;
  for (int l=0; l<4; l++){
    k_layer<<<NTOT/NPB, 256, 0, stream>>>(hc, off, csrp,
                                          wcp + 1024 + l*2048, bl + l*HID,
                                          hn, jk16);
    f16* tmp = hc; hc = hn; hn = tmp;
  }
  k_attn<<<BGRAPH, 256, 0, stream>>>(jk16, x, shf, wcp + WKV_OFF,
                                     wq, bq, bk, bv, wo, bo, wfc, bfc, out);
}

// Round 8
// 824.572 us; speedup vs baseline: 4.6767x; 1.0202x over previous
//
#include <hip/hip_runtime.h>
#include <cstdint>
#include <cstddef>

#define NODES   55
#define BGRAPH  16384
#define NTOT    (BGRAPH*NODES)    // 901120
#define INCH    13
#define HID     32
#define ETOT    (4*NTOT)          // 3604480
#define NPB     128               // nodes per block (layer kernels)
#define ECAP    768               // LDS edge-list capacity (mean 512, +11 sigma; global fallback)
#define ZN      NTOT              // dummy zero-row index for masked edge slots

// ---- deterministic binned CSR build ----
#define NBUCK   220               // NTOT/4096 buckets
#define BSH     12                // 4096 nodes per bucket
#define BMSK    4095
#define NBLK    2048              // k_bin blocks
#define BCAP2   32                // slots per (bucket,block) segment; mean 8, +8.5 sigma
#define BINTH   256
#define BINGRP  (ETOT/4/NBLK)     // 440 int4-groups per block (exact)
#define OVFCAP  8192

// ---- MFMA staging ----
#define ASTR    72                // A row stride (f16): 144B rows (16B-aligned)
#define BSTR    72
#define ASTR0   40                // layer0 A/B stride (f16): 80B rows
#define WKV_OFF 9216              // wkvT offset (f16 elems) inside wcp

typedef _Float16 f16;
typedef _Float16 f16x4 __attribute__((ext_vector_type(4))); // 8B
typedef _Float16 f16x8 __attribute__((ext_vector_type(8))); // 16B
typedef float    f32x4 __attribute__((ext_vector_type(4)));

__device__ __forceinline__ float selu_f(float v){
  const float s  = 1.0507009873554805f;
  const float sa = 1.7580993408473766f;   // scale*alpha
  return v > 0.f ? s*v : sa*(__expf(v)-1.f);
}

// ---------------- pad x[N,13] fp32 -> xf[N,16] fp32; zero dummy rows + ovf cursor ----------------
__global__ __launch_bounds__(256) void k_pad(const float* __restrict__ x,
                                             float* __restrict__ xf,
                                             uint32_t* __restrict__ ha32,
                                             int* __restrict__ ocnt){
  if (blockIdx.x == 0){
    int t = threadIdx.x;
    if (t == 0) *ocnt = 0;
    if (t < 16)            xf[(size_t)ZN*16 + t] = 0.f;       // zero row of xf (== h_b row ZN)
    if (t >= 16 && t < 32) ha32[(size_t)ZN*16 + (t-16)] = 0u; // zero row of h_a
  }
  int i = blockIdx.x*256 + threadIdx.x;   // one float4 per thread, ETOT total (grid exact)
  int node = i>>2, q = i&3;
  const float* r = x + (size_t)node*INCH + q*4;
  float4 v;
  v.x = r[0];
  v.y = (q<3) ? r[1] : 0.f;
  v.z = (q<3) ? r[2] : 0.f;
  v.w = (q<3) ? r[3] : 0.f;
  ((float4*)xf)[i] = v;
}

// ---------------- weight prep: concat+transpose to f16 once ----------------
// wcp layout: [0,1024)            = B0^T[32 oc][32 k]  (k<13: wl0, 16..28: wr0, else 0)
//             [1024 + l*2048 ...) = Bl^T[32 oc][64 k]  (k<32: wl[l], else wr[l])
//             [9216, 11264)       = [Wk|Wv]^T[64 oc][32 k]  (oc<32: wk, else wv)
__global__ __launch_bounds__(256) void k_wprep(
    const float* __restrict__ wl0, const float* __restrict__ wr0,
    const float* __restrict__ wl,  const float* __restrict__ wr,
    const float* __restrict__ wk,  const float* __restrict__ wv,
    f16* __restrict__ wcp)
{
  int t = threadIdx.x;
  for (int i=t; i<1024; i+=256){
    int oc = i>>5, k = i&31;
    float v = 0.f;
    if (k < 13)                 v = wl0[k*HID + oc];
    else if (k >= 16 && k < 29) v = wr0[(k-16)*HID + oc];
    wcp[oc*32 + k] = (f16)v;
  }
  for (int i=t; i<4*2048; i+=256){
    int l = i>>11, r = i&2047, oc = r>>6, k = r&63;
    float v = (k<32) ? wl[l*1024 + k*HID + oc] : wr[l*1024 + (k-32)*HID + oc];
    wcp[1024 + l*2048 + oc*64 + k] = (f16)v;
  }
  for (int i=t; i<2048; i+=256){
    int oc = i>>5, k = i&31;
    float v = (oc < 32) ? wk[k*HID + oc] : wv[k*HID + (oc-32)];
    wcp[WKV_OFF + oc*32 + k] = (f16)v;
  }
}

// ---------------- phase A: bin edges into per-(bucket,block) segments, no global atomics ----------------
__global__ __launch_bounds__(BINTH) void k_bin(
    const int* __restrict__ src, const int* __restrict__ dst,
    uint32_t* __restrict__ binned, int* __restrict__ gcnt,
    uint2* __restrict__ ovf, int* __restrict__ ocnt)
{
  __shared__ int lcnt[NBUCK];
  int t = threadIdx.x, bid = blockIdx.x;
  for (int i=t;i<NBUCK;i+=BINTH) lcnt[i]=0;
  __syncthreads();
  const int4* s4 = (const int4*)src;
  const int4* d4 = (const int4*)dst;
  int g0 = bid*BINGRP;
  for (int i=t; i<BINGRP; i+=BINTH){
    int4 s = s4[g0+i];
    int4 d = d4[g0+i];
    #pragma unroll
    for (int j=0;j<4;j++){
      int dd = (&d.x)[j];
      int ss = (&s.x)[j];
      int b  = dd >> BSH;
      uint32_t entry = (uint32_t)ss | ((uint32_t)(dd & BMSK) << 20);
      int pos = atomicAdd(&lcnt[b], 1);
      if (pos < BCAP2) binned[((size_t)b*NBLK + bid)*BCAP2 + pos] = entry;
      else {                                  // ~1e-10/cell; correctness fallback
        int gp = atomicAdd(ocnt, 1);
        if (gp < OVFCAP) ovf[gp] = make_uint2(entry, (uint32_t)b);
      }
    }
  }
  __syncthreads();
  for (int i=t;i<NBUCK;i+=BINTH){
    int c = lcnt[i]; if (c > BCAP2) c = BCAP2;
    gcnt[bid*NBUCK + i] = c;                  // coalesced per-block row
  }
}

// ---------------- bucket totals (incl. overflow) ----------------
__global__ __launch_bounds__(256) void k_btot(const int* __restrict__ gcnt,
                                              const uint2* __restrict__ ovf,
                                              const int* __restrict__ ocnt,
                                              int* __restrict__ btot){
  __shared__ int sd[256];
  int b = blockIdx.x, t = threadIdx.x;
  int s = 0;
  for (int i=t;i<NBLK;i+=256) s += gcnt[i*NBUCK + b];
  int oc = *ocnt; if (oc > OVFCAP) oc = OVFCAP;
  for (int j=t;j<oc;j+=256) if (ovf[j].y == (uint32_t)b) s++;
  sd[t]=s; __syncthreads();
  for (int o=128;o>0;o>>=1){ if (t<o) sd[t]+=sd[t+o]; __syncthreads(); }
  if (t==0) btot[b]=sd[0];
}

// ---------------- exclusive scan of 220 bucket totals ----------------
__global__ __launch_bounds__(256) void k_bscan(const int* __restrict__ btot,
                                               int* __restrict__ bbase){
  __shared__ int sd[256];
  int t = threadIdx.x;
  int v = (t<NBUCK) ? btot[t] : 0;
  sd[t] = v; __syncthreads();
  for (int o=1;o<256;o<<=1){
    int u = (t>=o) ? sd[t-o] : 0;
    __syncthreads();
    sd[t] += u;
    __syncthreads();
  }
  if (t<NBUCK) bbase[t] = sd[t] - v;
}

// ---------------- phase B: per-bucket counting sort -> off + csrp (L2-local) ----------------
__global__ __launch_bounds__(1024) void k_bucket(
    const uint32_t* __restrict__ binned, const int* __restrict__ gcnt,
    const int* __restrict__ bbase,
    const uint2* __restrict__ ovf, const int* __restrict__ ocnt,
    int* __restrict__ off, uint32_t* __restrict__ csrp)
{
  __shared__ int hist[4096];   // degree counts -> scatter cursors
  __shared__ int cnts[NBLK];
  __shared__ int ws[1024];
  int b = blockIdx.x, t = threadIdx.x;
  int base = bbase[b];
  for (int i=t;i<NBLK;i+=1024) cnts[i] = gcnt[i*NBUCK + b];
  #pragma unroll
  for (int i=0;i<4;i++) hist[t+1024*i] = 0;
  int oc = *ocnt; if (oc > OVFCAP) oc = OVFCAP;
  __syncthreads();

  const uint4* bb4 = (const uint4*)(binned + (size_t)b*(NBLK*BCAP2));
  // pass 1: local-degree histogram
  for (int i=t; i<NBLK*BCAP2/4; i+=1024){
    uint4 e = bb4[i];
    int c = cnts[i>>3];
    int s0 = (i&7)*4;
    if (s0   < c) atomicAdd(&hist[(e.x>>20)&BMSK],1);
    if (s0+1 < c) atomicAdd(&hist[(e.y>>20)&BMSK],1);
    if (s0+2 < c) atomicAdd(&hist[(e.z>>20)&BMSK],1);
    if (s0+3 < c) atomicAdd(&hist[(e.w>>20)&BMSK],1);
  }
  for (int j=t;j<oc;j+=1024){
    uint2 pr = ovf[j];
    if (pr.y == (uint32_t)b) atomicAdd(&hist[(pr.x>>20)&BMSK],1);
  }
  __syncthreads();
  // exclusive scan of 4096 degrees
  int t4 = t*4;
  int s0=hist[t4], s1=hist[t4+1], s2=hist[t4+2], s3=hist[t4+3];
  int sum = s0+s1+s2+s3;
  ws[t] = sum; __syncthreads();
  for (int o=1;o<1024;o<<=1){
    int u = (t>=o) ? ws[t-o] : 0;
    __syncthreads();
    ws[t] += u;
    __syncthreads();
  }
  int ex = ws[t] - sum;
  int p0 = ex, p1 = ex+s0, p2 = ex+s0+s1, p3 = ex+s0+s1+s2;
  hist[t4]=p0; hist[t4+1]=p1; hist[t4+2]=p2; hist[t4+3]=p3;   // cursors
  int4 ov; ov.x = base+p0; ov.y = base+p1; ov.z = base+p2; ov.w = base+p3;
  ((int4*)(off + (b<<BSH)))[t] = ov;
  if (b == NBUCK-1 && t == 1023) off[NTOT] = ETOT;
  __syncthreads();
  // pass 2: scatter to final CSR (256KB window -> single-XCD L2 absorbs)
  for (int i=t; i<NBLK*BCAP2/4; i+=1024){
    uint4 e = bb4[i];
    int c = cnts[i>>3];
    int s0b = (i&7)*4;
    int p;
    if (s0b   < c){ p = atomicAdd(&hist[(e.x>>20)&BMSK],1); csrp[base+p] = e.x & 0xFFFFFu; }
    if (s0b+1 < c){ p = atomicAdd(&hist[(e.y>>20)&BMSK],1); csrp[base+p] = e.y & 0xFFFFFu; }
    if (s0b+2 < c){ p = atomicAdd(&hist[(e.z>>20)&BMSK],1); csrp[base+p] = e.z & 0xFFFFFu; }
    if (s0b+3 < c){ p = atomicAdd(&hist[(e.w>>20)&BMSK],1); csrp[base+p] = e.w & 0xFFFFFu; }
  }
  for (int j=t;j<oc;j+=1024){
    uint2 pr = ovf[j];
    if (pr.y == (uint32_t)b){
      int p = atomicAdd(&hist[(pr.x>>20)&BMSK],1);
      csrp[base+p] = pr.x & 0xFFFFFu;
    }
  }
}

// ---------------- fused SAGE layer 0 (gather + MFMA, K=32) ----------------
__global__ __launch_bounds__(256,8) void k_layer0(
    const float* __restrict__ xf,
    const int* __restrict__ off, const uint32_t* __restrict__ csrp,
    const f16* __restrict__ wcat0, const float* __restrict__ bl0,
    f16* __restrict__ hout)
{
  __shared__ uint32_t ALDS[NPB*(ASTR0/2)];   // 10240B: A[128][40] f16 = [mean16|x16]; reused as ST
  __shared__ uint32_t BLDS[32*(ASTR0/2)];    // 2560B:  B0^T[32][40] f16
  __shared__ uint32_t EL[ECAP];              // 3072B
  __shared__ int      sOFF[NPB+2];
  __shared__ float    biasL[32];
  int t = threadIdx.x;
  int base = blockIdx.x*NPB;
  int e0 = off[base];
  int e1 = off[base+NPB];
  for (int i=t; i<NPB+1; i+=256) sOFF[i] = off[base+i];
  {
    int lim = (e1-e0) < ECAP ? (e1-e0) : ECAP;
    for (int i=t; i<lim; i+=256) EL[i] = csrp[e0+i];
  }
  if (t < 128){
    int oc = t>>2, kq = (t&3)*8;
    f16x8 wv = *(const f16x8*)(wcat0 + oc*32 + kq);
    *(f16x8*)((f16*)BLDS + oc*ASTR0 + kq) = wv;
  }
  if (t < 32) biasL[t] = bl0[t];
  __syncthreads();   // staging (sOFF/EL/BLDS/bias) visible before gather reads

  // gather: 4 lanes per node (float4 = 4 ch each); masked slots -> zero row ZN
  int c4 = t & 3;
  #pragma unroll
  for (int p=0;p<2;p++){
    int nl = p*64 + (t>>2);
    int node = base + nl;
    float4 xown = *((const float4*)(xf + (size_t)node*16) + c4);
    int s = sOFF[nl] - e0;
    int d = sOFF[nl+1] - sOFF[nl];
    float a0=0.f,a1=0.f,a2=0.f,a3=0.f;
    for (int i=0;i<d;i+=4){
      int j0 = s+i;
      uint32_t k0,k1,k2,k3;
      if (j0+3 < ECAP){ k0=EL[j0]; k1=EL[j0+1]; k2=EL[j0+2]; k3=EL[j0+3]; }
      else            { k0=csrp[e0+j0]; k1=csrp[e0+j0+1]; k2=csrp[e0+j0+2]; k3=csrp[e0+j0+3]; }
      k1 = (i+1<d)?k1:(uint32_t)ZN;
      k2 = (i+2<d)?k2:(uint32_t)ZN;
      k3 = (i+3<d)?k3:(uint32_t)ZN;
      float4 g0 = *((const float4*)(xf + (size_t)k0*16u) + c4);
      float4 g1 = *((const float4*)(xf + (size_t)k1*16u) + c4);
      float4 g2 = *((const float4*)(xf + (size_t)k2*16u) + c4);
      float4 g3 = *((const float4*)(xf + (size_t)k3*16u) + c4);
      a0 += (g0.x+g1.x)+(g2.x+g3.x);
      a1 += (g0.y+g1.y)+(g2.y+g3.y);
      a2 += (g0.z+g1.z)+(g2.z+g3.z);
      a3 += (g0.w+g1.w)+(g2.w+g3.w);
    }
    float inv = 1.f/(float)(d<1?1:d);
    union { f16 h[4]; uint32_t u[2]; } mp, xp;
    mp.h[0]=(f16)(a0*inv); mp.h[1]=(f16)(a1*inv); mp.h[2]=(f16)(a2*inv); mp.h[3]=(f16)(a3*inv);
    xp.h[0]=(f16)xown.x;   xp.h[1]=(f16)xown.y;   xp.h[2]=(f16)xown.z;   xp.h[3]=(f16)xown.w;
    uint32_t* arow = &ALDS[nl*(ASTR0/2)];
    *((uint2*)&arow[2*c4])     = make_uint2(mp.u[0], mp.u[1]);   // mean cols 4c4..
    *((uint2*)&arow[8 + 2*c4]) = make_uint2(xp.u[0], xp.u[1]);   // x cols 16+4c4..
  }
  __syncthreads();

  // MFMA: wave w owns rows 32w..32w+31, cols 0..31; single K=32 step
  int w = t>>6, l = t&63;
  int lrow = l&15, lg = l>>4;
  const f16* Af = (const f16*)ALDS;
  const f16* Bf = (const f16*)BLDS;
  f32x4 D00={0.f,0.f,0.f,0.f}, D01=D00, D10=D00, D11=D00;
  {
    f16x8 af0 = *(const f16x8*)(Af + (32*w+lrow)*ASTR0    + 8*lg);
    f16x8 af1 = *(const f16x8*)(Af + (32*w+16+lrow)*ASTR0 + 8*lg);
    f16x8 bf0 = *(const f16x8*)(Bf + lrow*ASTR0           + 8*lg);
    f16x8 bf1 = *(const f16x8*)(Bf + (16+lrow)*ASTR0      + 8*lg);
    D00 = __builtin_amdgcn_mfma_f32_16x16x32_f16(af0, bf0, D00, 0,0,0);
    D01 = __builtin_amdgcn_mfma_f32_16x16x32_f16(af0, bf1, D01, 0,0,0);
    D10 = __builtin_amdgcn_mfma_f32_16x16x32_f16(af1, bf0, D10, 0,0,0);
    D11 = __builtin_amdgcn_mfma_f32_16x16x32_f16(af1, bf1, D11, 0,0,0);
  }
  __syncthreads();       // all frag reads done -> ALDS reusable as ST

  f16* ST = (f16*)ALDS;  // [128][34] f16 staging
  #pragma unroll
  for (int j=0;j<4;j++){
    int r0 = 32*w + 4*lg + j, r1 = r0 + 16;
    ST[r0*34 + lrow]      = (f16)selu_f(D00[j] + biasL[lrow]);
    ST[r0*34 + 16 + lrow] = (f16)selu_f(D01[j] + biasL[16+lrow]);
    ST[r1*34 + lrow]      = (f16)selu_f(D10[j] + biasL[lrow]);
    ST[r1*34 + 16 + lrow] = (f16)selu_f(D11[j] + biasL[16+lrow]);
  }
  __syncthreads();

  const uint32_t* STd = (const uint32_t*)ALDS;
  uint4* ho4 = (uint4*)hout;
  int gbase = blockIdx.x*(NPB*HID/8);   // 512 16B-chunks per block
  #pragma unroll
  for (int k=0;k<2;k++){
    int cch = t + 256*k;
    int n = cch>>2, m = cch&3;
    int dd = n*17 + m*4;
    uint4 u;
    u.x=STd[dd]; u.y=STd[dd+1]; u.z=STd[dd+2]; u.w=STd[dd+3];
    ho4[gbase+cch] = u;   // jk no longer duplicated here (layer1 initializes it)
  }
}

// ---------------- fused SAGE layers 1..4 (gather + MFMA, K=64) ----------------
// mode 0 (layer 1): jk := max(hin_own, h_new)  — reads hin chunks (L2-hot), not jkio
// mode 1 (layers 2..3): jk := max(jkio, h_new)
// mode 2 (layer 4): write ONLY jk (h_new never consumed except via jk)
__global__ __launch_bounds__(256,6) void k_layer(
    const f16* __restrict__ hin,
    const int* __restrict__ off, const uint32_t* __restrict__ csrp,
    const f16* __restrict__ wcat, const float* __restrict__ bl,
    f16* __restrict__ hout, f16* __restrict__ jkio, int mode)
{
  __shared__ uint32_t ALDS[NPB*(ASTR/2)];    // 18432B: A[128][72] f16 = [mean32|h32]; reused as ST
  __shared__ uint32_t BLDS[32*(BSTR/2)];     // 4608B:  B^T[32][72] f16
  __shared__ uint32_t EL[ECAP];              // 3072B
  __shared__ int      sOFF[NPB+2];
  __shared__ float    biasL[32];
  int t = threadIdx.x;
  int base = blockIdx.x*NPB;
  int e0 = off[base];
  int e1 = off[base+NPB];
  for (int i=t; i<NPB+1; i+=256) sOFF[i] = off[base+i];
  {
    int lim = (e1-e0) < ECAP ? (e1-e0) : ECAP;
    for (int i=t; i<lim; i+=256) EL[i] = csrp[e0+i];
  }
  if (t < 128){
    int oc = t>>2, kq = (t&3)*8;               // 4 chunks of 8 f16 per row
    f16x8 wv0 = *(const f16x8*)(wcat + oc*64 + kq);
    f16x8 wv1 = *(const f16x8*)(wcat + oc*64 + 32 + kq);
    *(f16x8*)((f16*)BLDS + oc*BSTR + kq)      = wv0;
    *(f16x8*)((f16*)BLDS + oc*BSTR + 32 + kq) = wv1;
  }
  if (t < 32) biasL[t] = bl[t];
  __syncthreads();   // staging (sOFF/EL/BLDS/bias) visible before gather reads

  // gather: 4 lanes per node (f16x8 = 8 ch each); masked slots -> zero row ZN
  int c4 = t & 3;
  #pragma unroll
  for (int p=0;p<2;p++){
    int nl = p*64 + (t>>2);
    int node = base + nl;
    f16x8 hown = *(const f16x8*)(hin + (size_t)node*HID + 8u*c4);
    int s = sOFF[nl] - e0;
    int d = sOFF[nl+1] - sOFF[nl];
    float a[8];
    #pragma unroll
    for (int r=0;r<8;r++) a[r]=0.f;
    for (int i=0;i<d;i+=4){
      int j0 = s+i;
      uint32_t k0,k1,k2,k3;
      if (j0+3 < ECAP){ k0=EL[j0]; k1=EL[j0+1]; k2=EL[j0+2]; k3=EL[j0+3]; }
      else            { k0=csrp[e0+j0]; k1=csrp[e0+j0+1]; k2=csrp[e0+j0+2]; k3=csrp[e0+j0+3]; }
      k1 = (i+1<d)?k1:(uint32_t)ZN;
      k2 = (i+2<d)?k2:(uint32_t)ZN;
      k3 = (i+3<d)?k3:(uint32_t)ZN;
      f16x8 g0 = *((const f16x8*)(hin + (size_t)k0*32u) + c4);
      f16x8 g1 = *((const f16x8*)(hin + (size_t)k1*32u) + c4);
      f16x8 g2 = *((const f16x8*)(hin + (size_t)k2*32u) + c4);
      f16x8 g3 = *((const f16x8*)(hin + (size_t)k3*32u) + c4);
      #pragma unroll
      for (int r=0;r<8;r++)
        a[r] += ((float)g0[r]+(float)g1[r]) + ((float)g2[r]+(float)g3[r]);
    }
    float inv = 1.f/(float)(d<1?1:d);
    union { f16 h[8]; uint4 v; } mp;
    #pragma unroll
    for (int r=0;r<8;r++) mp.h[r] = (f16)(a[r]*inv);
    uint32_t* arow = &ALDS[nl*(ASTR/2)];
    *((uint4*)&arow[4*c4]) = mp.v;                          // mean cols 8c4..
    *((f16x8*)((f16*)arow + 32 + 8*c4)) = hown;             // h cols 32+8c4..
  }
  __syncthreads();

  // MFMA: wave w owns rows 32w..32w+31, cols 0..31; two K=32 steps
  int w = t>>6, l = t&63;
  int lrow = l&15, lg = l>>4;
  const f16* Af = (const f16*)ALDS;
  const f16* Bf = (const f16*)BLDS;
  f32x4 D00={0.f,0.f,0.f,0.f}, D01=D00, D10=D00, D11=D00;
  #pragma unroll
  for (int s2=0;s2<2;s2++){
    f16x8 af0 = *(const f16x8*)(Af + (32*w+lrow)*ASTR    + 32*s2 + 8*lg);
    f16x8 af1 = *(const f16x8*)(Af + (32*w+16+lrow)*ASTR + 32*s2 + 8*lg);
    f16x8 bf0 = *(const f16x8*)(Bf + lrow*BSTR           + 32*s2 + 8*lg);
    f16x8 bf1 = *(const f16x8*)(Bf + (16+lrow)*BSTR      + 32*s2 + 8*lg);
    D00 = __builtin_amdgcn_mfma_f32_16x16x32_f16(af0, bf0, D00, 0,0,0);
    D01 = __builtin_amdgcn_mfma_f32_16x16x32_f16(af0, bf1, D01, 0,0,0);
    D10 = __builtin_amdgcn_mfma_f32_16x16x32_f16(af1, bf0, D10, 0,0,0);
    D11 = __builtin_amdgcn_mfma_f32_16x16x32_f16(af1, bf1, D11, 0,0,0);
  }
  __syncthreads();       // all frag reads done -> ALDS reusable as ST

  f16* ST = (f16*)ALDS;  // [128][34] f16 staging
  #pragma unroll
  for (int j=0;j<4;j++){
    int r0 = 32*w + 4*lg + j, r1 = r0 + 16;
    ST[r0*34 + lrow]      = (f16)selu_f(D00[j] + biasL[lrow]);
    ST[r0*34 + 16 + lrow] = (f16)selu_f(D01[j] + biasL[16+lrow]);
    ST[r1*34 + lrow]      = (f16)selu_f(D10[j] + biasL[lrow]);
    ST[r1*34 + 16 + lrow] = (f16)selu_f(D11[j] + biasL[16+lrow]);
  }
  __syncthreads();

  const uint32_t* STd = (const uint32_t*)ALDS;
  uint4* ho4 = (uint4*)hout;
  uint4* jo4 = (uint4*)jkio;
  const uint4* hi4 = (const uint4*)hin;   // mode 0: jk seed = own h_in (L2-hot)
  int gbase = blockIdx.x*(NPB*HID/8);
  #pragma unroll
  for (int k=0;k<2;k++){
    int cch = t + 256*k;
    int n = cch>>2, m = cch&3;
    int dd = n*17 + m*4;
    union { uint4 u; f16 hh[8]; } hv, jv;
    hv.u.x=STd[dd]; hv.u.y=STd[dd+1]; hv.u.z=STd[dd+2]; hv.u.w=STd[dd+3];
    jv.u = (mode == 0) ? hi4[gbase+cch] : jo4[gbase+cch];
    #pragma unroll
    for (int r=0;r<8;r++){
      f16 a = jv.hh[r], b = hv.hh[r];
      jv.hh[r] = (b > a) ? b : a;       // f16 max: exact (selects one of two f16 values)
    }
    if (mode != 2) ho4[gbase+cch] = hv.u;
    jo4[gbase+cch] = jv.u;
  }
}

// ---------------- attention + head, one block per graph (MFMA K/V, slim LDS) ----------------
__global__ __launch_bounds__(256) void k_attn(
    const f16* __restrict__ jk, const float* __restrict__ x,
    const int* __restrict__ shuf, const f16* __restrict__ wkvT,
    const float* __restrict__ wq, const float* __restrict__ bq,
    const float* __restrict__ bk, const float* __restrict__ bv,
    const float* __restrict__ wo, const float* __restrict__ bo,
    const float* __restrict__ wfc, const float* __restrict__ bfc,
    float* __restrict__ out)
{
  __shared__ alignas(16) f16 Ah[64*40];   // 5120B: H=selu(jk) f16; rows 55..63 garbage (discarded)
  __shared__ float K[NODES*33];           // 7260B
  __shared__ float V[NODES*33];           // 7260B
  __shared__ float Qs[6*33];
  __shared__ float S[6*56];
  __shared__ float O[6*33];
  __shared__ float SO[192];
  __shared__ float part[96];
  __shared__ int   sel[8];

  int g = blockIdx.x, t = threadIdx.x;

  // stage H = selu(jk) as f16 into A-tile (rows=nodes, 40-f16 stride)
  {
    const f16x8* j8 = (const f16x8*)(jk + (size_t)g*NODES*HID);
    for (int i=t; i<NODES*HID/8; i+=256){   // 220 vectors of 8
      f16x8 v = j8[i];
      int node = i >> 2, c0 = (i & 3)*8;
      f16x8 hv;
      #pragma unroll
      for (int r=0;r<8;r++) hv[r] = (f16)selu_f((float)v[r]);
      *(f16x8*)(Ah + node*40 + c0) = hv;
    }
  }
  // wave 0: neighbor-mask ballot -> sel (no serial loop)
  if (t < 64){
    float mv = (t < NODES) ? x[(size_t)(g*NODES+t)*INCH + (INCH-3)] : 0.f;
    unsigned long long mb = __ballot(mv > 0.5f);
    if (t < 6){
      int kk = shuf[g*6 + t];
      for (int i2=0;i2<kk;i2++) mb &= (mb - 1ull);
      sel[t] = (int)__builtin_ctzll(mb);
    }
  }
  __syncthreads();

  // K/V projection via MFMA: [64x32] H @ [32x64] (Wk|Wv), wave w = row-tile w
  {
    int w = t>>6, l = t&63;
    int lrow = l&15, lg = l>>4;
    f16x8 af = *(const f16x8*)(Ah + (16*w + lrow)*40 + 8*lg);
    #pragma unroll
    for (int ct=0; ct<4; ct++){
      f16x8 bf = *(const f16x8*)(wkvT + (16*ct + lrow)*32 + 8*lg);  // global, L2-resident
      f32x4 D = {0.f,0.f,0.f,0.f};
      D = __builtin_amdgcn_mfma_f32_16x16x32_f16(af, bf, D, 0,0,0);
      int ocl = 16*(ct&1) + lrow;
      float bias = (ct < 2) ? bk[ocl] : bv[ocl];
      float* dst = (ct < 2) ? K : V;
      #pragma unroll
      for (int j=0;j<4;j++){
        int node = 16*w + 4*lg + j;
        if (node < NODES) dst[node*33 + ocl] = D[j] + bias;
      }
    }
  }
  // Q projection (6x32, VALU; wq from global - cache-resident)
  if (t < 192){
    int q = t>>5, oc = t&31;
    int node = sel[q];
    const f16x8* hr8 = (const f16x8*)(Ah + node*40);
    float a = bq[oc];
    #pragma unroll
    for (int cc=0;cc<4;cc++){
      f16x8 hv = hr8[cc];
      #pragma unroll
      for (int r=0;r<8;r++) a = fmaf((float)hv[r], wq[(8*cc+r)*HID + oc], a);
    }
    Qs[q*33+oc] = a;
  }
  __syncthreads();

  // scores = Q.K^T / sqrt(32)
  for (int idx=t; idx<6*NODES; idx+=256){
    int q = idx % 6, k = idx / 6;
    float a = 0.f;
    #pragma unroll
    for (int c=0;c<HID;c++) a = fmaf(Qs[q*33+c], K[k*33+c], a);
    S[q*56+k] = a * 0.17677669529663687f;
  }
  __syncthreads();

  // softmax over 55 keys: 32-lane group per query
  if (t < 192){
    int q = t>>5, l = t&31;
    float v0 = (l      < NODES) ? S[q*56+l]    : -1e30f;
    float v1 = (l+32   < NODES) ? S[q*56+l+32] : -1e30f;
    float mx = fmaxf(v0, v1);
    #pragma unroll
    for (int o=16;o>0;o>>=1) mx = fmaxf(mx, __shfl_xor(mx, o, 32));
    float p0 = (l    < NODES) ? __expf(v0-mx) : 0.f;
    float p1 = (l+32 < NODES) ? __expf(v1-mx) : 0.f;
    float sm = p0 + p1;
    #pragma unroll
    for (int o=16;o>0;o>>=1) sm += __shfl_xor(sm, o, 32);
    float inv = 1.f/sm;
    if (l    < NODES) S[q*56+l]    = p0*inv;
    if (l+32 < NODES) S[q*56+l+32] = p1*inv;
  }
  __syncthreads();

  // attn @ V
  if (t < 192){
    int q = t>>5, oc = t&31;
    float a = 0.f;
    for (int k=0;k<NODES;k++) a = fmaf(S[q*56+k], V[k*33+oc], a);
    O[q*33+oc] = a;
  }
  __syncthreads();

  // @ wo + bo, selu  (wo from global - cache-resident, 6x reuse per block)
  if (t < 192){
    int q = t>>5, oc = t&31;
    float a = bo[oc];
    #pragma unroll
    for (int c=0;c<HID;c++) a = fmaf(O[q*33+c], wo[c*HID+oc], a);
    SO[t] = selu_f(a);   // t == q*32+oc == flat reshape index
  }
  __syncthreads();

  // final FC: 6 outputs = SO[192] . Wfc[:,j]
  if (t < 96){
    int j = t % 6, pp = t / 6;   // 16 partials per output
    float a = 0.f;
    #pragma unroll
    for (int r=0;r<12;r++) a = fmaf(SO[pp*12+r], wfc[(pp*12+r)*6+j], a);
    part[pp*6+j] = a;
  }
  __syncthreads();
  if (t < 6){
    float a = bfc[t];
    #pragma unroll
    for (int pp=0;pp<16;pp++) a += part[pp*6+t];
    out[g*6+t] = a;
  }
}

extern "C" void kernel_launch(void* const* d_in, const int* in_sizes, int n_in,
                              void* d_out, int out_size, void* d_ws, size_t ws_size,
                              hipStream_t stream)
{
  const float* x   = (const float*)d_in[0];
  const int*   eix = (const int*)d_in[1];
  const int*   shf = (const int*)d_in[2];
  const float* wl0 = (const float*)d_in[3];
  const float* bl0 = (const float*)d_in[4];
  const float* wr0 = (const float*)d_in[5];
  const float* wl  = (const float*)d_in[6];
  const float* bl  = (const float*)d_in[7];
  const float* wr  = (const float*)d_in[8];
  const float* wq  = (const float*)d_in[9];
  const float* bq  = (const float*)d_in[10];
  const float* wk  = (const float*)d_in[11];
  const float* bk  = (const float*)d_in[12];
  const float* wv  = (const float*)d_in[13];
  const float* bv  = (const float*)d_in[14];
  const float* wo  = (const float*)d_in[15];
  const float* bo  = (const float*)d_in[16];
  const float* wfc = (const float*)d_in[17];
  const float* bfc = (const float*)d_in[18];
  float* out = (float*)d_out;

  const int* esrc = eix;
  const int* edst = eix + ETOT;

  // workspace carve
  char* p = (char*)d_ws;
  auto carve = [&](size_t bytes){ void* r = (void*)p; p += (bytes + 255) & ~(size_t)255; return r; };
  int*      off   = (int*)carve(sizeof(int)*(NTOT+1));
  int*      gcnt  = (int*)carve(sizeof(int)*(size_t)NBLK*NBUCK);   // 1.8 MB
  int*      btot  = (int*)carve(sizeof(int)*256);
  int*      bbase = (int*)carve(sizeof(int)*256);
  uint2*    ovf   = (uint2*)carve(sizeof(uint2)*OVFCAP);
  int*      ocnt  = (int*)carve(sizeof(int)*64);
  f16*      wcp   = (f16*)carve(sizeof(f16)*(WKV_OFF + 2048));
  uint32_t* csrp  = (uint32_t*)carve(sizeof(uint32_t)*((size_t)ETOT + 64));
  f16*      h_a   = (f16*)carve(2*((size_t)NTOT+1)*HID);   // +1 zero row (index ZN)
  f16*      h_b   = (f16*)carve(2*((size_t)NTOT+1)*HID);   // +1 zero row
  f16*      jk16  = (f16*)carve(2*(size_t)NTOT*HID);

  // aliases over dead regions:
  float*    xf     = (float*)h_b;       // padded x [NTOT+1][16] f32, dead after k_layer0
  uint32_t* binned = (uint32_t*)h_a;    // 220*2048*32*4 = 57,671,680 B = NTOT*64 (row ZN untouched)

  k_pad   <<<ETOT/256,  256, 0, stream>>>(x, xf, (uint32_t*)h_a, ocnt);
  k_wprep <<<1,         256, 0, stream>>>(wl0, wr0, wl, wr, wk, wv, wcp);
  k_bin   <<<NBLK,    BINTH, 0, stream>>>(esrc, edst, binned, gcnt, ovf, ocnt);
  k_btot  <<<NBUCK,     256, 0, stream>>>(gcnt, ovf, ocnt, btot);
  k_bscan <<<1,         256, 0, stream>>>(btot, bbase);
  k_bucket<<<NBUCK,    1024, 0, stream>>>(binned, gcnt, bbase, ovf, ocnt, off, csrp);

  k_layer0<<<NTOT/NPB, 256, 0, stream>>>(xf, off, csrp, wcp, bl0, h_a);
  f16* hc = h_a; f16* hn = h_b;
  for (int l=0; l<4; l++){
    int mode = (l == 0) ? 0 : ((l == 3) ? 2 : 1);
    k_layer<<<NTOT/NPB, 256, 0, stream>>>(hc, off, csrp,
                                          wcp + 1024 + l*2048, bl + l*HID,
                                          hn, jk16, mode);
    f16* tmp = hc; hc = hn; hn = tmp;
  }
  k_attn<<<BGRAPH, 256, 0, stream>>>(jk16, x, shf, wcp + WKV_OFF,
                                     wq, bq, bk, bv, wo, bo, wfc, bfc, out);
}

// Round 9
// 811.342 us; speedup vs baseline: 4.7530x; 1.0163x over previous
//
#include <hip/hip_runtime.h>
#include <cstdint>
#include <cstddef>

#define NODES   55
#define BGRAPH  16384
#define NTOT    (BGRAPH*NODES)    // 901120
#define INCH    13
#define HID     32
#define ETOT    (4*NTOT)          // 3604480
#define NPB     128               // nodes per block (layer kernels)
#define ECAP    768               // LDS edge-list capacity (mean 512, +11 sigma; global fallback)
#define ZN      NTOT              // dummy zero-row index for masked edge slots

// ---- deterministic binned CSR build ----
#define NBUCK   220               // NTOT/4096 buckets
#define BSH     12                // 4096 nodes per bucket
#define BMSK    4095
#define NBLK    2048              // k_bin blocks
#define BCAP2   32                // slots per (bucket,block) segment; mean 8, +8.5 sigma
#define BINTH   256
#define BINGRP  (ETOT/4/NBLK)     // 440 int4-groups per block (exact)
#define OVFCAP  8192

// ---- MFMA staging ----
#define ASTR    72                // A row stride (f16): 144B rows (16B-aligned)
#define BSTR    72
#define ASTR0   40                // layer0 A/B stride (f16): 80B rows
#define WKV_OFF 9216              // wkvT offset (f16 elems) inside wcp

// ---- jk folding modes ----
#define MODE_A  0   // L1: jk := max(hin_own, h_new); write hout
#define MODE_D  2   // L4: jk := max(jk, h_new); NO hout
#define MODE_B  3   // L2: no jk at all; write hout
#define MODE_C  4   // L3: jk := max(jk, hin_own, h_new); write hout

typedef _Float16 f16;
typedef _Float16 f16x4 __attribute__((ext_vector_type(4))); // 8B
typedef _Float16 f16x8 __attribute__((ext_vector_type(8))); // 16B
typedef float    f32x4 __attribute__((ext_vector_type(4)));
typedef uint32_t u32x4 __attribute__((ext_vector_type(4))); // 16B (nt-capable)

__device__ __forceinline__ float selu_f(float v){
  const float s  = 1.0507009873554805f;
  const float sa = 1.7580993408473766f;   // scale*alpha
  return v > 0.f ? s*v : sa*(__expf(v)-1.f);
}

// ---------------- pad x[N,13] fp32 -> xh[N,16] f16 (32B rows); zero dummy rows + ovf cursor ----------------
__global__ __launch_bounds__(256) void k_pad(const float* __restrict__ x,
                                             f16* __restrict__ xh,
                                             f16* __restrict__ ha,
                                             f16* __restrict__ hb,
                                             int* __restrict__ ocnt){
  if (blockIdx.x == 0){
    int t = threadIdx.x;
    if (t == 0) *ocnt = 0;
    if (t < 16)                  xh[(size_t)ZN*16 + t]      = (f16)0.f;  // zero row of xh
    else if (t >= 16 && t < 48)  ha[(size_t)ZN*32 + (t-16)] = (f16)0.f;  // zero row of h_a
    else if (t >= 48 && t < 80)  hb[(size_t)ZN*32 + (t-48)] = (f16)0.f;  // zero row of h_b
  }
  int i = blockIdx.x*256 + threadIdx.x;   // one f16x4 per thread, ETOT total (grid exact)
  int node = i>>2, q = i&3;
  const float* r = x + (size_t)node*INCH + q*4;
  f16x4 v;
  v[0] = (f16)r[0];
  v[1] = (q<3) ? (f16)r[1] : (f16)0.f;
  v[2] = (q<3) ? (f16)r[2] : (f16)0.f;
  v[3] = (q<3) ? (f16)r[3] : (f16)0.f;
  *(f16x4*)(xh + (size_t)node*16 + q*4) = v;
}

// ---------------- weight prep: concat+transpose to f16 once ----------------
// wcp layout: [0,1024)            = B0^T[32 oc][32 k]  (k<13: wl0, 16..28: wr0, else 0)
//             [1024 + l*2048 ...) = Bl^T[32 oc][64 k]  (k<32: wl[l], else wr[l])
//             [9216, 11264)       = [Wk|Wv]^T[64 oc][32 k]  (oc<32: wk, else wv)
__global__ __launch_bounds__(256) void k_wprep(
    const float* __restrict__ wl0, const float* __restrict__ wr0,
    const float* __restrict__ wl,  const float* __restrict__ wr,
    const float* __restrict__ wk,  const float* __restrict__ wv,
    f16* __restrict__ wcp)
{
  int t = threadIdx.x;
  for (int i=t; i<1024; i+=256){
    int oc = i>>5, k = i&31;
    float v = 0.f;
    if (k < 13)                 v = wl0[k*HID + oc];
    else if (k >= 16 && k < 29) v = wr0[(k-16)*HID + oc];
    wcp[oc*32 + k] = (f16)v;
  }
  for (int i=t; i<4*2048; i+=256){
    int l = i>>11, r = i&2047, oc = r>>6, k = r&63;
    float v = (k<32) ? wl[l*1024 + k*HID + oc] : wr[l*1024 + (k-32)*HID + oc];
    wcp[1024 + l*2048 + oc*64 + k] = (f16)v;
  }
  for (int i=t; i<2048; i+=256){
    int oc = i>>5, k = i&31;
    float v = (oc < 32) ? wk[k*HID + oc] : wv[k*HID + (oc-32)];
    wcp[WKV_OFF + oc*32 + k] = (f16)v;
  }
}

// ---------------- phase A: bin edges into per-(bucket,block) segments, no global atomics ----------------
__global__ __launch_bounds__(BINTH) void k_bin(
    const int* __restrict__ src, const int* __restrict__ dst,
    uint32_t* __restrict__ binned, int* __restrict__ gcnt,
    uint2* __restrict__ ovf, int* __restrict__ ocnt)
{
  __shared__ int lcnt[NBUCK];
  int t = threadIdx.x, bid = blockIdx.x;
  for (int i=t;i<NBUCK;i+=BINTH) lcnt[i]=0;
  __syncthreads();
  const int4* s4 = (const int4*)src;
  const int4* d4 = (const int4*)dst;
  int g0 = bid*BINGRP;
  for (int i=t; i<BINGRP; i+=BINTH){
    int4 s = s4[g0+i];
    int4 d = d4[g0+i];
    #pragma unroll
    for (int j=0;j<4;j++){
      int dd = (&d.x)[j];
      int ss = (&s.x)[j];
      int b  = dd >> BSH;
      uint32_t entry = (uint32_t)ss | ((uint32_t)(dd & BMSK) << 20);
      int pos = atomicAdd(&lcnt[b], 1);
      if (pos < BCAP2) binned[((size_t)b*NBLK + bid)*BCAP2 + pos] = entry;
      else {                                  // ~1e-10/cell; correctness fallback
        int gp = atomicAdd(ocnt, 1);
        if (gp < OVFCAP) ovf[gp] = make_uint2(entry, (uint32_t)b);
      }
    }
  }
  __syncthreads();
  for (int i=t;i<NBUCK;i+=BINTH){
    int c = lcnt[i]; if (c > BCAP2) c = BCAP2;
    gcnt[bid*NBUCK + i] = c;                  // coalesced per-block row
  }
}

// ---------------- bucket totals (incl. overflow) ----------------
__global__ __launch_bounds__(256) void k_btot(const int* __restrict__ gcnt,
                                              const uint2* __restrict__ ovf,
                                              const int* __restrict__ ocnt,
                                              int* __restrict__ btot){
  __shared__ int sd[256];
  int b = blockIdx.x, t = threadIdx.x;
  int s = 0;
  for (int i=t;i<NBLK;i+=256) s += gcnt[i*NBUCK + b];
  int oc = *ocnt; if (oc > OVFCAP) oc = OVFCAP;
  for (int j=t;j<oc;j+=256) if (ovf[j].y == (uint32_t)b) s++;
  sd[t]=s; __syncthreads();
  for (int o=128;o>0;o>>=1){ if (t<o) sd[t]+=sd[t+o]; __syncthreads(); }
  if (t==0) btot[b]=sd[0];
}

// ---------------- exclusive scan of 220 bucket totals ----------------
__global__ __launch_bounds__(256) void k_bscan(const int* __restrict__ btot,
                                               int* __restrict__ bbase){
  __shared__ int sd[256];
  int t = threadIdx.x;
  int v = (t<NBUCK) ? btot[t] : 0;
  sd[t] = v; __syncthreads();
  for (int o=1;o<256;o<<=1){
    int u = (t>=o) ? sd[t-o] : 0;
    __syncthreads();
    sd[t] += u;
    __syncthreads();
  }
  if (t<NBUCK) bbase[t] = sd[t] - v;
}

// ---------------- phase B: per-bucket counting sort -> off + csrp (L2-local) ----------------
__global__ __launch_bounds__(1024) void k_bucket(
    const uint32_t* __restrict__ binned, const int* __restrict__ gcnt,
    const int* __restrict__ bbase,
    const uint2* __restrict__ ovf, const int* __restrict__ ocnt,
    int* __restrict__ off, uint32_t* __restrict__ csrp)
{
  __shared__ int hist[4096];   // degree counts -> scatter cursors
  __shared__ int cnts[NBLK];
  __shared__ int ws[1024];
  int b = blockIdx.x, t = threadIdx.x;
  int base = bbase[b];
  for (int i=t;i<NBLK;i+=1024) cnts[i] = gcnt[i*NBUCK + b];
  #pragma unroll
  for (int i=0;i<4;i++) hist[t+1024*i] = 0;
  int oc = *ocnt; if (oc > OVFCAP) oc = OVFCAP;
  __syncthreads();

  const uint4* bb4 = (const uint4*)(binned + (size_t)b*(NBLK*BCAP2));
  // pass 1: local-degree histogram
  for (int i=t; i<NBLK*BCAP2/4; i+=1024){
    uint4 e = bb4[i];
    int c = cnts[i>>3];
    int s0 = (i&7)*4;
    if (s0   < c) atomicAdd(&hist[(e.x>>20)&BMSK],1);
    if (s0+1 < c) atomicAdd(&hist[(e.y>>20)&BMSK],1);
    if (s0+2 < c) atomicAdd(&hist[(e.z>>20)&BMSK],1);
    if (s0+3 < c) atomicAdd(&hist[(e.w>>20)&BMSK],1);
  }
  for (int j=t;j<oc;j+=1024){
    uint2 pr = ovf[j];
    if (pr.y == (uint32_t)b) atomicAdd(&hist[(pr.x>>20)&BMSK],1);
  }
  __syncthreads();
  // exclusive scan of 4096 degrees
  int t4 = t*4;
  int s0=hist[t4], s1=hist[t4+1], s2=hist[t4+2], s3=hist[t4+3];
  int sum = s0+s1+s2+s3;
  ws[t] = sum; __syncthreads();
  for (int o=1;o<1024;o<<=1){
    int u = (t>=o) ? ws[t-o] : 0;
    __syncthreads();
    ws[t] += u;
    __syncthreads();
  }
  int ex = ws[t] - sum;
  int p0 = ex, p1 = ex+s0, p2 = ex+s0+s1, p3 = ex+s0+s1+s2;
  hist[t4]=p0; hist[t4+1]=p1; hist[t4+2]=p2; hist[t4+3]=p3;   // cursors
  int4 ov; ov.x = base+p0; ov.y = base+p1; ov.z = base+p2; ov.w = base+p3;
  ((int4*)(off + (b<<BSH)))[t] = ov;
  if (b == NBUCK-1 && t == 1023) off[NTOT] = ETOT;
  __syncthreads();
  // pass 2: scatter to final CSR (256KB window -> single-XCD L2 absorbs)
  for (int i=t; i<NBLK*BCAP2/4; i+=1024){
    uint4 e = bb4[i];
    int c = cnts[i>>3];
    int s0b = (i&7)*4;
    int p;
    if (s0b   < c){ p = atomicAdd(&hist[(e.x>>20)&BMSK],1); csrp[base+p] = e.x & 0xFFFFFu; }
    if (s0b+1 < c){ p = atomicAdd(&hist[(e.y>>20)&BMSK],1); csrp[base+p] = e.y & 0xFFFFFu; }
    if (s0b+2 < c){ p = atomicAdd(&hist[(e.z>>20)&BMSK],1); csrp[base+p] = e.z & 0xFFFFFu; }
    if (s0b+3 < c){ p = atomicAdd(&hist[(e.w>>20)&BMSK],1); csrp[base+p] = e.w & 0xFFFFFu; }
  }
  for (int j=t;j<oc;j+=1024){
    uint2 pr = ovf[j];
    if (pr.y == (uint32_t)b){
      int p = atomicAdd(&hist[(pr.x>>20)&BMSK],1);
      csrp[base+p] = pr.x & 0xFFFFFu;
    }
  }
}

// ---------------- fused SAGE layer 0 (gather from f16 x-rows + MFMA, K=32) ----------------
__global__ __launch_bounds__(256,8) void k_layer0(
    const f16* __restrict__ xh,
    const int* __restrict__ off, const uint32_t* __restrict__ csrp,
    const f16* __restrict__ wcat0, const float* __restrict__ bl0,
    f16* __restrict__ hout)
{
  __shared__ uint32_t ALDS[NPB*(ASTR0/2)];   // 10240B: A[128][40] f16 = [mean16|x16]; reused as ST
  __shared__ uint32_t BLDS[32*(ASTR0/2)];    // 2560B:  B0^T[32][40] f16
  __shared__ uint32_t EL[ECAP];              // 3072B
  __shared__ int      sOFF[NPB+2];
  __shared__ float    biasL[32];
  int t = threadIdx.x;
  int base = blockIdx.x*NPB;
  int e0 = off[base];
  int e1 = off[base+NPB];
  for (int i=t; i<NPB+1; i+=256) sOFF[i] = off[base+i];
  {
    int lim = (e1-e0) < ECAP ? (e1-e0) : ECAP;
    for (int i=t; i<lim; i+=256) EL[i] = csrp[e0+i];
  }
  if (t < 128){
    int oc = t>>2, kq = (t&3)*8;
    f16x8 wv = *(const f16x8*)(wcat0 + oc*32 + kq);
    *(f16x8*)((f16*)BLDS + oc*ASTR0 + kq) = wv;
  }
  if (t < 32) biasL[t] = bl0[t];
  __syncthreads();   // staging (sOFF/EL/BLDS/bias) visible before gather reads

  // gather: 4 lanes per node (f16x4 = 4 ch each, 32B rows); masked slots -> zero row ZN
  int c4 = t & 3;
  #pragma unroll
  for (int p=0;p<2;p++){
    int nl = p*64 + (t>>2);
    int node = base + nl;
    f16x4 xown = *(const f16x4*)(xh + (size_t)node*16 + 4u*c4);
    int s = sOFF[nl] - e0;
    int d = sOFF[nl+1] - sOFF[nl];
    float a0=0.f,a1=0.f,a2=0.f,a3=0.f;
    for (int i=0;i<d;i+=4){
      int j0 = s+i;
      uint32_t k0,k1,k2,k3;
      if (j0+3 < ECAP){ k0=EL[j0]; k1=EL[j0+1]; k2=EL[j0+2]; k3=EL[j0+3]; }
      else            { k0=csrp[e0+j0]; k1=csrp[e0+j0+1]; k2=csrp[e0+j0+2]; k3=csrp[e0+j0+3]; }
      k1 = (i+1<d)?k1:(uint32_t)ZN;
      k2 = (i+2<d)?k2:(uint32_t)ZN;
      k3 = (i+3<d)?k3:(uint32_t)ZN;
      f16x4 g0 = *(const f16x4*)(xh + (size_t)k0*16u + 4u*c4);
      f16x4 g1 = *(const f16x4*)(xh + (size_t)k1*16u + 4u*c4);
      f16x4 g2 = *(const f16x4*)(xh + (size_t)k2*16u + 4u*c4);
      f16x4 g3 = *(const f16x4*)(xh + (size_t)k3*16u + 4u*c4);
      a0 += ((float)g0[0]+(float)g1[0]) + ((float)g2[0]+(float)g3[0]);
      a1 += ((float)g0[1]+(float)g1[1]) + ((float)g2[1]+(float)g3[1]);
      a2 += ((float)g0[2]+(float)g1[2]) + ((float)g2[2]+(float)g3[2]);
      a3 += ((float)g0[3]+(float)g1[3]) + ((float)g2[3]+(float)g3[3]);
    }
    float inv = 1.f/(float)(d<1?1:d);
    union { f16 h[4]; uint32_t u[2]; } mp, xp;
    mp.h[0]=(f16)(a0*inv); mp.h[1]=(f16)(a1*inv); mp.h[2]=(f16)(a2*inv); mp.h[3]=(f16)(a3*inv);
    xp.h[0]=xown[0]; xp.h[1]=xown[1]; xp.h[2]=xown[2]; xp.h[3]=xown[3];
    uint32_t* arow = &ALDS[nl*(ASTR0/2)];
    *((uint2*)&arow[2*c4])     = make_uint2(mp.u[0], mp.u[1]);   // mean cols 4c4..
    *((uint2*)&arow[8 + 2*c4]) = make_uint2(xp.u[0], xp.u[1]);   // x cols 16+4c4..
  }
  __syncthreads();

  // MFMA: wave w owns rows 32w..32w+31, cols 0..31; single K=32 step
  int w = t>>6, l = t&63;
  int lrow = l&15, lg = l>>4;
  const f16* Af = (const f16*)ALDS;
  const f16* Bf = (const f16*)BLDS;
  f32x4 D00={0.f,0.f,0.f,0.f}, D01=D00, D10=D00, D11=D00;
  {
    f16x8 af0 = *(const f16x8*)(Af + (32*w+lrow)*ASTR0    + 8*lg);
    f16x8 af1 = *(const f16x8*)(Af + (32*w+16+lrow)*ASTR0 + 8*lg);
    f16x8 bf0 = *(const f16x8*)(Bf + lrow*ASTR0           + 8*lg);
    f16x8 bf1 = *(const f16x8*)(Bf + (16+lrow)*ASTR0      + 8*lg);
    D00 = __builtin_amdgcn_mfma_f32_16x16x32_f16(af0, bf0, D00, 0,0,0);
    D01 = __builtin_amdgcn_mfma_f32_16x16x32_f16(af0, bf1, D01, 0,0,0);
    D10 = __builtin_amdgcn_mfma_f32_16x16x32_f16(af1, bf0, D10, 0,0,0);
    D11 = __builtin_amdgcn_mfma_f32_16x16x32_f16(af1, bf1, D11, 0,0,0);
  }
  __syncthreads();       // all frag reads done -> ALDS reusable as ST

  f16* ST = (f16*)ALDS;  // [128][34] f16 staging
  #pragma unroll
  for (int j=0;j<4;j++){
    int r0 = 32*w + 4*lg + j, r1 = r0 + 16;
    ST[r0*34 + lrow]      = (f16)selu_f(D00[j] + biasL[lrow]);
    ST[r0*34 + 16 + lrow] = (f16)selu_f(D01[j] + biasL[16+lrow]);
    ST[r1*34 + lrow]      = (f16)selu_f(D10[j] + biasL[lrow]);
    ST[r1*34 + 16 + lrow] = (f16)selu_f(D11[j] + biasL[16+lrow]);
  }
  __syncthreads();

  const uint32_t* STd = (const uint32_t*)ALDS;
  uint4* ho4 = (uint4*)hout;
  int gbase = blockIdx.x*(NPB*HID/8);   // 512 16B-chunks per block
  #pragma unroll
  for (int k=0;k<2;k++){
    int cch = t + 256*k;
    int n = cch>>2, m = cch&3;
    int dd = n*17 + m*4;
    uint4 u;
    u.x=STd[dd]; u.y=STd[dd+1]; u.z=STd[dd+2]; u.w=STd[dd+3];
    ho4[gbase+cch] = u;
  }
}

// ---------------- fused SAGE layers 1..4 (gather + MFMA, K=64) ----------------
// MODE_A (L1): jk := max(hin_own, h_new); write hout
// MODE_B (L2): no jk; write hout
// MODE_C (L3): jk := max(jk, hin_own, h_new); write hout
// MODE_D (L4): jk := max(jk, h_new); NO hout
__global__ __launch_bounds__(256,6) void k_layer(
    const f16* __restrict__ hin,
    const int* __restrict__ off, const uint32_t* __restrict__ csrp,
    const f16* __restrict__ wcat, const float* __restrict__ bl,
    f16* __restrict__ hout, f16* __restrict__ jkio, int mode)
{
  __shared__ uint32_t ALDS[NPB*(ASTR/2)];    // 18432B: A[128][72] f16 = [mean32|h32]; reused as ST
  __shared__ uint32_t BLDS[32*(BSTR/2)];     // 4608B:  B^T[32][72] f16
  __shared__ uint32_t EL[ECAP];              // 3072B
  __shared__ int      sOFF[NPB+2];
  __shared__ float    biasL[32];
  int t = threadIdx.x;
  int base = blockIdx.x*NPB;
  int e0 = off[base];
  int e1 = off[base+NPB];
  for (int i=t; i<NPB+1; i+=256) sOFF[i] = off[base+i];
  {
    int lim = (e1-e0) < ECAP ? (e1-e0) : ECAP;
    for (int i=t; i<lim; i+=256) EL[i] = csrp[e0+i];
  }
  if (t < 128){
    int oc = t>>2, kq = (t&3)*8;               // 4 chunks of 8 f16 per row
    f16x8 wv0 = *(const f16x8*)(wcat + oc*64 + kq);
    f16x8 wv1 = *(const f16x8*)(wcat + oc*64 + 32 + kq);
    *(f16x8*)((f16*)BLDS + oc*BSTR + kq)      = wv0;
    *(f16x8*)((f16*)BLDS + oc*BSTR + 32 + kq) = wv1;
  }
  if (t < 32) biasL[t] = bl[t];
  __syncthreads();   // staging (sOFF/EL/BLDS/bias) visible before gather reads

  // gather: 4 lanes per node (f16x8 = 8 ch each); masked slots -> zero row ZN
  int c4 = t & 3;
  #pragma unroll
  for (int p=0;p<2;p++){
    int nl = p*64 + (t>>2);
    int node = base + nl;
    f16x8 hown = *(const f16x8*)(hin + (size_t)node*HID + 8u*c4);
    int s = sOFF[nl] - e0;
    int d = sOFF[nl+1] - sOFF[nl];
    float a[8];
    #pragma unroll
    for (int r=0;r<8;r++) a[r]=0.f;
    for (int i=0;i<d;i+=4){
      int j0 = s+i;
      uint32_t k0,k1,k2,k3;
      if (j0+3 < ECAP){ k0=EL[j0]; k1=EL[j0+1]; k2=EL[j0+2]; k3=EL[j0+3]; }
      else            { k0=csrp[e0+j0]; k1=csrp[e0+j0+1]; k2=csrp[e0+j0+2]; k3=csrp[e0+j0+3]; }
      k1 = (i+1<d)?k1:(uint32_t)ZN;
      k2 = (i+2<d)?k2:(uint32_t)ZN;
      k3 = (i+3<d)?k3:(uint32_t)ZN;
      f16x8 g0 = *((const f16x8*)(hin + (size_t)k0*32u) + c4);
      f16x8 g1 = *((const f16x8*)(hin + (size_t)k1*32u) + c4);
      f16x8 g2 = *((const f16x8*)(hin + (size_t)k2*32u) + c4);
      f16x8 g3 = *((const f16x8*)(hin + (size_t)k3*32u) + c4);
      #pragma unroll
      for (int r=0;r<8;r++)
        a[r] += ((float)g0[r]+(float)g1[r]) + ((float)g2[r]+(float)g3[r]);
    }
    float inv = 1.f/(float)(d<1?1:d);
    union { f16 h[8]; uint4 v; } mp;
    #pragma unroll
    for (int r=0;r<8;r++) mp.h[r] = (f16)(a[r]*inv);
    uint32_t* arow = &ALDS[nl*(ASTR/2)];
    *((uint4*)&arow[4*c4]) = mp.v;                          // mean cols 8c4..
    *((f16x8*)((f16*)arow + 32 + 8*c4)) = hown;             // h cols 32+8c4..
  }
  __syncthreads();

  // MFMA: wave w owns rows 32w..32w+31, cols 0..31; two K=32 steps
  int w = t>>6, l = t&63;
  int lrow = l&15, lg = l>>4;
  const f16* Af = (const f16*)ALDS;
  const f16* Bf = (const f16*)BLDS;
  f32x4 D00={0.f,0.f,0.f,0.f}, D01=D00, D10=D00, D11=D00;
  #pragma unroll
  for (int s2=0;s2<2;s2++){
    f16x8 af0 = *(const f16x8*)(Af + (32*w+lrow)*ASTR    + 32*s2 + 8*lg);
    f16x8 af1 = *(const f16x8*)(Af + (32*w+16+lrow)*ASTR + 32*s2 + 8*lg);
    f16x8 bf0 = *(const f16x8*)(Bf + lrow*BSTR           + 32*s2 + 8*lg);
    f16x8 bf1 = *(const f16x8*)(Bf + (16+lrow)*BSTR      + 32*s2 + 8*lg);
    D00 = __builtin_amdgcn_mfma_f32_16x16x32_f16(af0, bf0, D00, 0,0,0);
    D01 = __builtin_amdgcn_mfma_f32_16x16x32_f16(af0, bf1, D01, 0,0,0);
    D10 = __builtin_amdgcn_mfma_f32_16x16x32_f16(af1, bf0, D10, 0,0,0);
    D11 = __builtin_amdgcn_mfma_f32_16x16x32_f16(af1, bf1, D11, 0,0,0);
  }
  __syncthreads();       // all frag reads done -> ALDS reusable as ST

  f16* ST = (f16*)ALDS;  // [128][34] f16 staging
  #pragma unroll
  for (int j=0;j<4;j++){
    int r0 = 32*w + 4*lg + j, r1 = r0 + 16;
    ST[r0*34 + lrow]      = (f16)selu_f(D00[j] + biasL[lrow]);
    ST[r0*34 + 16 + lrow] = (f16)selu_f(D01[j] + biasL[16+lrow]);
    ST[r1*34 + lrow]      = (f16)selu_f(D10[j] + biasL[lrow]);
    ST[r1*34 + 16 + lrow] = (f16)selu_f(D11[j] + biasL[16+lrow]);
  }
  __syncthreads();

  const uint32_t* STd = (const uint32_t*)ALDS;
  u32x4* ho4 = (u32x4*)hout;
  u32x4* jo4 = (u32x4*)jkio;
  const u32x4* hi4 = (const u32x4*)hin;   // own h_in rows (L2-hot: gather just touched them)
  int gbase = blockIdx.x*(NPB*HID/8);
  #pragma unroll
  for (int k=0;k<2;k++){
    int cch = t + 256*k;
    int n = cch>>2, m = cch&3;
    int dd = n*17 + m*4;
    union UU { u32x4 u; f16 hh[8]; };
    UU hv, jv, j2;
    hv.u = (u32x4){STd[dd], STd[dd+1], STd[dd+2], STd[dd+3]};
    if (mode != MODE_B){
      if (mode == MODE_A) jv.u = hi4[gbase+cch];
      else                jv.u = __builtin_nontemporal_load(jo4 + gbase + cch);
      if (mode == MODE_C){
        j2.u = hi4[gbase+cch];
        #pragma unroll
        for (int r=0;r<8;r++) jv.hh[r] = (j2.hh[r] > jv.hh[r]) ? j2.hh[r] : jv.hh[r];
      }
      #pragma unroll
      for (int r=0;r<8;r++) jv.hh[r] = (hv.hh[r] > jv.hh[r]) ? hv.hh[r] : jv.hh[r];
      __builtin_nontemporal_store(jv.u, jo4 + gbase + cch);   // streaming: don't pollute L2/L3
    }
    if (mode != MODE_D) ho4[gbase+cch] = hv.u;
  }
}

// ---------------- attention + head, one block per graph (MFMA K/V, slim LDS) ----------------
__global__ __launch_bounds__(256) void k_attn(
    const f16* __restrict__ jk, const float* __restrict__ x,
    const int* __restrict__ shuf, const f16* __restrict__ wkvT,
    const float* __restrict__ wq, const float* __restrict__ bq,
    const float* __restrict__ bk, const float* __restrict__ bv,
    const float* __restrict__ wo, const float* __restrict__ bo,
    const float* __restrict__ wfc, const float* __restrict__ bfc,
    float* __restrict__ out)
{
  __shared__ alignas(16) f16 Ah[64*40];   // 5120B: H=selu(jk) f16; rows 55..63 garbage (discarded)
  __shared__ float K[NODES*33];           // 7260B
  __shared__ float V[NODES*33];           // 7260B
  __shared__ float Qs[6*33];
  __shared__ float S[6*56];
  __shared__ float O[6*33];
  __shared__ float SO[192];
  __shared__ float part[96];
  __shared__ int   sel[8];

  int g = blockIdx.x, t = threadIdx.x;

  // stage H = selu(jk) as f16 into A-tile (rows=nodes, 40-f16 stride); jk is single-use -> nt
  {
    const f16x8* j8 = (const f16x8*)(jk + (size_t)g*NODES*HID);
    for (int i=t; i<NODES*HID/8; i+=256){   // 220 vectors of 8
      f16x8 v = __builtin_nontemporal_load(j8 + i);
      int node = i >> 2, c0 = (i & 3)*8;
      f16x8 hv;
      #pragma unroll
      for (int r=0;r<8;r++) hv[r] = (f16)selu_f((float)v[r]);
      *(f16x8*)(Ah + node*40 + c0) = hv;
    }
  }
  // wave 0: neighbor-mask ballot -> sel (no serial loop)
  if (t < 64){
    float mv = (t < NODES) ? x[(size_t)(g*NODES+t)*INCH + (INCH-3)] : 0.f;
    unsigned long long mb = __ballot(mv > 0.5f);
    if (t < 6){
      int kk = shuf[g*6 + t];
      for (int i2=0;i2<kk;i2++) mb &= (mb - 1ull);
      sel[t] = (int)__builtin_ctzll(mb);
    }
  }
  __syncthreads();

  // K/V projection via MFMA: [64x32] H @ [32x64] (Wk|Wv), wave w = row-tile w
  {
    int w = t>>6, l = t&63;
    int lrow = l&15, lg = l>>4;
    f16x8 af = *(const f16x8*)(Ah + (16*w + lrow)*40 + 8*lg);
    #pragma unroll
    for (int ct=0; ct<4; ct++){
      f16x8 bf = *(const f16x8*)(wkvT + (16*ct + lrow)*32 + 8*lg);  // global, L2-resident
      f32x4 D = {0.f,0.f,0.f,0.f};
      D = __builtin_amdgcn_mfma_f32_16x16x32_f16(af, bf, D, 0,0,0);
      int ocl = 16*(ct&1) + lrow;
      float bias = (ct < 2) ? bk[ocl] : bv[ocl];
      float* dst = (ct < 2) ? K : V;
      #pragma unroll
      for (int j=0;j<4;j++){
        int node = 16*w + 4*lg + j;
        if (node < NODES) dst[node*33 + ocl] = D[j] + bias;
      }
    }
  }
  // Q projection (6x32, VALU; wq from global - cache-resident)
  if (t < 192){
    int q = t>>5, oc = t&31;
    int node = sel[q];
    const f16x8* hr8 = (const f16x8*)(Ah + node*40);
    float a = bq[oc];
    #pragma unroll
    for (int cc=0;cc<4;cc++){
      f16x8 hv = hr8[cc];
      #pragma unroll
      for (int r=0;r<8;r++) a = fmaf((float)hv[r], wq[(8*cc+r)*HID + oc], a);
    }
    Qs[q*33+oc] = a;
  }
  __syncthreads();

  // scores = Q.K^T / sqrt(32)
  for (int idx=t; idx<6*NODES; idx+=256){
    int q = idx % 6, k = idx / 6;
    float a = 0.f;
    #pragma unroll
    for (int c=0;c<HID;c++) a = fmaf(Qs[q*33+c], K[k*33+c], a);
    S[q*56+k] = a * 0.17677669529663687f;
  }
  __syncthreads();

  // softmax over 55 keys: 32-lane group per query
  if (t < 192){
    int q = t>>5, l = t&31;
    float v0 = (l      < NODES) ? S[q*56+l]    : -1e30f;
    float v1 = (l+32   < NODES) ? S[q*56+l+32] : -1e30f;
    float mx = fmaxf(v0, v1);
    #pragma unroll
    for (int o=16;o>0;o>>=1) mx = fmaxf(mx, __shfl_xor(mx, o, 32));
    float p0 = (l    < NODES) ? __expf(v0-mx) : 0.f;
    float p1 = (l+32 < NODES) ? __expf(v1-mx) : 0.f;
    float sm = p0 + p1;
    #pragma unroll
    for (int o=16;o>0;o>>=1) sm += __shfl_xor(sm, o, 32);
    float inv = 1.f/sm;
    if (l    < NODES) S[q*56+l]    = p0*inv;
    if (l+32 < NODES) S[q*56+l+32] = p1*inv;
  }
  __syncthreads();

  // attn @ V
  if (t < 192){
    int q = t>>5, oc = t&31;
    float a = 0.f;
    for (int k=0;k<NODES;k++) a = fmaf(S[q*56+k], V[k*33+oc], a);
    O[q*33+oc] = a;
  }
  __syncthreads();

  // @ wo + bo, selu  (wo from global - cache-resident, 6x reuse per block)
  if (t < 192){
    int q = t>>5, oc = t&31;
    float a = bo[oc];
    #pragma unroll
    for (int c=0;c<HID;c++) a = fmaf(O[q*33+c], wo[c*HID+oc], a);
    SO[t] = selu_f(a);   // t == q*32+oc == flat reshape index
  }
  __syncthreads();

  // final FC: 6 outputs = SO[192] . Wfc[:,j]
  if (t < 96){
    int j = t % 6, pp = t / 6;   // 16 partials per output
    float a = 0.f;
    #pragma unroll
    for (int r=0;r<12;r++) a = fmaf(SO[pp*12+r], wfc[(pp*12+r)*6+j], a);
    part[pp*6+j] = a;
  }
  __syncthreads();
  if (t < 6){
    float a = bfc[t];
    #pragma unroll
    for (int pp=0;pp<16;pp++) a += part[pp*6+t];
    out[g*6+t] = a;
  }
}

extern "C" void kernel_launch(void* const* d_in, const int* in_sizes, int n_in,
                              void* d_out, int out_size, void* d_ws, size_t ws_size,
                              hipStream_t stream)
{
  const float* x   = (const float*)d_in[0];
  const int*   eix = (const int*)d_in[1];
  const int*   shf = (const int*)d_in[2];
  const float* wl0 = (const float*)d_in[3];
  const float* bl0 = (const float*)d_in[4];
  const float* wr0 = (const float*)d_in[5];
  const float* wl  = (const float*)d_in[6];
  const float* bl  = (const float*)d_in[7];
  const float* wr  = (const float*)d_in[8];
  const float* wq  = (const float*)d_in[9];
  const float* bq  = (const float*)d_in[10];
  const float* wk  = (const float*)d_in[11];
  const float* bk  = (const float*)d_in[12];
  const float* wv  = (const float*)d_in[13];
  const float* bv  = (const float*)d_in[14];
  const float* wo  = (const float*)d_in[15];
  const float* bo  = (const float*)d_in[16];
  const float* wfc = (const float*)d_in[17];
  const float* bfc = (const float*)d_in[18];
  float* out = (float*)d_out;

  const int* esrc = eix;
  const int* edst = eix + ETOT;

  // workspace carve
  char* p = (char*)d_ws;
  auto carve = [&](size_t bytes){ void* r = (void*)p; p += (bytes + 255) & ~(size_t)255; return r; };
  int*      off   = (int*)carve(sizeof(int)*(NTOT+1));
  int*      gcnt  = (int*)carve(sizeof(int)*(size_t)NBLK*NBUCK);   // 1.8 MB
  int*      btot  = (int*)carve(sizeof(int)*256);
  int*      bbase = (int*)carve(sizeof(int)*256);
  uint2*    ovf   = (uint2*)carve(sizeof(uint2)*OVFCAP);
  int*      ocnt  = (int*)carve(sizeof(int)*64);
  f16*      wcp   = (f16*)carve(sizeof(f16)*(WKV_OFF + 2048));
  uint32_t* csrp  = (uint32_t*)carve(sizeof(uint32_t)*((size_t)ETOT + 64));
  f16*      h_a   = (f16*)carve(2*((size_t)NTOT+1)*HID);   // +1 zero row (index ZN)
  f16*      h_b   = (f16*)carve(2*((size_t)NTOT+1)*HID);   // +1 zero row
  f16*      jk16  = (f16*)carve(2*(size_t)NTOT*HID);

  // aliases over dead regions:
  f16*      xh     = (f16*)h_b;         // padded f16 x [NTOT+1][16] (28.8MB), dead after k_layer0
  uint32_t* binned = (uint32_t*)h_a;    // 220*2048*32*4 = NTOT*64 B (row ZN untouched)

  k_pad   <<<ETOT/256,  256, 0, stream>>>(x, xh, h_a, h_b, ocnt);
  k_wprep <<<1,         256, 0, stream>>>(wl0, wr0, wl, wr, wk, wv, wcp);
  k_bin   <<<NBLK,    BINTH, 0, stream>>>(esrc, edst, binned, gcnt, ovf, ocnt);
  k_btot  <<<NBUCK,     256, 0, stream>>>(gcnt, ovf, ocnt, btot);
  k_bscan <<<1,         256, 0, stream>>>(btot, bbase);
  k_bucket<<<NBUCK,    1024, 0, stream>>>(binned, gcnt, bbase, ovf, ocnt, off, csrp);

  k_layer0<<<NTOT/NPB, 256, 0, stream>>>(xh, off, csrp, wcp, bl0, h_a);
  f16* hc = h_a; f16* hn = h_b;
  static const int modes[4] = {MODE_A, MODE_B, MODE_C, MODE_D};
  for (int l=0; l<4; l++){
    k_layer<<<NTOT/NPB, 256, 0, stream>>>(hc, off, csrp,
                                          wcp + 1024 + l*2048, bl + l*HID,
                                          hn, jk16, modes[l]);
    f16* tmp = hc; hc = hn; hn = tmp;
  }
  k_attn<<<BGRAPH, 256, 0, stream>>>(jk16, x, shf, wcp + WKV_OFF,
                                     wq, bq, bk, bv, wo, bo, wfc, bfc, out);
}

// Round 11
// 810.699 us; speedup vs baseline: 4.7567x; 1.0008x over previous
//
#include <hip/hip_runtime.h>
#include <cstdint>
#include <cstddef>

#define NODES   55
#define BGRAPH  16384
#define NTOT    (BGRAPH*NODES)    // 901120
#define INCH    13
#define HID     32
#define ETOT    (4*NTOT)          // 3604480
#define NPB     128               // nodes per block (layer kernels)
#define ECAP    768               // layer0 LDS edge-list capacity
#define ECAP2   640               // k_layer LDS edge-list capacity (mean 512, +5.7 sigma; global fallback)
#define ZN      NTOT              // dummy zero-row index for masked edge slots

// ---- deterministic binned CSR build ----
#define NBUCK   220               // NTOT/4096 buckets
#define BSH     12                // 4096 nodes per bucket
#define BMSK    4095
#define NBLK    2048              // k_bin blocks
#define BCAP2   32                // slots per (bucket,block) segment; mean 8, +8.5 sigma
#define BINTH   256
#define BINGRP  (ETOT/4/NBLK)     // 440 int4-groups per block (exact)
#define OVFCAP  8192

// ---- MFMA staging ----
#define ASTR0   40                // layer0 A/B stride (f16): 80B rows
#define WKV_OFF 9216              // wkvT offset (f16 elems) inside wcp

// ---- jk folding modes ----
#define MODE_A  0   // L1: jk := max(hin_own, h_new); write hout
#define MODE_D  2   // L4: jk := max(jk, h_new); NO hout
#define MODE_B  3   // L2: no jk at all; write hout
#define MODE_C  4   // L3: jk := max(jk, hin_own, h_new); write hout

typedef _Float16 f16;
typedef _Float16 f16x4 __attribute__((ext_vector_type(4))); // 8B
typedef _Float16 f16x8 __attribute__((ext_vector_type(8))); // 16B
typedef float    f32x4 __attribute__((ext_vector_type(4)));

__device__ __forceinline__ float selu_f(float v){
  const float s  = 1.0507009873554805f;
  const float sa = 1.7580993408473766f;   // scale*alpha
  return v > 0.f ? s*v : sa*(__expf(v)-1.f);
}

// ---------------- pad x[N,13] fp32 -> xh[N,16] f16 (32B rows); zero dummy rows + ovf cursor ----------------
__global__ __launch_bounds__(256) void k_pad(const float* __restrict__ x,
                                             f16* __restrict__ xh,
                                             f16* __restrict__ ha,
                                             f16* __restrict__ hb,
                                             int* __restrict__ ocnt){
  if (blockIdx.x == 0){
    int t = threadIdx.x;
    if (t == 0) *ocnt = 0;
    if (t < 16)                  xh[(size_t)ZN*16 + t]      = (f16)0.f;  // zero row of xh
    else if (t >= 16 && t < 48)  ha[(size_t)ZN*32 + (t-16)] = (f16)0.f;  // zero row of h_a
    else if (t >= 48 && t < 80)  hb[(size_t)ZN*32 + (t-48)] = (f16)0.f;  // zero row of h_b
  }
  int i = blockIdx.x*256 + threadIdx.x;   // one f16x4 per thread, ETOT total (grid exact)
  int node = i>>2, q = i&3;
  const float* r = x + (size_t)node*INCH + q*4;
  f16x4 v;
  v[0] = (f16)r[0];
  v[1] = (q<3) ? (f16)r[1] : (f16)0.f;
  v[2] = (q<3) ? (f16)r[2] : (f16)0.f;
  v[3] = (q<3) ? (f16)r[3] : (f16)0.f;
  *(f16x4*)(xh + (size_t)node*16 + q*4) = v;
}

// ---------------- weight prep: concat+transpose to f16 once ----------------
// wcp layout: [0,1024)            = B0^T[32 oc][32 k]  (k<13: wl0, 16..28: wr0, else 0)
//             [1024 + l*2048 ...) = Bl^T[32 oc][64 k]  (k<32: wl[l], else wr[l])
//             [9216, 11264)       = [Wk|Wv]^T[64 oc][32 k]  (oc<32: wk, else wv)
__global__ __launch_bounds__(256) void k_wprep(
    const float* __restrict__ wl0, const float* __restrict__ wr0,
    const float* __restrict__ wl,  const float* __restrict__ wr,
    const float* __restrict__ wk,  const float* __restrict__ wv,
    f16* __restrict__ wcp)
{
  int t = threadIdx.x;
  for (int i=t; i<1024; i+=256){
    int oc = i>>5, k = i&31;
    float v = 0.f;
    if (k < 13)                 v = wl0[k*HID + oc];
    else if (k >= 16 && k < 29) v = wr0[(k-16)*HID + oc];
    wcp[oc*32 + k] = (f16)v;
  }
  for (int i=t; i<4*2048; i+=256){
    int l = i>>11, r = i&2047, oc = r>>6, k = r&63;
    float v = (k<32) ? wl[l*1024 + k*HID + oc] : wr[l*1024 + (k-32)*HID + oc];
    wcp[1024 + l*2048 + oc*64 + k] = (f16)v;
  }
  for (int i=t; i<2048; i+=256){
    int oc = i>>5, k = i&31;
    float v = (oc < 32) ? wk[k*HID + oc] : wv[k*HID + (oc-32)];
    wcp[WKV_OFF + oc*32 + k] = (f16)v;
  }
}

// ---------------- phase A: bin edges into per-(bucket,block) segments, no global atomics ----------------
__global__ __launch_bounds__(BINTH) void k_bin(
    const int* __restrict__ src, const int* __restrict__ dst,
    uint32_t* __restrict__ binned, int* __restrict__ gcnt,
    uint2* __restrict__ ovf, int* __restrict__ ocnt)
{
  __shared__ int lcnt[NBUCK];
  int t = threadIdx.x, bid = blockIdx.x;
  for (int i=t;i<NBUCK;i+=BINTH) lcnt[i]=0;
  __syncthreads();
  const int4* s4 = (const int4*)src;
  const int4* d4 = (const int4*)dst;
  int g0 = bid*BINGRP;
  for (int i=t; i<BINGRP; i+=BINTH){
    int4 s = s4[g0+i];
    int4 d = d4[g0+i];
    #pragma unroll
    for (int j=0;j<4;j++){
      int dd = (&d.x)[j];
      int ss = (&s.x)[j];
      int b  = dd >> BSH;
      uint32_t entry = (uint32_t)ss | ((uint32_t)(dd & BMSK) << 20);
      int pos = atomicAdd(&lcnt[b], 1);
      if (pos < BCAP2) binned[((size_t)b*NBLK + bid)*BCAP2 + pos] = entry;
      else {                                  // ~1e-10/cell; correctness fallback
        int gp = atomicAdd(ocnt, 1);
        if (gp < OVFCAP) ovf[gp] = make_uint2(entry, (uint32_t)b);
      }
    }
  }
  __syncthreads();
  for (int i=t;i<NBUCK;i+=BINTH){
    int c = lcnt[i]; if (c > BCAP2) c = BCAP2;
    gcnt[bid*NBUCK + i] = c;                  // coalesced per-block row
  }
}

// ---------------- bucket totals (incl. overflow) ----------------
__global__ __launch_bounds__(256) void k_btot(const int* __restrict__ gcnt,
                                              const uint2* __restrict__ ovf,
                                              const int* __restrict__ ocnt,
                                              int* __restrict__ btot){
  __shared__ int sd[256];
  int b = blockIdx.x, t = threadIdx.x;
  int s = 0;
  for (int i=t;i<NBLK;i+=256) s += gcnt[i*NBUCK + b];
  int oc = *ocnt; if (oc > OVFCAP) oc = OVFCAP;
  for (int j=t;j<oc;j+=256) if (ovf[j].y == (uint32_t)b) s++;
  sd[t]=s; __syncthreads();
  for (int o=128;o>0;o>>=1){ if (t<o) sd[t]+=sd[t+o]; __syncthreads(); }
  if (t==0) btot[b]=sd[0];
}

// ---------------- exclusive scan of 220 bucket totals ----------------
__global__ __launch_bounds__(256) void k_bscan(const int* __restrict__ btot,
                                               int* __restrict__ bbase){
  __shared__ int sd[256];
  int t = threadIdx.x;
  int v = (t<NBUCK) ? btot[t] : 0;
  sd[t] = v; __syncthreads();
  for (int o=1;o<256;o<<=1){
    int u = (t>=o) ? sd[t-o] : 0;
    __syncthreads();
    sd[t] += u;
    __syncthreads();
  }
  if (t<NBUCK) bbase[t] = sd[t] - v;
}

// ---------------- phase B: per-bucket counting sort -> off + csrp (L2-local) ----------------
__global__ __launch_bounds__(1024) void k_bucket(
    const uint32_t* __restrict__ binned, const int* __restrict__ gcnt,
    const int* __restrict__ bbase,
    const uint2* __restrict__ ovf, const int* __restrict__ ocnt,
    int* __restrict__ off, uint32_t* __restrict__ csrp)
{
  __shared__ int hist[4096];   // degree counts -> scatter cursors
  __shared__ int cnts[NBLK];
  __shared__ int ws[1024];
  int b = blockIdx.x, t = threadIdx.x;
  int base = bbase[b];
  for (int i=t;i<NBLK;i+=1024) cnts[i] = gcnt[i*NBUCK + b];
  #pragma unroll
  for (int i=0;i<4;i++) hist[t+1024*i] = 0;
  int oc = *ocnt; if (oc > OVFCAP) oc = OVFCAP;
  __syncthreads();

  const uint4* bb4 = (const uint4*)(binned + (size_t)b*(NBLK*BCAP2));
  // pass 1: local-degree histogram
  for (int i=t; i<NBLK*BCAP2/4; i+=1024){
    uint4 e = bb4[i];
    int c = cnts[i>>3];
    int s0 = (i&7)*4;
    if (s0   < c) atomicAdd(&hist[(e.x>>20)&BMSK],1);
    if (s0+1 < c) atomicAdd(&hist[(e.y>>20)&BMSK],1);
    if (s0+2 < c) atomicAdd(&hist[(e.z>>20)&BMSK],1);
    if (s0+3 < c) atomicAdd(&hist[(e.w>>20)&BMSK],1);
  }
  for (int j=t;j<oc;j+=1024){
    uint2 pr = ovf[j];
    if (pr.y == (uint32_t)b) atomicAdd(&hist[(pr.x>>20)&BMSK],1);
  }
  __syncthreads();
  // exclusive scan of 4096 degrees
  int t4 = t*4;
  int s0=hist[t4], s1=hist[t4+1], s2=hist[t4+2], s3=hist[t4+3];
  int sum = s0+s1+s2+s3;
  ws[t] = sum; __syncthreads();
  for (int o=1;o<1024;o<<=1){
    int u = (t>=o) ? ws[t-o] : 0;
    __syncthreads();
    ws[t] += u;
    __syncthreads();
  }
  int ex = ws[t] - sum;
  int p0 = ex, p1 = ex+s0, p2 = ex+s0+s1, p3 = ex+s0+s1+s2;
  hist[t4]=p0; hist[t4+1]=p1; hist[t4+2]=p2; hist[t4+3]=p3;   // cursors
  int4 ov; ov.x = base+p0; ov.y = base+p1; ov.z = base+p2; ov.w = base+p3;
  ((int4*)(off + (b<<BSH)))[t] = ov;
  if (b == NBUCK-1 && t == 1023) off[NTOT] = ETOT;
  __syncthreads();
  // pass 2: scatter to final CSR (256KB window -> single-XCD L2 absorbs)
  for (int i=t; i<NBLK*BCAP2/4; i+=1024){
    uint4 e = bb4[i];
    int c = cnts[i>>3];
    int s0b = (i&7)*4;
    int p;
    if (s0b   < c){ p = atomicAdd(&hist[(e.x>>20)&BMSK],1); csrp[base+p] = e.x & 0xFFFFFu; }
    if (s0b+1 < c){ p = atomicAdd(&hist[(e.y>>20)&BMSK],1); csrp[base+p] = e.y & 0xFFFFFu; }
    if (s0b+2 < c){ p = atomicAdd(&hist[(e.z>>20)&BMSK],1); csrp[base+p] = e.z & 0xFFFFFu; }
    if (s0b+3 < c){ p = atomicAdd(&hist[(e.w>>20)&BMSK],1); csrp[base+p] = e.w & 0xFFFFFu; }
  }
  for (int j=t;j<oc;j+=1024){
    uint2 pr = ovf[j];
    if (pr.y == (uint32_t)b){
      int p = atomicAdd(&hist[(pr.x>>20)&BMSK],1);
      csrp[base+p] = pr.x & 0xFFFFFu;
    }
  }
}

// ---------------- fused SAGE layer 0 (gather from f16 x-rows + MFMA, K=32) ----------------
__global__ __launch_bounds__(256,8) void k_layer0(
    const f16* __restrict__ xh,
    const int* __restrict__ off, const uint32_t* __restrict__ csrp,
    const f16* __restrict__ wcat0, const float* __restrict__ bl0,
    f16* __restrict__ hout)
{
  __shared__ uint32_t ALDS[NPB*(ASTR0/2)];   // 10240B: A[128][40] f16 = [mean16|x16]; reused as ST
  __shared__ uint32_t BLDS[32*(ASTR0/2)];    // 2560B:  B0^T[32][40] f16
  __shared__ uint32_t EL[ECAP];              // 3072B
  __shared__ int      sOFF[NPB+2];
  __shared__ float    biasL[32];
  int t = threadIdx.x;
  int base = blockIdx.x*NPB;
  int e0 = off[base];
  int e1 = off[base+NPB];
  for (int i=t; i<NPB+1; i+=256) sOFF[i] = off[base+i];
  {
    int lim = (e1-e0) < ECAP ? (e1-e0) : ECAP;
    for (int i=t; i<lim; i+=256) EL[i] = csrp[e0+i];
  }
  if (t < 128){
    int oc = t>>2, kq = (t&3)*8;
    f16x8 wv = *(const f16x8*)(wcat0 + oc*32 + kq);
    *(f16x8*)((f16*)BLDS + oc*ASTR0 + kq) = wv;
  }
  if (t < 32) biasL[t] = bl0[t];
  __syncthreads();   // staging (sOFF/EL/BLDS/bias) visible before gather reads

  // gather: 4 lanes per node (f16x4 = 4 ch each, 32B rows); masked slots -> zero row ZN
  int c4 = t & 3;
  #pragma unroll
  for (int p=0;p<2;p++){
    int nl = p*64 + (t>>2);
    int node = base + nl;
    f16x4 xown = *(const f16x4*)(xh + (size_t)node*16 + 4u*c4);
    int s = sOFF[nl] - e0;
    int d = sOFF[nl+1] - sOFF[nl];
    float a0=0.f,a1=0.f,a2=0.f,a3=0.f;
    for (int i=0;i<d;i+=4){
      int j0 = s+i;
      uint32_t k0,k1,k2,k3;
      if (j0+3 < ECAP){ k0=EL[j0]; k1=EL[j0+1]; k2=EL[j0+2]; k3=EL[j0+3]; }
      else            { k0=csrp[e0+j0]; k1=csrp[e0+j0+1]; k2=csrp[e0+j0+2]; k3=csrp[e0+j0+3]; }
      k1 = (i+1<d)?k1:(uint32_t)ZN;
      k2 = (i+2<d)?k2:(uint32_t)ZN;
      k3 = (i+3<d)?k3:(uint32_t)ZN;
      f16x4 g0 = *(const f16x4*)(xh + (size_t)k0*16u + 4u*c4);
      f16x4 g1 = *(const f16x4*)(xh + (size_t)k1*16u + 4u*c4);
      f16x4 g2 = *(const f16x4*)(xh + (size_t)k2*16u + 4u*c4);
      f16x4 g3 = *(const f16x4*)(xh + (size_t)k3*16u + 4u*c4);
      a0 += ((float)g0[0]+(float)g1[0]) + ((float)g2[0]+(float)g3[0]);
      a1 += ((float)g0[1]+(float)g1[1]) + ((float)g2[1]+(float)g3[1]);
      a2 += ((float)g0[2]+(float)g1[2]) + ((float)g2[2]+(float)g3[2]);
      a3 += ((float)g0[3]+(float)g1[3]) + ((float)g2[3]+(float)g3[3]);
    }
    float inv = 1.f/(float)(d<1?1:d);
    union { f16 h[4]; uint32_t u[2]; } mp, xp;
    mp.h[0]=(f16)(a0*inv); mp.h[1]=(f16)(a1*inv); mp.h[2]=(f16)(a2*inv); mp.h[3]=(f16)(a3*inv);
    xp.h[0]=xown[0]; xp.h[1]=xown[1]; xp.h[2]=xown[2]; xp.h[3]=xown[3];
    uint32_t* arow = &ALDS[nl*(ASTR0/2)];
    *((uint2*)&arow[2*c4])     = make_uint2(mp.u[0], mp.u[1]);   // mean cols 4c4..
    *((uint2*)&arow[8 + 2*c4]) = make_uint2(xp.u[0], xp.u[1]);   // x cols 16+4c4..
  }
  __syncthreads();

  // MFMA: wave w owns rows 32w..32w+31, cols 0..31; single K=32 step
  int w = t>>6, l = t&63;
  int lrow = l&15, lg = l>>4;
  const f16* Af = (const f16*)ALDS;
  const f16* Bf = (const f16*)BLDS;
  f32x4 D00={0.f,0.f,0.f,0.f}, D01=D00, D10=D00, D11=D00;
  {
    f16x8 af0 = *(const f16x8*)(Af + (32*w+lrow)*ASTR0    + 8*lg);
    f16x8 af1 = *(const f16x8*)(Af + (32*w+16+lrow)*ASTR0 + 8*lg);
    f16x8 bf0 = *(const f16x8*)(Bf + lrow*ASTR0           + 8*lg);
    f16x8 bf1 = *(const f16x8*)(Bf + (16+lrow)*ASTR0      + 8*lg);
    D00 = __builtin_amdgcn_mfma_f32_16x16x32_f16(af0, bf0, D00, 0,0,0);
    D01 = __builtin_amdgcn_mfma_f32_16x16x32_f16(af0, bf1, D01, 0,0,0);
    D10 = __builtin_amdgcn_mfma_f32_16x16x32_f16(af1, bf0, D10, 0,0,0);
    D11 = __builtin_amdgcn_mfma_f32_16x16x32_f16(af1, bf1, D11, 0,0,0);
  }
  __syncthreads();       // all frag reads done -> ALDS reusable as ST

  f16* ST = (f16*)ALDS;  // [128][34] f16 staging
  #pragma unroll
  for (int j=0;j<4;j++){
    int r0 = 32*w + 4*lg + j, r1 = r0 + 16;
    ST[r0*34 + lrow]      = (f16)selu_f(D00[j] + biasL[lrow]);
    ST[r0*34 + 16 + lrow] = (f16)selu_f(D01[j] + biasL[16+lrow]);
    ST[r1*34 + lrow]      = (f16)selu_f(D10[j] + biasL[lrow]);
    ST[r1*34 + 16 + lrow] = (f16)selu_f(D11[j] + biasL[16+lrow]);
  }
  __syncthreads();

  const uint32_t* STd = (const uint32_t*)ALDS;
  uint4* ho4 = (uint4*)hout;
  int gbase = blockIdx.x*(NPB*HID/8);   // 512 16B-chunks per block
  #pragma unroll
  for (int k=0;k<2;k++){
    int cch = t + 256*k;
    int n = cch>>2, m = cch&3;
    int dd = n*17 + m*4;
    uint4 u;
    u.x=STd[dd]; u.y=STd[dd+1]; u.z=STd[dd+2]; u.w=STd[dd+3];
    ho4[gbase+cch] = u;
  }
}

// ---------------- fused SAGE layers 1..4 (gather + MFMA, K=64; slim LDS, 8 blocks/CU) ----------------
// MODE_A (L1): jk := max(hin_own, h_new); write hout
// MODE_B (L2): no jk; write hout
// MODE_C (L3): jk := max(jk, hin_own, h_new); write hout
// MODE_D (L4): jk := max(jk, h_new); NO hout
__global__ __launch_bounds__(256,8) void k_layer(
    const f16* __restrict__ hin,
    const int* __restrict__ off, const uint32_t* __restrict__ csrp,
    const f16* __restrict__ wcat, const float* __restrict__ bl,
    f16* __restrict__ hout, f16* __restrict__ jkio, int mode)
{
  __shared__ uint32_t ALDS[NPB*32];    // 16384B: A[128][64] f16 = [mean32|h32], no pad; reused as ST
  __shared__ uint32_t EL[ECAP2];       // 2560B
  __shared__ int      sOFF[NPB+2];     // 520B
  __shared__ float    biasL[32];       // 128B   => ~19.6KB -> 8 blocks/CU
  int t = threadIdx.x;
  int base = blockIdx.x*NPB;
  int e0 = off[base];
  int e1 = off[base+NPB];
  for (int i=t; i<NPB+1; i+=256) sOFF[i] = off[base+i];
  {
    int lim = (e1-e0) < ECAP2 ? (e1-e0) : ECAP2;
    for (int i=t; i<lim; i+=256) EL[i] = csrp[e0+i];
  }
  if (t < 32) biasL[t] = bl[t];
  __syncthreads();   // staging (sOFF/EL/bias) visible before gather reads

  // gather: 4 lanes per node (f16x8 = 8 ch each); masked slots -> zero row ZN
  int c4 = t & 3;
  #pragma unroll
  for (int p=0;p<2;p++){
    int nl = p*64 + (t>>2);
    int node = base + nl;
    f16x8 hown = *(const f16x8*)(hin + (size_t)node*HID + 8u*c4);
    int s = sOFF[nl] - e0;
    int d = sOFF[nl+1] - sOFF[nl];
    float a[8];
    #pragma unroll
    for (int r=0;r<8;r++) a[r]=0.f;
    for (int i=0;i<d;i+=4){
      int j0 = s+i;
      uint32_t k0,k1,k2,k3;
      if (j0+3 < ECAP2){ k0=EL[j0]; k1=EL[j0+1]; k2=EL[j0+2]; k3=EL[j0+3]; }
      else             { k0=csrp[e0+j0]; k1=csrp[e0+j0+1]; k2=csrp[e0+j0+2]; k3=csrp[e0+j0+3]; }
      k1 = (i+1<d)?k1:(uint32_t)ZN;
      k2 = (i+2<d)?k2:(uint32_t)ZN;
      k3 = (i+3<d)?k3:(uint32_t)ZN;
      f16x8 g0 = *((const f16x8*)(hin + (size_t)k0*32u) + c4);
      f16x8 g1 = *((const f16x8*)(hin + (size_t)k1*32u) + c4);
      f16x8 g2 = *((const f16x8*)(hin + (size_t)k2*32u) + c4);
      f16x8 g3 = *((const f16x8*)(hin + (size_t)k3*32u) + c4);
      #pragma unroll
      for (int r=0;r<8;r++)
        a[r] += ((float)g0[r]+(float)g1[r]) + ((float)g2[r]+(float)g3[r]);
    }
    float inv = 1.f/(float)(d<1?1:d);
    union { f16 h[8]; uint4 v; } mp;
    #pragma unroll
    for (int r=0;r<8;r++) mp.h[r] = (f16)(a[r]*inv);
    uint32_t* arow = &ALDS[nl*32];
    *((uint4*)&arow[4*c4]) = mp.v;                          // mean cols 8c4..
    *((f16x8*)((f16*)arow + 32 + 8*c4)) = hown;             // h cols 32+8c4..
  }
  __syncthreads();

  // MFMA: wave w owns rows 32w..32w+31, cols 0..31; two K=32 steps.
  // B^T read directly from global (4KB table, L2-resident across all blocks).
  int w = t>>6, l = t&63;
  int lrow = l&15, lg = l>>4;
  const f16* Af = (const f16*)ALDS;
  f32x4 D00={0.f,0.f,0.f,0.f}, D01=D00, D10=D00, D11=D00;
  #pragma unroll
  for (int s2=0;s2<2;s2++){
    f16x8 af0 = *(const f16x8*)(Af + (32*w+lrow)*64    + 32*s2 + 8*lg);
    f16x8 af1 = *(const f16x8*)(Af + (32*w+16+lrow)*64 + 32*s2 + 8*lg);
    f16x8 bf0 = *(const f16x8*)(wcat + lrow*64         + 32*s2 + 8*lg);
    f16x8 bf1 = *(const f16x8*)(wcat + (16+lrow)*64    + 32*s2 + 8*lg);
    D00 = __builtin_amdgcn_mfma_f32_16x16x32_f16(af0, bf0, D00, 0,0,0);
    D01 = __builtin_amdgcn_mfma_f32_16x16x32_f16(af0, bf1, D01, 0,0,0);
    D10 = __builtin_amdgcn_mfma_f32_16x16x32_f16(af1, bf0, D10, 0,0,0);
    D11 = __builtin_amdgcn_mfma_f32_16x16x32_f16(af1, bf1, D11, 0,0,0);
  }
  __syncthreads();       // all frag reads done -> ALDS reusable as ST

  f16* ST = (f16*)ALDS;  // [128][34] f16 staging (8704B <= 16384B)
  #pragma unroll
  for (int j=0;j<4;j++){
    int r0 = 32*w + 4*lg + j, r1 = r0 + 16;
    ST[r0*34 + lrow]      = (f16)selu_f(D00[j] + biasL[lrow]);
    ST[r0*34 + 16 + lrow] = (f16)selu_f(D01[j] + biasL[16+lrow]);
    ST[r1*34 + lrow]      = (f16)selu_f(D10[j] + biasL[lrow]);
    ST[r1*34 + 16 + lrow] = (f16)selu_f(D11[j] + biasL[16+lrow]);
  }
  __syncthreads();

  const uint32_t* STd = (const uint32_t*)ALDS;
  uint4* ho4 = (uint4*)hout;
  uint4* jo4 = (uint4*)jkio;
  const uint4* hi4 = (const uint4*)hin;   // own h_in rows
  int gbase = blockIdx.x*(NPB*HID/8);
  #pragma unroll
  for (int k=0;k<2;k++){
    int cch = t + 256*k;
    int n = cch>>2, m = cch&3;
    int dd = n*17 + m*4;
    union UU { uint4 u; f16 hh[8]; };
    UU hv, jv, j2;
    hv.u.x=STd[dd]; hv.u.y=STd[dd+1]; hv.u.z=STd[dd+2]; hv.u.w=STd[dd+3];
    if (mode != MODE_B){
      if (mode == MODE_A) jv.u = hi4[gbase+cch];
      else                jv.u = jo4[gbase+cch];
      if (mode == MODE_C){
        j2.u = hi4[gbase+cch];
        #pragma unroll
        for (int r=0;r<8;r++) jv.hh[r] = (j2.hh[r] > jv.hh[r]) ? j2.hh[r] : jv.hh[r];
      }
      #pragma unroll
      for (int r=0;r<8;r++) jv.hh[r] = (hv.hh[r] > jv.hh[r]) ? hv.hh[r] : jv.hh[r];
      jo4[gbase+cch] = jv.u;
    }
    if (mode != MODE_D) ho4[gbase+cch] = hv.u;
  }
}

// ---------------- attention + head, one block per graph (MFMA K/V, slim LDS) ----------------
__global__ __launch_bounds__(256) void k_attn(
    const f16* __restrict__ jk, const float* __restrict__ x,
    const int* __restrict__ shuf, const f16* __restrict__ wkvT,
    const float* __restrict__ wq, const float* __restrict__ bq,
    const float* __restrict__ bk, const float* __restrict__ bv,
    const float* __restrict__ wo, const float* __restrict__ bo,
    const float* __restrict__ wfc, const float* __restrict__ bfc,
    float* __restrict__ out)
{
  __shared__ alignas(16) f16 Ah[64*40];   // 5120B: H=selu(jk) f16; rows 55..63 garbage (discarded)
  __shared__ float K[NODES*33];           // 7260B
  __shared__ float V[NODES*33];           // 7260B
  __shared__ float Qs[6*33];
  __shared__ float S[6*56];
  __shared__ float O[6*33];
  __shared__ float SO[192];
  __shared__ float part[96];
  __shared__ int   sel[8];

  int g = blockIdx.x, t = threadIdx.x;

  // stage H = selu(jk) as f16 into A-tile (rows=nodes, 40-f16 stride)
  {
    const f16x8* j8 = (const f16x8*)(jk + (size_t)g*NODES*HID);
    for (int i=t; i<NODES*HID/8; i+=256){   // 220 vectors of 8
      f16x8 v = j8[i];
      int node = i >> 2, c0 = (i & 3)*8;
      f16x8 hv;
      #pragma unroll
      for (int r=0;r<8;r++) hv[r] = (f16)selu_f((float)v[r]);
      *(f16x8*)(Ah + node*40 + c0) = hv;
    }
  }
  // wave 0: neighbor-mask ballot -> sel (no serial loop)
  if (t < 64){
    float mv = (t < NODES) ? x[(size_t)(g*NODES+t)*INCH + (INCH-3)] : 0.f;
    unsigned long long mb = __ballot(mv > 0.5f);
    if (t < 6){
      int kk = shuf[g*6 + t];
      for (int i2=0;i2<kk;i2++) mb &= (mb - 1ull);
      sel[t] = (int)__builtin_ctzll(mb);
    }
  }
  __syncthreads();

  // K/V projection via MFMA: [64x32] H @ [32x64] (Wk|Wv), wave w = row-tile w
  {
    int w = t>>6, l = t&63;
    int lrow = l&15, lg = l>>4;
    f16x8 af = *(const f16x8*)(Ah + (16*w + lrow)*40 + 8*lg);
    #pragma unroll
    for (int ct=0; ct<4; ct++){
      f16x8 bf = *(const f16x8*)(wkvT + (16*ct + lrow)*32 + 8*lg);  // global, L2-resident
      f32x4 D = {0.f,0.f,0.f,0.f};
      D = __builtin_amdgcn_mfma_f32_16x16x32_f16(af, bf, D, 0,0,0);
      int ocl = 16*(ct&1) + lrow;
      float bias = (ct < 2) ? bk[ocl] : bv[ocl];
      float* dst = (ct < 2) ? K : V;
      #pragma unroll
      for (int j=0;j<4;j++){
        int node = 16*w + 4*lg + j;
        if (node < NODES) dst[node*33 + ocl] = D[j] + bias;
      }
    }
  }
  // Q projection (6x32, VALU; wq from global - cache-resident)
  if (t < 192){
    int q = t>>5, oc = t&31;
    int node = sel[q];
    const f16x8* hr8 = (const f16x8*)(Ah + node*40);
    float a = bq[oc];
    #pragma unroll
    for (int cc=0;cc<4;cc++){
      f16x8 hv = hr8[cc];
      #pragma unroll
      for (int r=0;r<8;r++) a = fmaf((float)hv[r], wq[(8*cc+r)*HID + oc], a);
    }
    Qs[q*33+oc] = a;
  }
  __syncthreads();

  // scores = Q.K^T / sqrt(32)
  for (int idx=t; idx<6*NODES; idx+=256){
    int q = idx % 6, k = idx / 6;
    float a = 0.f;
    #pragma unroll
    for (int c=0;c<HID;c++) a = fmaf(Qs[q*33+c], K[k*33+c], a);
    S[q*56+k] = a * 0.17677669529663687f;
  }
  __syncthreads();

  // softmax over 55 keys: 32-lane group per query
  if (t < 192){
    int q = t>>5, l = t&31;
    float v0 = (l      < NODES) ? S[q*56+l]    : -1e30f;
    float v1 = (l+32   < NODES) ? S[q*56+l+32] : -1e30f;
    float mx = fmaxf(v0, v1);
    #pragma unroll
    for (int o=16;o>0;o>>=1) mx = fmaxf(mx, __shfl_xor(mx, o, 32));
    float p0 = (l    < NODES) ? __expf(v0-mx) : 0.f;
    float p1 = (l+32 < NODES) ? __expf(v1-mx) : 0.f;
    float sm = p0 + p1;
    #pragma unroll
    for (int o=16;o>0;o>>=1) sm += __shfl_xor(sm, o, 32);
    float inv = 1.f/sm;
    if (l    < NODES) S[q*56+l]    = p0*inv;
    if (l+32 < NODES) S[q*56+l+32] = p1*inv;
  }
  __syncthreads();

  // attn @ V
  if (t < 192){
    int q = t>>5, oc = t&31;
    float a = 0.f;
    for (int k=0;k<NODES;k++) a = fmaf(S[q*56+k], V[k*33+oc], a);
    O[q*33+oc] = a;
  }
  __syncthreads();

  // @ wo + bo, selu  (wo from global - cache-resident, 6x reuse per block)
  if (t < 192){
    int q = t>>5, oc = t&31;
    float a = bo[oc];
    #pragma unroll
    for (int c=0;c<HID;c++) a = fmaf(O[q*33+c], wo[c*HID+oc], a);
    SO[t] = selu_f(a);   // t == q*32+oc == flat reshape index
  }
  __syncthreads();

  // final FC: 6 outputs = SO[192] . Wfc[:,j]
  if (t < 96){
    int j = t % 6, pp = t / 6;   // 16 partials per output
    float a = 0.f;
    #pragma unroll
    for (int r=0;r<12;r++) a = fmaf(SO[pp*12+r], wfc[(pp*12+r)*6+j], a);
    part[pp*6+j] = a;
  }
  __syncthreads();
  if (t < 6){
    float a = bfc[t];
    #pragma unroll
    for (int pp=0;pp<16;pp++) a += part[pp*6+t];
    out[g*6+t] = a;
  }
}

extern "C" void kernel_launch(void* const* d_in, const int* in_sizes, int n_in,
                              void* d_out, int out_size, void* d_ws, size_t ws_size,
                              hipStream_t stream)
{
  const float* x   = (const float*)d_in[0];
  const int*   eix = (const int*)d_in[1];
  const int*   shf = (const int*)d_in[2];
  const float* wl0 = (const float*)d_in[3];
  const float* bl0 = (const float*)d_in[4];
  const float* wr0 = (const float*)d_in[5];
  const float* wl  = (const float*)d_in[6];
  const float* bl  = (const float*)d_in[7];
  const float* wr  = (const float*)d_in[8];
  const float* wq  = (const float*)d_in[9];
  const float* bq  = (const float*)d_in[10];
  const float* wk  = (const float*)d_in[11];
  const float* bk  = (const float*)d_in[12];
  const float* wv  = (const float*)d_in[13];
  const float* bv  = (const float*)d_in[14];
  const float* wo  = (const float*)d_in[15];
  const float* bo  = (const float*)d_in[16];
  const float* wfc = (const float*)d_in[17];
  const float* bfc = (const float*)d_in[18];
  float* out = (float*)d_out;

  const int* esrc = eix;
  const int* edst = eix + ETOT;

  // workspace carve
  char* p = (char*)d_ws;
  auto carve = [&](size_t bytes){ void* r = (void*)p; p += (bytes + 255) & ~(size_t)255; return r; };
  int*      off   = (int*)carve(sizeof(int)*(NTOT+1));
  int*      gcnt  = (int*)carve(sizeof(int)*(size_t)NBLK*NBUCK);   // 1.8 MB
  int*      btot  = (int*)carve(sizeof(int)*256);
  int*      bbase = (int*)carve(sizeof(int)*256);
  uint2*    ovf   = (uint2*)carve(sizeof(uint2)*OVFCAP);
  int*      ocnt  = (int*)carve(sizeof(int)*64);
  f16*      wcp   = (f16*)carve(sizeof(f16)*(WKV_OFF + 2048));
  uint32_t* csrp  = (uint32_t*)carve(sizeof(uint32_t)*((size_t)ETOT + 64));
  f16*      h_a   = (f16*)carve(2*((size_t)NTOT+1)*HID);   // +1 zero row (index ZN)
  f16*      h_b   = (f16*)carve(2*((size_t)NTOT+1)*HID);   // +1 zero row
  f16*      jk16  = (f16*)carve(2*(size_t)NTOT*HID);

  // aliases over dead regions:
  f16*      xh     = (f16*)h_b;         // padded f16 x [NTOT+1][16] (28.8MB), dead after k_layer0
  uint32_t* binned = (uint32_t*)h_a;    // 220*2048*32*4 = NTOT*64 B (row ZN untouched)

  k_pad   <<<ETOT/256,  256, 0, stream>>>(x, xh, h_a, h_b, ocnt);
  k_wprep <<<1,         256, 0, stream>>>(wl0, wr0, wl, wr, wk, wv, wcp);
  k_bin   <<<NBLK,    BINTH, 0, stream>>>(esrc, edst, binned, gcnt, ovf, ocnt);
  k_btot  <<<NBUCK,     256, 0, stream>>>(gcnt, ovf, ocnt, btot);
  k_bscan <<<1,         256, 0, stream>>>(btot, bbase);
  k_bucket<<<NBUCK,    1024, 0, stream>>>(binned, gcnt, bbase, ovf, ocnt, off, csrp);

  k_layer0<<<NTOT/NPB, 256, 0, stream>>>(xh, off, csrp, wcp, bl0, h_a);
  f16* hc = h_a; f16* hn = h_b;
  static const int modes[4] = {MODE_A, MODE_B, MODE_C, MODE_D};
  for (int l=0; l<4; l++){
    k_layer<<<NTOT/NPB, 256, 0, stream>>>(hc, off, csrp,
                                          wcp + 1024 + l*2048, bl + l*HID,
                                          hn, jk16, modes[l]);
    f16* tmp = hc; hc = hn; hn = tmp;
  }
  k_attn<<<BGRAPH, 256, 0, stream>>>(jk16, x, shf, wcp + WKV_OFF,
                                     wq, bq, bk, bv, wo, bo, wfc, bfc, out);
}

// Round 12
// 796.346 us; speedup vs baseline: 4.8425x; 1.0180x over previous
//
#include <hip/hip_runtime.h>
#include <cstdint>
#include <cstddef>

#define NODES   55
#define BGRAPH  16384
#define NTOT    (BGRAPH*NODES)    // 901120
#define INCH    13
#define HID     32
#define ETOT    (4*NTOT)          // 3604480
#define NPB     128               // nodes per block (layer kernels)
#define ECAP    768               // layer0 LDS edge-list capacity
#define ECAP2   640               // k_layer LDS edge-list capacity (mean 512, +5.7 sigma; global fallback)
#define ZN      NTOT              // dummy zero-row index for masked edge slots

// ---- deterministic binned CSR build ----
#define NBUCK   220               // NTOT/4096 buckets
#define BSH     12                // 4096 nodes per bucket
#define BMSK    4095
#define NBLK    2048              // k_bin blocks
#define BCAP2   32                // slots per (bucket,block) segment; mean 8, +8.5 sigma
#define BINTH   256
#define BINGRP  (ETOT/4/NBLK)     // 440 int4-groups per block (exact)
#define OVFCAP  8192

// ---- MFMA staging ----
#define ASTR0   40                // layer0 A/B stride (f16): 80B rows
#define WKV_OFF 9216              // wkvT offset (f16 elems) inside wcp

// ---- jk folding modes ----
#define MODE_A  0   // L1: jk1 := max(h1own(hin), h2); write hout
#define MODE_B  1   // L2/L3: no jk; write hout
#define MODE_E  2   // L4: jk := max(jk1, h3own(hout-buf), h4own(hin), h5); NO hout write

typedef _Float16 f16;
typedef _Float16 f16x4 __attribute__((ext_vector_type(4))); // 8B
typedef _Float16 f16x8 __attribute__((ext_vector_type(8))); // 16B
typedef float    f32x4 __attribute__((ext_vector_type(4)));

__device__ __forceinline__ float selu_f(float v){
  const float s  = 1.0507009873554805f;
  const float sa = 1.7580993408473766f;   // scale*alpha
  return v > 0.f ? s*v : sa*(__expf(v)-1.f);
}

// ---------------- pad x[N,13] fp32 -> xh[N,16] f16 (32B rows); zero dummy rows + ovf cursor ----------------
__global__ __launch_bounds__(256) void k_pad(const float* __restrict__ x,
                                             f16* __restrict__ xh,
                                             f16* __restrict__ ha,
                                             f16* __restrict__ hb,
                                             int* __restrict__ ocnt){
  if (blockIdx.x == 0){
    int t = threadIdx.x;
    if (t == 0) *ocnt = 0;
    if (t < 16)                  xh[(size_t)ZN*16 + t]      = (f16)0.f;  // zero row of xh
    else if (t >= 16 && t < 48)  ha[(size_t)ZN*32 + (t-16)] = (f16)0.f;  // zero row of h_a
    else if (t >= 48 && t < 80)  hb[(size_t)ZN*32 + (t-48)] = (f16)0.f;  // zero row of h_b
  }
  int i = blockIdx.x*256 + threadIdx.x;   // one f16x4 per thread, ETOT total (grid exact)
  int node = i>>2, q = i&3;
  const float* r = x + (size_t)node*INCH + q*4;
  f16x4 v;
  v[0] = (f16)r[0];
  v[1] = (q<3) ? (f16)r[1] : (f16)0.f;
  v[2] = (q<3) ? (f16)r[2] : (f16)0.f;
  v[3] = (q<3) ? (f16)r[3] : (f16)0.f;
  *(f16x4*)(xh + (size_t)node*16 + q*4) = v;
}

// ---------------- weight prep: concat+transpose to f16 once ----------------
// wcp layout: [0,1024)            = B0^T[32 oc][32 k]  (k<13: wl0, 16..28: wr0, else 0)
//             [1024 + l*2048 ...) = Bl^T[32 oc][64 k]  (k<32: wl[l], else wr[l])
//             [9216, 11264)       = [Wk|Wv]^T[64 oc][32 k]  (oc<32: wk, else wv)
__global__ __launch_bounds__(256) void k_wprep(
    const float* __restrict__ wl0, const float* __restrict__ wr0,
    const float* __restrict__ wl,  const float* __restrict__ wr,
    const float* __restrict__ wk,  const float* __restrict__ wv,
    f16* __restrict__ wcp)
{
  int t = threadIdx.x;
  for (int i=t; i<1024; i+=256){
    int oc = i>>5, k = i&31;
    float v = 0.f;
    if (k < 13)                 v = wl0[k*HID + oc];
    else if (k >= 16 && k < 29) v = wr0[(k-16)*HID + oc];
    wcp[oc*32 + k] = (f16)v;
  }
  for (int i=t; i<4*2048; i+=256){
    int l = i>>11, r = i&2047, oc = r>>6, k = r&63;
    float v = (k<32) ? wl[l*1024 + k*HID + oc] : wr[l*1024 + (k-32)*HID + oc];
    wcp[1024 + l*2048 + oc*64 + k] = (f16)v;
  }
  for (int i=t; i<2048; i+=256){
    int oc = i>>5, k = i&31;
    float v = (oc < 32) ? wk[k*HID + oc] : wv[k*HID + (oc-32)];
    wcp[WKV_OFF + oc*32 + k] = (f16)v;
  }
}

// ---------------- phase A: bin edges into per-(bucket,block) segments, no global atomics ----------------
__global__ __launch_bounds__(BINTH) void k_bin(
    const int* __restrict__ src, const int* __restrict__ dst,
    uint32_t* __restrict__ binned, int* __restrict__ gcnt,
    uint2* __restrict__ ovf, int* __restrict__ ocnt)
{
  __shared__ int lcnt[NBUCK];
  int t = threadIdx.x, bid = blockIdx.x;
  for (int i=t;i<NBUCK;i+=BINTH) lcnt[i]=0;
  __syncthreads();
  const int4* s4 = (const int4*)src;
  const int4* d4 = (const int4*)dst;
  int g0 = bid*BINGRP;
  for (int i=t; i<BINGRP; i+=BINTH){
    int4 s = s4[g0+i];
    int4 d = d4[g0+i];
    #pragma unroll
    for (int j=0;j<4;j++){
      int dd = (&d.x)[j];
      int ss = (&s.x)[j];
      int b  = dd >> BSH;
      uint32_t entry = (uint32_t)ss | ((uint32_t)(dd & BMSK) << 20);
      int pos = atomicAdd(&lcnt[b], 1);
      if (pos < BCAP2) binned[((size_t)b*NBLK + bid)*BCAP2 + pos] = entry;
      else {                                  // ~1e-10/cell; correctness fallback
        int gp = atomicAdd(ocnt, 1);
        if (gp < OVFCAP) ovf[gp] = make_uint2(entry, (uint32_t)b);
      }
    }
  }
  __syncthreads();
  for (int i=t;i<NBUCK;i+=BINTH){
    int c = lcnt[i]; if (c > BCAP2) c = BCAP2;
    gcnt[bid*NBUCK + i] = c;                  // coalesced per-block row
  }
}

// ---------------- bucket totals (incl. overflow) ----------------
__global__ __launch_bounds__(256) void k_btot(const int* __restrict__ gcnt,
                                              const uint2* __restrict__ ovf,
                                              const int* __restrict__ ocnt,
                                              int* __restrict__ btot){
  __shared__ int sd[256];
  int b = blockIdx.x, t = threadIdx.x;
  int s = 0;
  for (int i=t;i<NBLK;i+=256) s += gcnt[i*NBUCK + b];
  int oc = *ocnt; if (oc > OVFCAP) oc = OVFCAP;
  for (int j=t;j<oc;j+=256) if (ovf[j].y == (uint32_t)b) s++;
  sd[t]=s; __syncthreads();
  for (int o=128;o>0;o>>=1){ if (t<o) sd[t]+=sd[t+o]; __syncthreads(); }
  if (t==0) btot[b]=sd[0];
}

// ---------------- exclusive scan of 220 bucket totals ----------------
__global__ __launch_bounds__(256) void k_bscan(const int* __restrict__ btot,
                                               int* __restrict__ bbase){
  __shared__ int sd[256];
  int t = threadIdx.x;
  int v = (t<NBUCK) ? btot[t] : 0;
  sd[t] = v; __syncthreads();
  for (int o=1;o<256;o<<=1){
    int u = (t>=o) ? sd[t-o] : 0;
    __syncthreads();
    sd[t] += u;
    __syncthreads();
  }
  if (t<NBUCK) bbase[t] = sd[t] - v;
}

// ---------------- phase B: per-bucket counting sort -> off + csrp (L2-local) ----------------
__global__ __launch_bounds__(1024) void k_bucket(
    const uint32_t* __restrict__ binned, const int* __restrict__ gcnt,
    const int* __restrict__ bbase,
    const uint2* __restrict__ ovf, const int* __restrict__ ocnt,
    int* __restrict__ off, uint32_t* __restrict__ csrp)
{
  __shared__ int hist[4096];   // degree counts -> scatter cursors
  __shared__ int cnts[NBLK];
  __shared__ int ws[1024];
  int b = blockIdx.x, t = threadIdx.x;
  int base = bbase[b];
  for (int i=t;i<NBLK;i+=1024) cnts[i] = gcnt[i*NBUCK + b];
  #pragma unroll
  for (int i=0;i<4;i++) hist[t+1024*i] = 0;
  int oc = *ocnt; if (oc > OVFCAP) oc = OVFCAP;
  __syncthreads();

  const uint4* bb4 = (const uint4*)(binned + (size_t)b*(NBLK*BCAP2));
  // pass 1: local-degree histogram (segment loads guarded by fill count: ~50% traffic cut)
  for (int i=t; i<NBLK*BCAP2/4; i+=1024){
    int c = cnts[i>>3];
    int s0 = (i&7)*4;
    if (s0 >= c) continue;
    uint4 e = bb4[i];
    atomicAdd(&hist[(e.x>>20)&BMSK],1);
    if (s0+1 < c) atomicAdd(&hist[(e.y>>20)&BMSK],1);
    if (s0+2 < c) atomicAdd(&hist[(e.z>>20)&BMSK],1);
    if (s0+3 < c) atomicAdd(&hist[(e.w>>20)&BMSK],1);
  }
  for (int j=t;j<oc;j+=1024){
    uint2 pr = ovf[j];
    if (pr.y == (uint32_t)b) atomicAdd(&hist[(pr.x>>20)&BMSK],1);
  }
  __syncthreads();
  // exclusive scan of 4096 degrees
  int t4 = t*4;
  int s0=hist[t4], s1=hist[t4+1], s2=hist[t4+2], s3=hist[t4+3];
  int sum = s0+s1+s2+s3;
  ws[t] = sum; __syncthreads();
  for (int o=1;o<1024;o<<=1){
    int u = (t>=o) ? ws[t-o] : 0;
    __syncthreads();
    ws[t] += u;
    __syncthreads();
  }
  int ex = ws[t] - sum;
  int p0 = ex, p1 = ex+s0, p2 = ex+s0+s1, p3 = ex+s0+s1+s2;
  hist[t4]=p0; hist[t4+1]=p1; hist[t4+2]=p2; hist[t4+3]=p3;   // cursors
  int4 ov; ov.x = base+p0; ov.y = base+p1; ov.z = base+p2; ov.w = base+p3;
  ((int4*)(off + (b<<BSH)))[t] = ov;
  if (b == NBUCK-1 && t == 1023) off[NTOT] = ETOT;
  __syncthreads();
  // pass 2: scatter to final CSR (guarded loads; 256KB window -> single-XCD L2 absorbs)
  for (int i=t; i<NBLK*BCAP2/4; i+=1024){
    int c = cnts[i>>3];
    int s0b = (i&7)*4;
    if (s0b >= c) continue;
    uint4 e = bb4[i];
    int p;
    p = atomicAdd(&hist[(e.x>>20)&BMSK],1); csrp[base+p] = e.x & 0xFFFFFu;
    if (s0b+1 < c){ p = atomicAdd(&hist[(e.y>>20)&BMSK],1); csrp[base+p] = e.y & 0xFFFFFu; }
    if (s0b+2 < c){ p = atomicAdd(&hist[(e.z>>20)&BMSK],1); csrp[base+p] = e.z & 0xFFFFFu; }
    if (s0b+3 < c){ p = atomicAdd(&hist[(e.w>>20)&BMSK],1); csrp[base+p] = e.w & 0xFFFFFu; }
  }
  for (int j=t;j<oc;j+=1024){
    uint2 pr = ovf[j];
    if (pr.y == (uint32_t)b){
      int p = atomicAdd(&hist[(pr.x>>20)&BMSK],1);
      csrp[base+p] = pr.x & 0xFFFFFu;
    }
  }
}

// ---------------- fused SAGE layer 0 (gather from f16 x-rows + MFMA, K=32) ----------------
__global__ __launch_bounds__(256,8) void k_layer0(
    const f16* __restrict__ xh,
    const int* __restrict__ off, const uint32_t* __restrict__ csrp,
    const f16* __restrict__ wcat0, const float* __restrict__ bl0,
    f16* __restrict__ hout)
{
  __shared__ uint32_t ALDS[NPB*(ASTR0/2)];   // 10240B: A[128][40] f16 = [mean16|x16]; reused as ST
  __shared__ uint32_t BLDS[32*(ASTR0/2)];    // 2560B:  B0^T[32][40] f16
  __shared__ uint32_t EL[ECAP];              // 3072B
  __shared__ int      sOFF[NPB+2];
  __shared__ float    biasL[32];
  int t = threadIdx.x;
  int base = blockIdx.x*NPB;
  int e0 = off[base];
  int e1 = off[base+NPB];
  for (int i=t; i<NPB+1; i+=256) sOFF[i] = off[base+i];
  {
    int lim = (e1-e0) < ECAP ? (e1-e0) : ECAP;
    for (int i=t; i<lim; i+=256) EL[i] = csrp[e0+i];
  }
  if (t < 128){
    int oc = t>>2, kq = (t&3)*8;
    f16x8 wv = *(const f16x8*)(wcat0 + oc*32 + kq);
    *(f16x8*)((f16*)BLDS + oc*ASTR0 + kq) = wv;
  }
  if (t < 32) biasL[t] = bl0[t];
  __syncthreads();   // staging (sOFF/EL/BLDS/bias) visible before gather reads

  // gather: 4 lanes per node (f16x4 = 4 ch each, 32B rows); masked slots -> zero row ZN
  int c4 = t & 3;
  #pragma unroll
  for (int p=0;p<2;p++){
    int nl = p*64 + (t>>2);
    int node = base + nl;
    f16x4 xown = *(const f16x4*)(xh + (size_t)node*16 + 4u*c4);
    int s = sOFF[nl] - e0;
    int d = sOFF[nl+1] - sOFF[nl];
    float a0=0.f,a1=0.f,a2=0.f,a3=0.f;
    for (int i=0;i<d;i+=4){
      int j0 = s+i;
      uint32_t k0,k1,k2,k3;
      if (j0+3 < ECAP){ k0=EL[j0]; k1=EL[j0+1]; k2=EL[j0+2]; k3=EL[j0+3]; }
      else            { k0=csrp[e0+j0]; k1=csrp[e0+j0+1]; k2=csrp[e0+j0+2]; k3=csrp[e0+j0+3]; }
      k1 = (i+1<d)?k1:(uint32_t)ZN;
      k2 = (i+2<d)?k2:(uint32_t)ZN;
      k3 = (i+3<d)?k3:(uint32_t)ZN;
      f16x4 g0 = *(const f16x4*)(xh + (size_t)k0*16u + 4u*c4);
      f16x4 g1 = *(const f16x4*)(xh + (size_t)k1*16u + 4u*c4);
      f16x4 g2 = *(const f16x4*)(xh + (size_t)k2*16u + 4u*c4);
      f16x4 g3 = *(const f16x4*)(xh + (size_t)k3*16u + 4u*c4);
      a0 += ((float)g0[0]+(float)g1[0]) + ((float)g2[0]+(float)g3[0]);
      a1 += ((float)g0[1]+(float)g1[1]) + ((float)g2[1]+(float)g3[1]);
      a2 += ((float)g0[2]+(float)g1[2]) + ((float)g2[2]+(float)g3[2]);
      a3 += ((float)g0[3]+(float)g1[3]) + ((float)g2[3]+(float)g3[3]);
    }
    float inv = 1.f/(float)(d<1?1:d);
    union { f16 h[4]; uint32_t u[2]; } mp, xp;
    mp.h[0]=(f16)(a0*inv); mp.h[1]=(f16)(a1*inv); mp.h[2]=(f16)(a2*inv); mp.h[3]=(f16)(a3*inv);
    xp.h[0]=xown[0]; xp.h[1]=xown[1]; xp.h[2]=xown[2]; xp.h[3]=xown[3];
    uint32_t* arow = &ALDS[nl*(ASTR0/2)];
    *((uint2*)&arow[2*c4])     = make_uint2(mp.u[0], mp.u[1]);   // mean cols 4c4..
    *((uint2*)&arow[8 + 2*c4]) = make_uint2(xp.u[0], xp.u[1]);   // x cols 16+4c4..
  }
  __syncthreads();

  // MFMA: wave w owns rows 32w..32w+31, cols 0..31; single K=32 step
  int w = t>>6, l = t&63;
  int lrow = l&15, lg = l>>4;
  const f16* Af = (const f16*)ALDS;
  const f16* Bf = (const f16*)BLDS;
  f32x4 D00={0.f,0.f,0.f,0.f}, D01=D00, D10=D00, D11=D00;
  {
    f16x8 af0 = *(const f16x8*)(Af + (32*w+lrow)*ASTR0    + 8*lg);
    f16x8 af1 = *(const f16x8*)(Af + (32*w+16+lrow)*ASTR0 + 8*lg);
    f16x8 bf0 = *(const f16x8*)(Bf + lrow*ASTR0           + 8*lg);
    f16x8 bf1 = *(const f16x8*)(Bf + (16+lrow)*ASTR0      + 8*lg);
    D00 = __builtin_amdgcn_mfma_f32_16x16x32_f16(af0, bf0, D00, 0,0,0);
    D01 = __builtin_amdgcn_mfma_f32_16x16x32_f16(af0, bf1, D01, 0,0,0);
    D10 = __builtin_amdgcn_mfma_f32_16x16x32_f16(af1, bf0, D10, 0,0,0);
    D11 = __builtin_amdgcn_mfma_f32_16x16x32_f16(af1, bf1, D11, 0,0,0);
  }
  __syncthreads();       // all frag reads done -> ALDS reusable as ST

  f16* ST = (f16*)ALDS;  // [128][34] f16 staging
  #pragma unroll
  for (int j=0;j<4;j++){
    int r0 = 32*w + 4*lg + j, r1 = r0 + 16;
    ST[r0*34 + lrow]      = (f16)selu_f(D00[j] + biasL[lrow]);
    ST[r0*34 + 16 + lrow] = (f16)selu_f(D01[j] + biasL[16+lrow]);
    ST[r1*34 + lrow]      = (f16)selu_f(D10[j] + biasL[lrow]);
    ST[r1*34 + 16 + lrow] = (f16)selu_f(D11[j] + biasL[16+lrow]);
  }
  __syncthreads();

  const uint32_t* STd = (const uint32_t*)ALDS;
  uint4* ho4 = (uint4*)hout;
  int gbase = blockIdx.x*(NPB*HID/8);   // 512 16B-chunks per block
  #pragma unroll
  for (int k=0;k<2;k++){
    int cch = t + 256*k;
    int n = cch>>2, m = cch&3;
    int dd = n*17 + m*4;
    uint4 u;
    u.x=STd[dd]; u.y=STd[dd+1]; u.z=STd[dd+2]; u.w=STd[dd+3];
    ho4[gbase+cch] = u;
  }
}

// ---------------- fused SAGE layers 1..4 (gather + MFMA, K=64; slim LDS, 8 blocks/CU) ----------------
// MODE_A (L1): jk1 := max(h1own(hin), h2); write hout
// MODE_B (L2/L3): no jk; write hout
// MODE_E (L4): jk := max(jk1, h3own(hout-buf), h4own(hin), h5); NO hout write
__global__ __launch_bounds__(256,8) void k_layer(
    const f16* __restrict__ hin,
    const int* __restrict__ off, const uint32_t* __restrict__ csrp,
    const f16* __restrict__ wcat, const float* __restrict__ bl,
    f16* __restrict__ hout, f16* __restrict__ jkio, int mode)
{
  __shared__ uint32_t ALDS[NPB*32];    // 16384B: A[128][64] f16 = [mean32|h32], no pad; reused as ST
  __shared__ uint32_t EL[ECAP2];       // 2560B
  __shared__ int      sOFF[NPB+2];     // 520B
  __shared__ float    biasL[32];       // 128B   => ~19.6KB -> 8 blocks/CU
  int t = threadIdx.x;
  int base = blockIdx.x*NPB;
  int e0 = off[base];
  int e1 = off[base+NPB];
  for (int i=t; i<NPB+1; i+=256) sOFF[i] = off[base+i];
  {
    int lim = (e1-e0) < ECAP2 ? (e1-e0) : ECAP2;
    for (int i=t; i<lim; i+=256) EL[i] = csrp[e0+i];
  }
  if (t < 32) biasL[t] = bl[t];
  __syncthreads();   // staging (sOFF/EL/bias) visible before gather reads

  // gather: 4 lanes per node (f16x8 = 8 ch each); masked slots -> zero row ZN
  int c4 = t & 3;
  #pragma unroll
  for (int p=0;p<2;p++){
    int nl = p*64 + (t>>2);
    int node = base + nl;
    f16x8 hown = *(const f16x8*)(hin + (size_t)node*HID + 8u*c4);
    int s = sOFF[nl] - e0;
    int d = sOFF[nl+1] - sOFF[nl];
    float a[8];
    #pragma unroll
    for (int r=0;r<8;r++) a[r]=0.f;
    for (int i=0;i<d;i+=4){
      int j0 = s+i;
      uint32_t k0,k1,k2,k3;
      if (j0+3 < ECAP2){ k0=EL[j0]; k1=EL[j0+1]; k2=EL[j0+2]; k3=EL[j0+3]; }
      else             { k0=csrp[e0+j0]; k1=csrp[e0+j0+1]; k2=csrp[e0+j0+2]; k3=csrp[e0+j0+3]; }
      k1 = (i+1<d)?k1:(uint32_t)ZN;
      k2 = (i+2<d)?k2:(uint32_t)ZN;
      k3 = (i+3<d)?k3:(uint32_t)ZN;
      f16x8 g0 = *((const f16x8*)(hin + (size_t)k0*32u) + c4);
      f16x8 g1 = *((const f16x8*)(hin + (size_t)k1*32u) + c4);
      f16x8 g2 = *((const f16x8*)(hin + (size_t)k2*32u) + c4);
      f16x8 g3 = *((const f16x8*)(hin + (size_t)k3*32u) + c4);
      #pragma unroll
      for (int r=0;r<8;r++)
        a[r] += ((float)g0[r]+(float)g1[r]) + ((float)g2[r]+(float)g3[r]);
    }
    float inv = 1.f/(float)(d<1?1:d);
    union { f16 h[8]; uint4 v; } mp;
    #pragma unroll
    for (int r=0;r<8;r++) mp.h[r] = (f16)(a[r]*inv);
    uint32_t* arow = &ALDS[nl*32];
    *((uint4*)&arow[4*c4]) = mp.v;                          // mean cols 8c4..
    *((f16x8*)((f16*)arow + 32 + 8*c4)) = hown;             // h cols 32+8c4..
  }
  __syncthreads();

  // MFMA: wave w owns rows 32w..32w+31, cols 0..31; two K=32 steps.
  // B^T read directly from global (4KB table, L2-resident across all blocks).
  int w = t>>6, l = t&63;
  int lrow = l&15, lg = l>>4;
  const f16* Af = (const f16*)ALDS;
  f32x4 D00={0.f,0.f,0.f,0.f}, D01=D00, D10=D00, D11=D00;
  #pragma unroll
  for (int s2=0;s2<2;s2++){
    f16x8 af0 = *(const f16x8*)(Af + (32*w+lrow)*64    + 32*s2 + 8*lg);
    f16x8 af1 = *(const f16x8*)(Af + (32*w+16+lrow)*64 + 32*s2 + 8*lg);
    f16x8 bf0 = *(const f16x8*)(wcat + lrow*64         + 32*s2 + 8*lg);
    f16x8 bf1 = *(const f16x8*)(wcat + (16+lrow)*64    + 32*s2 + 8*lg);
    D00 = __builtin_amdgcn_mfma_f32_16x16x32_f16(af0, bf0, D00, 0,0,0);
    D01 = __builtin_amdgcn_mfma_f32_16x16x32_f16(af0, bf1, D01, 0,0,0);
    D10 = __builtin_amdgcn_mfma_f32_16x16x32_f16(af1, bf0, D10, 0,0,0);
    D11 = __builtin_amdgcn_mfma_f32_16x16x32_f16(af1, bf1, D11, 0,0,0);
  }
  __syncthreads();       // all frag reads done -> ALDS reusable as ST

  f16* ST = (f16*)ALDS;  // [128][34] f16 staging (8704B <= 16384B)
  #pragma unroll
  for (int j=0;j<4;j++){
    int r0 = 32*w + 4*lg + j, r1 = r0 + 16;
    ST[r0*34 + lrow]      = (f16)selu_f(D00[j] + biasL[lrow]);
    ST[r0*34 + 16 + lrow] = (f16)selu_f(D01[j] + biasL[16+lrow]);
    ST[r1*34 + lrow]      = (f16)selu_f(D10[j] + biasL[lrow]);
    ST[r1*34 + 16 + lrow] = (f16)selu_f(D11[j] + biasL[16+lrow]);
  }
  __syncthreads();

  const uint32_t* STd = (const uint32_t*)ALDS;
  uint4* ho4 = (uint4*)hout;
  uint4* jo4 = (uint4*)jkio;
  const uint4* hi4 = (const uint4*)hin;   // own h_in rows (gather-warmed)
  int gbase = blockIdx.x*(NPB*HID/8);
  #pragma unroll
  for (int k=0;k<2;k++){
    int cch = t + 256*k;
    int n = cch>>2, m = cch&3;
    int dd = n*17 + m*4;
    union UU { uint4 u; f16 hh[8]; };
    UU hv, jv, j2;
    hv.u.x=STd[dd]; hv.u.y=STd[dd+1]; hv.u.z=STd[dd+2]; hv.u.w=STd[dd+3];
    if (mode == MODE_B){
      ho4[gbase+cch] = hv.u;
    } else if (mode == MODE_A){
      jv.u = hi4[gbase+cch];                 // h1 own
      #pragma unroll
      for (int r=0;r<8;r++) jv.hh[r] = (hv.hh[r] > jv.hh[r]) ? hv.hh[r] : jv.hh[r];
      jo4[gbase+cch] = jv.u;                 // jk1 = max(h1,h2)
      ho4[gbase+cch] = hv.u;
    } else {                                 // MODE_E
      jv.u = jo4[gbase+cch];                 // jk1
      j2.u = hi4[gbase+cch];                 // h4 own
      #pragma unroll
      for (int r=0;r<8;r++) jv.hh[r] = (j2.hh[r] > jv.hh[r]) ? j2.hh[r] : jv.hh[r];
      j2.u = ho4[gbase+cch];                 // h3 (hout param = h3 buffer, read-only here)
      #pragma unroll
      for (int r=0;r<8;r++) jv.hh[r] = (j2.hh[r] > jv.hh[r]) ? j2.hh[r] : jv.hh[r];
      #pragma unroll
      for (int r=0;r<8;r++) jv.hh[r] = (hv.hh[r] > jv.hh[r]) ? hv.hh[r] : jv.hh[r];
      jo4[gbase+cch] = jv.u;                 // jk = max(h1..h5)
    }
  }
}

// ---------------- attention + head, one block per graph (MFMA K/V, slim LDS) ----------------
__global__ __launch_bounds__(256) void k_attn(
    const f16* __restrict__ jk, const float* __restrict__ x,
    const int* __restrict__ shuf, const f16* __restrict__ wkvT,
    const float* __restrict__ wq, const float* __restrict__ bq,
    const float* __restrict__ bk, const float* __restrict__ bv,
    const float* __restrict__ wo, const float* __restrict__ bo,
    const float* __restrict__ wfc, const float* __restrict__ bfc,
    float* __restrict__ out)
{
  __shared__ alignas(16) f16 Ah[64*40];   // 5120B: H=selu(jk) f16; rows 55..63 garbage (discarded)
  __shared__ float K[NODES*33];           // 7260B
  __shared__ float V[NODES*33];           // 7260B
  __shared__ float Qs[6*33];
  __shared__ float S[6*56];
  __shared__ float O[6*33];
  __shared__ float SO[192];
  __shared__ float part[96];
  __shared__ int   sel[8];

  int g = blockIdx.x, t = threadIdx.x;

  // stage H = selu(jk) as f16 into A-tile (rows=nodes, 40-f16 stride)
  {
    const f16x8* j8 = (const f16x8*)(jk + (size_t)g*NODES*HID);
    for (int i=t; i<NODES*HID/8; i+=256){   // 220 vectors of 8
      f16x8 v = j8[i];
      int node = i >> 2, c0 = (i & 3)*8;
      f16x8 hv;
      #pragma unroll
      for (int r=0;r<8;r++) hv[r] = (f16)selu_f((float)v[r]);
      *(f16x8*)(Ah + node*40 + c0) = hv;
    }
  }
  // wave 0: neighbor-mask ballot -> sel (no serial loop)
  if (t < 64){
    float mv = (t < NODES) ? x[(size_t)(g*NODES+t)*INCH + (INCH-3)] : 0.f;
    unsigned long long mb = __ballot(mv > 0.5f);
    if (t < 6){
      int kk = shuf[g*6 + t];
      for (int i2=0;i2<kk;i2++) mb &= (mb - 1ull);
      sel[t] = (int)__builtin_ctzll(mb);
    }
  }
  __syncthreads();

  // K/V projection via MFMA: [64x32] H @ [32x64] (Wk|Wv), wave w = row-tile w
  {
    int w = t>>6, l = t&63;
    int lrow = l&15, lg = l>>4;
    f16x8 af = *(const f16x8*)(Ah + (16*w + lrow)*40 + 8*lg);
    #pragma unroll
    for (int ct=0; ct<4; ct++){
      f16x8 bf = *(const f16x8*)(wkvT + (16*ct + lrow)*32 + 8*lg);  // global, L2-resident
      f32x4 D = {0.f,0.f,0.f,0.f};
      D = __builtin_amdgcn_mfma_f32_16x16x32_f16(af, bf, D, 0,0,0);
      int ocl = 16*(ct&1) + lrow;
      float bias = (ct < 2) ? bk[ocl] : bv[ocl];
      float* dst = (ct < 2) ? K : V;
      #pragma unroll
      for (int j=0;j<4;j++){
        int node = 16*w + 4*lg + j;
        if (node < NODES) dst[node*33 + ocl] = D[j] + bias;
      }
    }
  }
  // Q projection (6x32, VALU; wq from global - cache-resident)
  if (t < 192){
    int q = t>>5, oc = t&31;
    int node = sel[q];
    const f16x8* hr8 = (const f16x8*)(Ah + node*40);
    float a = bq[oc];
    #pragma unroll
    for (int cc=0;cc<4;cc++){
      f16x8 hv = hr8[cc];
      #pragma unroll
      for (int r=0;r<8;r++) a = fmaf((float)hv[r], wq[(8*cc+r)*HID + oc], a);
    }
    Qs[q*33+oc] = a;
  }
  __syncthreads();

  // scores = Q.K^T / sqrt(32)
  for (int idx=t; idx<6*NODES; idx+=256){
    int q = idx % 6, k = idx / 6;
    float a = 0.f;
    #pragma unroll
    for (int c=0;c<HID;c++) a = fmaf(Qs[q*33+c], K[k*33+c], a);
    S[q*56+k] = a * 0.17677669529663687f;
  }
  __syncthreads();

  // softmax over 55 keys: 32-lane group per query
  if (t < 192){
    int q = t>>5, l = t&31;
    float v0 = (l      < NODES) ? S[q*56+l]    : -1e30f;
    float v1 = (l+32   < NODES) ? S[q*56+l+32] : -1e30f;
    float mx = fmaxf(v0, v1);
    #pragma unroll
    for (int o=16;o>0;o>>=1) mx = fmaxf(mx, __shfl_xor(mx, o, 32));
    float p0 = (l    < NODES) ? __expf(v0-mx) : 0.f;
    float p1 = (l+32 < NODES) ? __expf(v1-mx) : 0.f;
    float sm = p0 + p1;
    #pragma unroll
    for (int o=16;o>0;o>>=1) sm += __shfl_xor(sm, o, 32);
    float inv = 1.f/sm;
    if (l    < NODES) S[q*56+l]    = p0*inv;
    if (l+32 < NODES) S[q*56+l+32] = p1*inv;
  }
  __syncthreads();

  // attn @ V
  if (t < 192){
    int q = t>>5, oc = t&31;
    float a = 0.f;
    for (int k=0;k<NODES;k++) a = fmaf(S[q*56+k], V[k*33+oc], a);
    O[q*33+oc] = a;
  }
  __syncthreads();

  // @ wo + bo, selu  (wo from global - cache-resident, 6x reuse per block)
  if (t < 192){
    int q = t>>5, oc = t&31;
    float a = bo[oc];
    #pragma unroll
    for (int c=0;c<HID;c++) a = fmaf(O[q*33+c], wo[c*HID+oc], a);
    SO[t] = selu_f(a);   // t == q*32+oc == flat reshape index
  }
  __syncthreads();

  // final FC: 6 outputs = SO[192] . Wfc[:,j]
  if (t < 96){
    int j = t % 6, pp = t / 6;   // 16 partials per output
    float a = 0.f;
    #pragma unroll
    for (int r=0;r<12;r++) a = fmaf(SO[pp*12+r], wfc[(pp*12+r)*6+j], a);
    part[pp*6+j] = a;
  }
  __syncthreads();
  if (t < 6){
    float a = bfc[t];
    #pragma unroll
    for (int pp=0;pp<16;pp++) a += part[pp*6+t];
    out[g*6+t] = a;
  }
}

extern "C" void kernel_launch(void* const* d_in, const int* in_sizes, int n_in,
                              void* d_out, int out_size, void* d_ws, size_t ws_size,
                              hipStream_t stream)
{
  const float* x   = (const float*)d_in[0];
  const int*   eix = (const int*)d_in[1];
  const int*   shf = (const int*)d_in[2];
  const float* wl0 = (const float*)d_in[3];
  const float* bl0 = (const float*)d_in[4];
  const float* wr0 = (const float*)d_in[5];
  const float* wl  = (const float*)d_in[6];
  const float* bl  = (const float*)d_in[7];
  const float* wr  = (const float*)d_in[8];
  const float* wq  = (const float*)d_in[9];
  const float* bq  = (const float*)d_in[10];
  const float* wk  = (const float*)d_in[11];
  const float* bk  = (const float*)d_in[12];
  const float* wv  = (const float*)d_in[13];
  const float* bv  = (const float*)d_in[14];
  const float* wo  = (const float*)d_in[15];
  const float* bo  = (const float*)d_in[16];
  const float* wfc = (const float*)d_in[17];
  const float* bfc = (const float*)d_in[18];
  float* out = (float*)d_out;

  const int* esrc = eix;
  const int* edst = eix + ETOT;

  // workspace carve
  char* p = (char*)d_ws;
  auto carve = [&](size_t bytes){ void* r = (void*)p; p += (bytes + 255) & ~(size_t)255; return r; };
  int*      off   = (int*)carve(sizeof(int)*(NTOT+1));
  int*      gcnt  = (int*)carve(sizeof(int)*(size_t)NBLK*NBUCK);   // 1.8 MB
  int*      btot  = (int*)carve(sizeof(int)*256);
  int*      bbase = (int*)carve(sizeof(int)*256);
  uint2*    ovf   = (uint2*)carve(sizeof(uint2)*OVFCAP);
  int*      ocnt  = (int*)carve(sizeof(int)*64);
  f16*      wcp   = (f16*)carve(sizeof(f16)*(WKV_OFF + 2048));
  uint32_t* csrp  = (uint32_t*)carve(sizeof(uint32_t)*((size_t)ETOT + 64));
  f16*      h_a   = (f16*)carve(2*((size_t)NTOT+1)*HID);   // +1 zero row (index ZN)
  f16*      h_b   = (f16*)carve(2*((size_t)NTOT+1)*HID);   // +1 zero row
  f16*      jk16  = (f16*)carve(2*(size_t)NTOT*HID);

  // aliases over dead regions:
  f16*      xh     = (f16*)h_b;         // padded f16 x [NTOT+1][16] (28.8MB), dead after k_layer0
  uint32_t* binned = (uint32_t*)h_a;    // 220*2048*32*4 = NTOT*64 B (row ZN untouched)

  k_pad   <<<ETOT/256,  256, 0, stream>>>(x, xh, h_a, h_b, ocnt);
  k_wprep <<<1,         256, 0, stream>>>(wl0, wr0, wl, wr, wk, wv, wcp);
  k_bin   <<<NBLK,    BINTH, 0, stream>>>(esrc, edst, binned, gcnt, ovf, ocnt);
  k_btot  <<<NBUCK,     256, 0, stream>>>(gcnt, ovf, ocnt, btot);
  k_bscan <<<1,         256, 0, stream>>>(btot, bbase);
  k_bucket<<<NBUCK,    1024, 0, stream>>>(binned, gcnt, bbase, ovf, ocnt, off, csrp);

  // buffer trace: L0->h_a(h1); L1 h_a->h_b(h2), jk1=max(h1,h2); L2 h_b->h_a(h3);
  // L3 h_a->h_b(h4); L4 hin=h_b(h4), hout param = h_a (holds h3, read-only), jk=max(all).
  k_layer0<<<NTOT/NPB, 256, 0, stream>>>(xh, off, csrp, wcp, bl0, h_a);
  f16* hc = h_a; f16* hn = h_b;
  static const int modes[4] = {MODE_A, MODE_B, MODE_B, MODE_E};
  for (int l=0; l<4; l++){
    k_layer<<<NTOT/NPB, 256, 0, stream>>>(hc, off, csrp,
                                          wcp + 1024 + l*2048, bl + l*HID,
                                          hn, jk16, modes[l]);
    f16* tmp = hc; hc = hn; hn = tmp;
  }
  k_attn<<<BGRAPH, 256, 0, stream>>>(jk16, x, shf, wcp + WKV_OFF,
                                     wq, bq, bk, bv, wo, bo, wfc, bfc, out);
}